// Round 6
// baseline (2434.733 us; speedup 1.0000x reference)
//
#include <hip/hip_runtime.h>
#include <hip/hip_bf16.h>
#include <math.h>

#define BB 2
#define SS 2048
#define EE 512
#define HH 8
#define NN (BB*SS)

__device__ __forceinline__ float bflo(unsigned u){ return __uint_as_float(u << 16); }
__device__ __forceinline__ float bfhi(unsigned u){ return __uint_as_float(u & 0xffff0000u); }

__device__ __forceinline__ float block_reduce_sum(float v, float* red) {
    #pragma unroll
    for (int o = 32; o > 0; o >>= 1) v += __shfl_down(v, o, 64);
    __syncthreads();
    if ((threadIdx.x & 63) == 0) red[threadIdx.x >> 6] = v;
    __syncthreads();
    return red[0] + red[1] + red[2] + red[3];
}

// C = A @ W^T (+bias). W/bias are f32 inputs (reference dtype).
// 64x64 tiles, 256 thr, 4x4/thread, K=512.
// AF32=1: A is f32 input (x). AF32=0: A is internal bf16 buffer.
// CF32=1: C written f32.     CF32=0: C written bf16.
// MODE 0: plain  (qkv projections, out proj)
// MODE 1: ldb=520, + constant-ef(1/S) tail, exact GELU  (MLP1)
// MODE 2: in-place C accumulate: C_new = A@W^T + bias + C_old(bf16)  (MLP2 + u1)
template<int MODE, int AF32, int CF32>
__global__ __launch_bounds__(256) void gemm_bt(
    const void* __restrict__ Av,
    const float* __restrict__ W,
    const float* __restrict__ bias,
    void* __restrict__ Cv,
    int ldb)
{
    __shared__ float As[64][65];
    __shared__ float Bs[64][65];
    const int tid = threadIdx.x;
    const int col0 = blockIdx.x * 64;
    const int row0 = blockIdx.y * 64;
    const int tx = tid & 15;
    const int ty = tid >> 4;
    float acc[4][4] = {};

    for (int k0 = 0; k0 < 512; k0 += 64) {
        if (AF32) {
            const float* Af = (const float*)Av;
            #pragma unroll
            for (int l = 0; l < 4; ++l) {
                const int base = (tid + l * 256) * 4;
                const int r = base >> 6, c = base & 63;
                const float4 f = *reinterpret_cast<const float4*>(
                    Af + (size_t)(row0 + r) * EE + k0 + c);
                As[r][c+0] = f.x; As[r][c+1] = f.y; As[r][c+2] = f.z; As[r][c+3] = f.w;
            }
        } else {
            const __hip_bfloat16* Ab = (const __hip_bfloat16*)Av;
            #pragma unroll
            for (int l = 0; l < 2; ++l) {
                const int base = (tid + l * 256) * 8;
                const int r = base >> 6, c = base & 63;
                const uint4 ua = *reinterpret_cast<const uint4*>(
                    Ab + (size_t)(row0 + r) * EE + k0 + c);
                As[r][c+0] = bflo(ua.x); As[r][c+1] = bfhi(ua.x);
                As[r][c+2] = bflo(ua.y); As[r][c+3] = bfhi(ua.y);
                As[r][c+4] = bflo(ua.z); As[r][c+5] = bfhi(ua.z);
                As[r][c+6] = bflo(ua.w); As[r][c+7] = bfhi(ua.w);
            }
        }
        #pragma unroll
        for (int l = 0; l < 4; ++l) {
            const int base = (tid + l * 256) * 4;
            const int r = base >> 6, c = base & 63;
            const float4 f = *reinterpret_cast<const float4*>(
                W + (size_t)(col0 + r) * ldb + k0 + c);
            Bs[r][c+0] = f.x; Bs[r][c+1] = f.y; Bs[r][c+2] = f.z; Bs[r][c+3] = f.w;
        }
        __syncthreads();
        #pragma unroll
        for (int kk = 0; kk < 64; ++kk) {
            float a[4], bv[4];
            #pragma unroll
            for (int i = 0; i < 4; ++i) a[i] = As[ty*4+i][kk];
            #pragma unroll
            for (int j = 0; j < 4; ++j) bv[j] = Bs[tx*4+j][kk];
            #pragma unroll
            for (int i = 0; i < 4; ++i)
                #pragma unroll
                for (int j = 0; j < 4; ++j)
                    acc[i][j] += a[i] * bv[j];
        }
        __syncthreads();
    }

    if (MODE == 1) {
        // combined = [x ; ef], ef == 1/SS exactly (softmax sums to 1 over j):
        // tail = (1/SS) * sum_h Wm1[col, 512+h]
        #pragma unroll
        for (int j = 0; j < 4; ++j) {
            float ts = 0.f;
            #pragma unroll
            for (int h = 0; h < 8; ++h)
                ts += W[(size_t)(col0 + tx*4 + j) * ldb + 512 + h];
            ts *= (1.0f / (float)SS);
            #pragma unroll
            for (int i = 0; i < 4; ++i) acc[i][j] += ts;
        }
    }

    #pragma unroll
    for (int i = 0; i < 4; ++i) {
        const int gr = row0 + ty*4 + i;
        #pragma unroll
        for (int j = 0; j < 4; ++j) {
            const int gc = col0 + tx*4 + j;
            const size_t ci = (size_t)gr * EE + gc;
            float c = acc[i][j] + bias[gc];
            if (MODE == 1) c = 0.5f * c * (1.0f + erff(c * 0.70710678118654752f));
            if (MODE == 2) c += (float)((const __hip_bfloat16*)Cv)[ci];  // + u1 in-place
            if (CF32) ((float*)Cv)[ci] = c;
            else      ((__hip_bfloat16*)Cv)[ci] = __float2bfloat16(c);
        }
    }
}

// Fused attention + message passing, one block per (b,i) row.
// qu: q buffer; each block reads ONLY its own row and overwrites it with u1
// at the end (per-row RAW inside one block -> aliasing safe).
__global__ __launch_bounds__(256) void attn_fused(
    __hip_bfloat16* qu,
    const __hip_bfloat16* __restrict__ kws,
    const float* __restrict__ vws,
    const float* __restrict__ x)
{
    __shared__ __align__(16) __hip_bfloat16 E[8][2048];   // e^score per head (32 KB)
    __shared__ float qrow[EE];
    __shared__ float ewr[2048];             // head-mean edge weights (8 KB)
    __shared__ float red[4];
    const int tid = threadIdx.x;
    const int i = blockIdx.x;
    const int b = blockIdx.y;
    const size_t row = (size_t)b * SS + i;

    const __hip_bfloat16* qr = qu + row * EE;
    for (int l = tid; l < EE; l += 256) qrow[l] = (float)qr[l];
    __syncthreads();

    // pass 1: e^scores per head + denominators
    const float scale = 0.125f;  // 1/sqrt(64)
    float inv_h[8];
    #pragma unroll
    for (int h = 0; h < HH; ++h) {
        const float* qh = qrow + h * 64;
        float local = 0.f;
        #pragma unroll
        for (int m = 0; m < 8; ++m) {
            const int j = tid + m * 256;
            const uint4* kr = reinterpret_cast<const uint4*>(
                kws + ((size_t)b * SS + j) * EE + h * 64);
            float s = 0.f;
            #pragma unroll
            for (int c2 = 0; c2 < 8; ++c2) {
                const uint4 u = kr[c2];
                const float* q8 = qh + c2 * 8;
                s += bflo(u.x) * q8[0] + bfhi(u.x) * q8[1]
                   + bflo(u.y) * q8[2] + bfhi(u.y) * q8[3]
                   + bflo(u.z) * q8[4] + bfhi(u.z) * q8[5]
                   + bflo(u.w) * q8[6] + bfhi(u.w) * q8[7];
            }
            // scores ~ N(0, ~0.2^2): exp safe without max subtraction
            const float e = __expf(s * scale);
            E[h][j] = __float2bfloat16(e);
            local += e;
        }
        const float denom = block_reduce_sum(local, red);
        inv_h[h] = 1.0f / denom;
    }

    // pass 2: head-mean edge weights + neighbor count
    float cl = 0.f;
    #pragma unroll
    for (int m = 0; m < 8; ++m) {
        const int j = tid + m * 256;
        float w = 0.f;
        #pragma unroll
        for (int h = 0; h < HH; ++h) w += (float)E[h][j] * inv_h[h];
        w *= (1.0f / HH);
        ewr[j] = w;
        cl += (w > 0.1f) ? 1.f : 0.f;
    }
    const float cnt = block_reduce_sum(cl, red);
    const float invn = 1.0f / fmaxf(cnt, 1.0f);
    __syncthreads();   // ewr fully written; E region reusable below

    // pass 3: attended + messages. 4 j-groups x 64 e-groups of 8 columns.
    const int eg = tid & 63;
    const int jg = tid >> 6;
    const int e0 = eg * 8;
    float aA[8] = {}, aM[8] = {};
    const float* vbase = vws + (size_t)b * SS * EE + e0;
    const float* xbase = x   + (size_t)b * SS * EE + e0;
    for (int j = jg; j < SS; j += 4) {
        const float w  = ewr[j];
        const float mw = (w > 0.1f) ? w : 0.f;
        const float4 v0 = *reinterpret_cast<const float4*>(vbase + (size_t)j * EE);
        const float4 v1 = *reinterpret_cast<const float4*>(vbase + (size_t)j * EE + 4);
        const float4 f0 = *reinterpret_cast<const float4*>(xbase + (size_t)j * EE);
        const float4 f1 = *reinterpret_cast<const float4*>(xbase + (size_t)j * EE + 4);
        aA[0] += w * v0.x; aA[1] += w * v0.y;
        aA[2] += w * v0.z; aA[3] += w * v0.w;
        aA[4] += w * v1.x; aA[5] += w * v1.y;
        aA[6] += w * v1.z; aA[7] += w * v1.w;
        aM[0] += mw * f0.x; aM[1] += mw * f0.y;
        aM[2] += mw * f0.z; aM[3] += mw * f0.w;
        aM[4] += mw * f1.x; aM[5] += mw * f1.y;
        aM[6] += mw * f1.z; aM[7] += mw * f1.w;
    }
    // reduce the 4 j-groups via LDS (reuse E storage as float[4096] = 16 KB)
    float* redA = reinterpret_cast<float*>(&E[0][0]);   // [4][512]
    float* redM = redA + 2048;                          // [4][512]
    #pragma unroll
    for (int t = 0; t < 8; ++t) {
        redA[jg * 512 + e0 + t] = aA[t];
        redM[jg * 512 + e0 + t] = aM[t];
    }
    __syncthreads();
    #pragma unroll
    for (int t = 0; t < 2; ++t) {
        const int e = tid + t * 256;
        const float sa = redA[e] + redA[512 + e] + redA[1024 + e] + redA[1536 + e];
        const float sm = redM[e] + redM[512 + e] + redM[1024 + e] + redM[1536 + e];
        qu[row * EE + e] = __float2bfloat16(sa + sm * invn);   // u1 overwrites own q row
    }
}

extern "C" void kernel_launch(void* const* d_in, const int* in_sizes, int n_in,
                              void* d_out, int out_size, void* d_ws, size_t ws_size,
                              hipStream_t stream)
{
    const float* x   = (const float*)d_in[0];
    const float* Wq  = (const float*)d_in[1];
    const float* bq  = (const float*)d_in[2];
    const float* Wk  = (const float*)d_in[3];
    const float* bk  = (const float*)d_in[4];
    const float* Wv  = (const float*)d_in[5];
    const float* bv  = (const float*)d_in[6];
    const float* Wm1 = (const float*)d_in[7];
    const float* bm1 = (const float*)d_in[8];
    const float* Wm2 = (const float*)d_in[9];
    const float* bm2 = (const float*)d_in[10];
    const float* Wo  = (const float*)d_in[11];
    const float* bo  = (const float*)d_in[12];

    // Inputs f32, OUTPUT f32 (reference dtype; d_out = [N,E] f32 = 8 MB).
    // ws: 8 MB touched. v lives in d_out as f32 (dead before final GEMM
    // overwrites it). u1 aliases qb (per-row RAW inside one block only);
    // hm aliases kb; MLP2 accumulates in-place into qb; final reads qb.
    char* ws = (char*)d_ws;
    const size_t MB = 1024 * 1024;
    __hip_bfloat16* qb = (__hip_bfloat16*)(ws + 0);        // q -> u1 -> t   4MB
    __hip_bfloat16* kb = (__hip_bfloat16*)(ws + 4*MB);     // k -> hm        4MB
    float* vb = (float*)d_out;                             // v f32 (scratch in out)

    dim3 blk(256, 1, 1);
    dim3 gg(EE / 64, NN / 64, 1);

    gemm_bt<0,1,0><<<gg, blk, 0, stream>>>(x, Wq, bq, qb, EE);
    gemm_bt<0,1,0><<<gg, blk, 0, stream>>>(x, Wk, bk, kb, EE);
    gemm_bt<0,1,1><<<gg, blk, 0, stream>>>(x, Wv, bv, vb, EE);
    attn_fused<<<dim3(SS, BB, 1), blk, 0, stream>>>(qb, kb, vb, x);
    gemm_bt<1,1,0><<<gg, blk, 0, stream>>>(x, Wm1, bm1, kb, EE + HH);   // hm
    gemm_bt<2,0,0><<<gg, blk, 0, stream>>>(kb, Wm2, bm2, qb, EE);       // t = MLP2 + u1
    gemm_bt<0,0,1><<<gg, blk, 0, stream>>>(qb, Wo, bo, d_out, EE);      // out f32
}

// Round 7
// 929.928 us; speedup vs baseline: 2.6182x; 2.6182x over previous
//
#include <hip/hip_runtime.h>
#include <hip/hip_bf16.h>
#include <math.h>

#define BB 2
#define SS 2048
#define EE 512
#define HH 8
#define NN (BB*SS)
#define TI 16

typedef __attribute__((ext_vector_type(8))) short short8;
typedef __attribute__((ext_vector_type(4))) float f32x4;

__device__ __forceinline__ float bflo(unsigned u){ return __uint_as_float(u << 16); }
__device__ __forceinline__ float bfhi(unsigned u){ return __uint_as_float(u & 0xffff0000u); }
// RNE f32->bf16 bits (matches __float2bfloat16)
__device__ __forceinline__ unsigned f2bf(float f){
    unsigned u = __float_as_uint(f);
    u += 0x7fffu + ((u >> 16) & 1u);
    return u >> 16;
}

// ---------------- GEMM (unchanged from r6 except usage) ----------------
// C = A @ W^T (+bias). W/bias f32 inputs. 64x64 tiles, 256 thr, 4x4/thr, K=512.
// AF32: A f32 (x) vs internal bf16.  CF32: C f32 vs bf16.
// MODE 0 plain; MODE 1 ldb=520 + const-ef(1/S) tail + exact GELU; MODE 2 in-place +C_old
template<int MODE, int AF32, int CF32>
__global__ __launch_bounds__(256) void gemm_bt(
    const void* __restrict__ Av,
    const float* __restrict__ W,
    const float* __restrict__ bias,
    void* __restrict__ Cv,
    int ldb)
{
    __shared__ float As[64][65];
    __shared__ float Bs[64][65];
    const int tid = threadIdx.x;
    const int col0 = blockIdx.x * 64;
    const int row0 = blockIdx.y * 64;
    const int tx = tid & 15;
    const int ty = tid >> 4;
    float acc[4][4] = {};

    for (int k0 = 0; k0 < 512; k0 += 64) {
        if (AF32) {
            const float* Af = (const float*)Av;
            #pragma unroll
            for (int l = 0; l < 4; ++l) {
                const int base = (tid + l * 256) * 4;
                const int r = base >> 6, c = base & 63;
                const float4 f = *reinterpret_cast<const float4*>(
                    Af + (size_t)(row0 + r) * EE + k0 + c);
                As[r][c+0] = f.x; As[r][c+1] = f.y; As[r][c+2] = f.z; As[r][c+3] = f.w;
            }
        } else {
            const __hip_bfloat16* Ab = (const __hip_bfloat16*)Av;
            #pragma unroll
            for (int l = 0; l < 2; ++l) {
                const int base = (tid + l * 256) * 8;
                const int r = base >> 6, c = base & 63;
                const uint4 ua = *reinterpret_cast<const uint4*>(
                    Ab + (size_t)(row0 + r) * EE + k0 + c);
                As[r][c+0] = bflo(ua.x); As[r][c+1] = bfhi(ua.x);
                As[r][c+2] = bflo(ua.y); As[r][c+3] = bfhi(ua.y);
                As[r][c+4] = bflo(ua.z); As[r][c+5] = bfhi(ua.z);
                As[r][c+6] = bflo(ua.w); As[r][c+7] = bfhi(ua.w);
            }
        }
        #pragma unroll
        for (int l = 0; l < 4; ++l) {
            const int base = (tid + l * 256) * 4;
            const int r = base >> 6, c = base & 63;
            const float4 f = *reinterpret_cast<const float4*>(
                W + (size_t)(col0 + r) * ldb + k0 + c);
            Bs[r][c+0] = f.x; Bs[r][c+1] = f.y; Bs[r][c+2] = f.z; Bs[r][c+3] = f.w;
        }
        __syncthreads();
        #pragma unroll
        for (int kk = 0; kk < 64; ++kk) {
            float a[4], bv[4];
            #pragma unroll
            for (int i = 0; i < 4; ++i) a[i] = As[ty*4+i][kk];
            #pragma unroll
            for (int j = 0; j < 4; ++j) bv[j] = Bs[tx*4+j][kk];
            #pragma unroll
            for (int i = 0; i < 4; ++i)
                #pragma unroll
                for (int j = 0; j < 4; ++j)
                    acc[i][j] += a[i] * bv[j];
        }
        __syncthreads();
    }

    if (MODE == 1) {
        #pragma unroll
        for (int j = 0; j < 4; ++j) {
            float ts = 0.f;
            #pragma unroll
            for (int h = 0; h < 8; ++h)
                ts += W[(size_t)(col0 + tx*4 + j) * ldb + 512 + h];
            ts *= (1.0f / (float)SS);
            #pragma unroll
            for (int i = 0; i < 4; ++i) acc[i][j] += ts;
        }
    }

    #pragma unroll
    for (int i = 0; i < 4; ++i) {
        const int gr = row0 + ty*4 + i;
        #pragma unroll
        for (int j = 0; j < 4; ++j) {
            const int gc = col0 + tx*4 + j;
            const size_t ci = (size_t)gr * EE + gc;
            float c = acc[i][j] + bias[gc];
            if (MODE == 1) c = 0.5f * c * (1.0f + erff(c * 0.70710678118654752f));
            if (MODE == 2) c += (float)((const __hip_bfloat16*)Cv)[ci];
            if (CF32) ((float*)Cv)[ci] = c;
            else      ((__hip_bfloat16*)Cv)[ci] = __float2bfloat16(c);
        }
    }
}

// ---------------- Fused attention v2: i-tiled, MFMA scores ----------------
// Block: 256 thr (4 waves), TI=16 q-rows. Grid (SS/TI, BB).
// Phase A: denominators per (i,h) via MFMA QK^T + exp row-sums.
// Per j-half: B1 recompute scores -> ew tile (bf16 LDS) + neighbor flags;
//             B2 accumulate attended (and masked-aggregated iff flagged).
// u1 = attended + messages overwrites this block's own q rows.
__global__ __launch_bounds__(256) void attn_fused(
    __hip_bfloat16* qu,
    const __hip_bfloat16* __restrict__ kws,
    const __hip_bfloat16* __restrict__ vws,
    const float* __restrict__ x)
{
    __shared__ __hip_bfloat16 ewL[TI][1024];   // 32 KB
    __shared__ float dpart[4][HH][TI];         // 2 KB (reused for cnt)
    __shared__ float invd[HH][TI];
    __shared__ float invnL[TI];
    __shared__ int   flagH;

    const int tid  = threadIdx.x;
    const int wv   = tid >> 6;
    const int lane = tid & 63;
    const int quad = lane >> 4;
    const int m16  = lane & 15;
    const int b    = blockIdx.y;
    const int i0   = blockIdx.x * TI;
    const size_t g0 = (size_t)b * SS + i0;   // q/u1 rows
    const size_t gb = (size_t)b * SS;        // k/v/x rows
    const float scale = 0.125f;              // 1/sqrt(64)

    // preload Q A-frags: [h][k-half]; lane holds Q[i0+m16][h*64 + ks*32 + quad*8 .. +8]
    short8 aq[HH][2];
    #pragma unroll
    for (int h = 0; h < HH; ++h)
        #pragma unroll
        for (int ks = 0; ks < 2; ++ks)
            aq[h][ks] = *reinterpret_cast<const short8*>(
                qu + (g0 + m16) * EE + h * 64 + ks * 32 + quad * 8);

    // ---- phase A: denominators (each wave covers a 512-wide j quarter) ----
    #pragma unroll
    for (int h = 0; h < HH; ++h) {
        float dp[4] = {0.f, 0.f, 0.f, 0.f};
        for (int jt = 0; jt < 32; ++jt) {
            const int j0 = wv * 512 + jt * 16;
            const short8 bk0 = *reinterpret_cast<const short8*>(
                kws + (gb + j0 + m16) * EE + h * 64 + quad * 8);
            const short8 bk1 = *reinterpret_cast<const short8*>(
                kws + (gb + j0 + m16) * EE + h * 64 + 32 + quad * 8);
            f32x4 c = {0.f, 0.f, 0.f, 0.f};
            c = __builtin_amdgcn_mfma_f32_16x16x32_bf16(aq[h][0], bk0, c, 0, 0, 0);
            c = __builtin_amdgcn_mfma_f32_16x16x32_bf16(aq[h][1], bk1, c, 0, 0, 0);
            #pragma unroll
            for (int r = 0; r < 4; ++r) dp[r] += __expf(c[r] * scale);
        }
        #pragma unroll
        for (int off = 1; off <= 8; off <<= 1)
            #pragma unroll
            for (int r = 0; r < 4; ++r) dp[r] += __shfl_xor(dp[r], off, 64);
        if (m16 == 0)
            #pragma unroll
            for (int r = 0; r < 4; ++r) dpart[wv][h][quad * 4 + r] = dp[r];
    }
    __syncthreads();
    if (tid < HH * TI) {
        const int h = tid >> 4, i = tid & 15;
        invd[h][i] = 1.0f / (dpart[0][h][i] + dpart[1][h][i]
                           + dpart[2][h][i] + dpart[3][h][i]);
    }
    __syncthreads();

    float idv[HH][4];
    #pragma unroll
    for (int h = 0; h < HH; ++h)
        #pragma unroll
        for (int r = 0; r < 4; ++r) idv[h][r] = invd[h][quad * 4 + r];

    // PV accumulators: wave wv owns rows i0+wv*4..+3; lane owns e = lane*8..+8
    const int e0 = lane * 8;
    const int ib = wv * 4;
    float acc[4][8] = {};
    float mac[4][8] = {};
    float cl[4] = {0.f, 0.f, 0.f, 0.f};

    for (int half = 0; half < 2; ++half) {
        if (tid == 0) flagH = 0;
        __syncthreads();

        // ---- B1: ew tile for j in [half*1024, half*1024+1024) ----
        int localAny = 0;
        for (int jt = 0; jt < 16; ++jt) {
            const int j0 = half * 1024 + wv * 256 + jt * 16;
            float ws[4] = {0.f, 0.f, 0.f, 0.f};
            #pragma unroll
            for (int h = 0; h < HH; ++h) {
                const short8 bk0 = *reinterpret_cast<const short8*>(
                    kws + (gb + j0 + m16) * EE + h * 64 + quad * 8);
                const short8 bk1 = *reinterpret_cast<const short8*>(
                    kws + (gb + j0 + m16) * EE + h * 64 + 32 + quad * 8);
                f32x4 c = {0.f, 0.f, 0.f, 0.f};
                c = __builtin_amdgcn_mfma_f32_16x16x32_bf16(aq[h][0], bk0, c, 0, 0, 0);
                c = __builtin_amdgcn_mfma_f32_16x16x32_bf16(aq[h][1], bk1, c, 0, 0, 0);
                #pragma unroll
                for (int r = 0; r < 4; ++r) ws[r] += __expf(c[r] * scale) * idv[h][r];
            }
            const int jloc = wv * 256 + jt * 16 + m16;
            #pragma unroll
            for (int r = 0; r < 4; ++r) {
                const float w = ws[r] * 0.125f;   // head mean
                if (w > 0.1f) { cl[r] += 1.f; localAny = 1; }
                ewL[quad * 4 + r][jloc] = __float2bfloat16(w);
            }
        }
        if (localAny) flagH = 1;
        __syncthreads();

        // ---- B2: attended (+ masked aggregated if this half has neighbors) ----
        const bool doX = (flagH != 0);
        for (int jj = 0; jj < 1024; jj += 2) {
            const int j = half * 1024 + jj;
            // two j at once: ew row reads as packed u32 (broadcast per wave)
            float w4a[4], w4b[4];
            #pragma unroll
            for (int ii = 0; ii < 4; ++ii) {
                const unsigned p = *reinterpret_cast<const unsigned*>(&ewL[ib + ii][jj]);
                w4a[ii] = bflo(p);
                w4b[ii] = bfhi(p);
            }
            const uint4 uva = *reinterpret_cast<const uint4*>(vws + (gb + j) * EE + e0);
            const uint4 uvb = *reinterpret_cast<const uint4*>(vws + (gb + j + 1) * EE + e0);
            float va[8] = { bflo(uva.x), bfhi(uva.x), bflo(uva.y), bfhi(uva.y),
                            bflo(uva.z), bfhi(uva.z), bflo(uva.w), bfhi(uva.w) };
            float vb[8] = { bflo(uvb.x), bfhi(uvb.x), bflo(uvb.y), bfhi(uvb.y),
                            bflo(uvb.z), bfhi(uvb.z), bflo(uvb.w), bfhi(uvb.w) };
            #pragma unroll
            for (int ii = 0; ii < 4; ++ii)
                #pragma unroll
                for (int e = 0; e < 8; ++e)
                    acc[ii][e] += w4a[ii] * va[e] + w4b[ii] * vb[e];
            if (doX) {
                const float4 xa0 = *reinterpret_cast<const float4*>(x + (gb + j) * EE + e0);
                const float4 xa1 = *reinterpret_cast<const float4*>(x + (gb + j) * EE + e0 + 4);
                const float4 xb0 = *reinterpret_cast<const float4*>(x + (gb + j + 1) * EE + e0);
                const float4 xb1 = *reinterpret_cast<const float4*>(x + (gb + j + 1) * EE + e0 + 4);
                const float xaf[8] = { xa0.x, xa0.y, xa0.z, xa0.w, xa1.x, xa1.y, xa1.z, xa1.w };
                const float xbf[8] = { xb0.x, xb0.y, xb0.z, xb0.w, xb1.x, xb1.y, xb1.z, xb1.w };
                #pragma unroll
                for (int ii = 0; ii < 4; ++ii) {
                    const float mwa = (w4a[ii] > 0.1f) ? w4a[ii] : 0.f;
                    const float mwb = (w4b[ii] > 0.1f) ? w4b[ii] : 0.f;
                    #pragma unroll
                    for (int e = 0; e < 8; ++e)
                        mac[ii][e] += mwa * xaf[e] + mwb * xbf[e];
                }
            }
        }
        __syncthreads();   // ewL reusable next half
    }

    // neighbor counts -> invn (cl counted per-lane over its B1 (i,j) coverage)
    #pragma unroll
    for (int off = 1; off <= 8; off <<= 1)
        #pragma unroll
        for (int r = 0; r < 4; ++r) cl[r] += __shfl_xor(cl[r], off, 64);
    if (m16 == 0)
        #pragma unroll
        for (int r = 0; r < 4; ++r) dpart[wv][0][quad * 4 + r] = cl[r];
    __syncthreads();
    if (tid < TI) {
        const float c = dpart[0][0][tid] + dpart[1][0][tid]
                      + dpart[2][0][tid] + dpart[3][0][tid];
        invnL[tid] = 1.0f / fmaxf(c, 1.0f);
    }
    __syncthreads();

    // u1 = attended + messages -> overwrite own q rows (bf16, packed stores)
    #pragma unroll
    for (int ii = 0; ii < 4; ++ii) {
        const int i = ib + ii;
        const float invn = invnL[i];
        unsigned pw[4];
        #pragma unroll
        for (int p = 0; p < 4; ++p) {
            const unsigned lo = f2bf(acc[ii][2*p]   + mac[ii][2*p]   * invn);
            const unsigned hi = f2bf(acc[ii][2*p+1] + mac[ii][2*p+1] * invn);
            pw[p] = lo | (hi << 16);
        }
        uint4 st; st.x = pw[0]; st.y = pw[1]; st.z = pw[2]; st.w = pw[3];
        *reinterpret_cast<uint4*>(qu + (g0 + i) * EE + e0) = st;
    }
}

extern "C" void kernel_launch(void* const* d_in, const int* in_sizes, int n_in,
                              void* d_out, int out_size, void* d_ws, size_t ws_size,
                              hipStream_t stream)
{
    const float* x   = (const float*)d_in[0];
    const float* Wq  = (const float*)d_in[1];
    const float* bq  = (const float*)d_in[2];
    const float* Wk  = (const float*)d_in[3];
    const float* bk  = (const float*)d_in[4];
    const float* Wv  = (const float*)d_in[5];
    const float* bv  = (const float*)d_in[6];
    const float* Wm1 = (const float*)d_in[7];
    const float* bm1 = (const float*)d_in[8];
    const float* Wm2 = (const float*)d_in[9];
    const float* bm2 = (const float*)d_in[10];
    const float* Wo  = (const float*)d_in[11];
    const float* bo  = (const float*)d_in[12];

    // ws: 8 MB (qb, kb). v lives bf16 in d_out scratch (dead before final GEMM).
    char* ws = (char*)d_ws;
    const size_t MB = 1024 * 1024;
    __hip_bfloat16* qb = (__hip_bfloat16*)(ws + 0);        // q -> u1 -> t   4MB
    __hip_bfloat16* kb = (__hip_bfloat16*)(ws + 4*MB);     // k -> hm        4MB
    __hip_bfloat16* vb = (__hip_bfloat16*)d_out;           // v bf16 scratch 4MB

    dim3 blk(256, 1, 1);
    dim3 gg(EE / 64, NN / 64, 1);

    gemm_bt<0,1,0><<<gg, blk, 0, stream>>>(x, Wq, bq, qb, EE);
    gemm_bt<0,1,0><<<gg, blk, 0, stream>>>(x, Wk, bk, kb, EE);
    gemm_bt<0,1,0><<<gg, blk, 0, stream>>>(x, Wv, bv, vb, EE);
    attn_fused<<<dim3(SS / TI, BB, 1), blk, 0, stream>>>(qb, kb, vb, x);
    gemm_bt<1,1,0><<<gg, blk, 0, stream>>>(x, Wm1, bm1, kb, EE + HH);   // hm
    gemm_bt<2,0,0><<<gg, blk, 0, stream>>>(kb, Wm2, bm2, qb, EE);       // t = MLP2 + u1
    gemm_bt<0,0,1><<<gg, blk, 0, stream>>>(qb, Wo, bo, d_out, EE);      // out f32
}

// Round 8
// 866.518 us; speedup vs baseline: 2.8098x; 1.0732x over previous
//
#include <hip/hip_runtime.h>
#include <hip/hip_bf16.h>
#include <math.h>

#define BB 2
#define SS 2048
#define EE 512
#define HH 8
#define NN (BB*SS)
#define TI 16
#define JC1 8   // K1 j-chunks (256 j each)
#define JC2 4   // K2 j-chunks (512 j each)

typedef __attribute__((ext_vector_type(8))) short short8;
typedef __attribute__((ext_vector_type(4))) float f32x4;

__device__ __forceinline__ float bflo(unsigned u){ return __uint_as_float(u << 16); }
__device__ __forceinline__ float bfhi(unsigned u){ return __uint_as_float(u & 0xffff0000u); }
__device__ __forceinline__ unsigned f2bf(float f){
    unsigned u = __float_as_uint(f);
    u += 0x7fffu + ((u >> 16) & 1u);
    return u >> 16;
}

// ---------------- GEMM (unchanged, r6-verified) ----------------
template<int MODE, int AF32, int CF32>
__global__ __launch_bounds__(256) void gemm_bt(
    const void* __restrict__ Av,
    const float* __restrict__ W,
    const float* __restrict__ bias,
    void* __restrict__ Cv,
    int ldb)
{
    __shared__ float As[64][65];
    __shared__ float Bs[64][65];
    const int tid = threadIdx.x;
    const int col0 = blockIdx.x * 64;
    const int row0 = blockIdx.y * 64;
    const int tx = tid & 15;
    const int ty = tid >> 4;
    float acc[4][4] = {};

    for (int k0 = 0; k0 < 512; k0 += 64) {
        if (AF32) {
            const float* Af = (const float*)Av;
            #pragma unroll
            for (int l = 0; l < 4; ++l) {
                const int base = (tid + l * 256) * 4;
                const int r = base >> 6, c = base & 63;
                const float4 f = *reinterpret_cast<const float4*>(
                    Af + (size_t)(row0 + r) * EE + k0 + c);
                As[r][c+0] = f.x; As[r][c+1] = f.y; As[r][c+2] = f.z; As[r][c+3] = f.w;
            }
        } else {
            const __hip_bfloat16* Ab = (const __hip_bfloat16*)Av;
            #pragma unroll
            for (int l = 0; l < 2; ++l) {
                const int base = (tid + l * 256) * 8;
                const int r = base >> 6, c = base & 63;
                const uint4 ua = *reinterpret_cast<const uint4*>(
                    Ab + (size_t)(row0 + r) * EE + k0 + c);
                As[r][c+0] = bflo(ua.x); As[r][c+1] = bfhi(ua.x);
                As[r][c+2] = bflo(ua.y); As[r][c+3] = bfhi(ua.y);
                As[r][c+4] = bflo(ua.z); As[r][c+5] = bfhi(ua.z);
                As[r][c+6] = bflo(ua.w); As[r][c+7] = bfhi(ua.w);
            }
        }
        #pragma unroll
        for (int l = 0; l < 4; ++l) {
            const int base = (tid + l * 256) * 4;
            const int r = base >> 6, c = base & 63;
            const float4 f = *reinterpret_cast<const float4*>(
                W + (size_t)(col0 + r) * ldb + k0 + c);
            Bs[r][c+0] = f.x; Bs[r][c+1] = f.y; Bs[r][c+2] = f.z; Bs[r][c+3] = f.w;
        }
        __syncthreads();
        #pragma unroll
        for (int kk = 0; kk < 64; ++kk) {
            float a[4], bv[4];
            #pragma unroll
            for (int i = 0; i < 4; ++i) a[i] = As[ty*4+i][kk];
            #pragma unroll
            for (int j = 0; j < 4; ++j) bv[j] = Bs[tx*4+j][kk];
            #pragma unroll
            for (int i = 0; i < 4; ++i)
                #pragma unroll
                for (int j = 0; j < 4; ++j)
                    acc[i][j] += a[i] * bv[j];
        }
        __syncthreads();
    }

    if (MODE == 1) {
        #pragma unroll
        for (int j = 0; j < 4; ++j) {
            float ts = 0.f;
            #pragma unroll
            for (int h = 0; h < 8; ++h)
                ts += W[(size_t)(col0 + tx*4 + j) * ldb + 512 + h];
            ts *= (1.0f / (float)SS);
            #pragma unroll
            for (int i = 0; i < 4; ++i) acc[i][j] += ts;
        }
    }

    #pragma unroll
    for (int i = 0; i < 4; ++i) {
        const int gr = row0 + ty*4 + i;
        #pragma unroll
        for (int j = 0; j < 4; ++j) {
            const int gc = col0 + tx*4 + j;
            const size_t ci = (size_t)gr * EE + gc;
            float c = acc[i][j] + bias[gc];
            if (MODE == 1) c = 0.5f * c * (1.0f + erff(c * 0.70710678118654752f));
            if (MODE == 2) c += (float)((const __hip_bfloat16*)Cv)[ci];
            if (CF32) ((float*)Cv)[ci] = c;
            else      ((__hip_bfloat16*)Cv)[ci] = __float2bfloat16(c);
        }
    }
}

// ---------------- K1: partial softmax denominators ----------------
// grid (JC1, SS/TI, BB), 256 thr. dnP[jc][b][i][h] (f32, fully written).
__global__ __launch_bounds__(256) void attn_denoms(
    const __hip_bfloat16* __restrict__ qws,
    const __hip_bfloat16* __restrict__ kws,
    float* __restrict__ dnP)
{
    __shared__ float dpart[4][HH][TI];
    const int tid = threadIdx.x;
    const int wv = tid >> 6, lane = tid & 63, quad = lane >> 4, m16 = lane & 15;
    const int jc = blockIdx.x;
    const int i0 = blockIdx.y * TI;
    const int b  = blockIdx.z;
    const size_t g0 = (size_t)b * SS + i0;
    const size_t gb = (size_t)b * SS;
    const float scale = 0.125f;

    short8 aq[HH][2];
    #pragma unroll
    for (int h = 0; h < HH; ++h)
        #pragma unroll
        for (int ks = 0; ks < 2; ++ks)
            aq[h][ks] = *reinterpret_cast<const short8*>(
                qws + (g0 + m16) * EE + h * 64 + ks * 32 + quad * 8);

    #pragma unroll
    for (int h = 0; h < HH; ++h) {
        float dp[4] = {0.f, 0.f, 0.f, 0.f};
        #pragma unroll
        for (int jt = 0; jt < 4; ++jt) {
            const int j0 = jc * 256 + wv * 64 + jt * 16;
            const short8 bk0 = *reinterpret_cast<const short8*>(
                kws + (gb + j0 + m16) * EE + h * 64 + quad * 8);
            const short8 bk1 = *reinterpret_cast<const short8*>(
                kws + (gb + j0 + m16) * EE + h * 64 + 32 + quad * 8);
            f32x4 c = {0.f, 0.f, 0.f, 0.f};
            c = __builtin_amdgcn_mfma_f32_16x16x32_bf16(aq[h][0], bk0, c, 0, 0, 0);
            c = __builtin_amdgcn_mfma_f32_16x16x32_bf16(aq[h][1], bk1, c, 0, 0, 0);
            #pragma unroll
            for (int r = 0; r < 4; ++r) dp[r] += __expf(c[r] * scale);
        }
        #pragma unroll
        for (int off = 1; off <= 8; off <<= 1)
            #pragma unroll
            for (int r = 0; r < 4; ++r) dp[r] += __shfl_xor(dp[r], off, 64);
        if (m16 == 0)
            #pragma unroll
            for (int r = 0; r < 4; ++r) dpart[wv][h][quad * 4 + r] = dp[r];
    }
    __syncthreads();
    if (tid < HH * TI) {
        const int h = tid >> 4, i = tid & 15;
        dnP[((size_t)(jc * BB + b) * SS + i0 + i) * HH + h] =
            dpart[0][h][i] + dpart[1][h][i] + dpart[2][h][i] + dpart[3][h][i];
    }
}

// ---------------- K2: ew chunk + partial PV ----------------
// grid (JC2, SS/TI, BB), 256 thr. slabs[jc][b*S+i][e] bf16; cnt atomicAdd (int-valued).
__global__ __launch_bounds__(256) void attn_pv(
    const __hip_bfloat16* __restrict__ qws,
    const __hip_bfloat16* __restrict__ kws,
    const __hip_bfloat16* __restrict__ vws,
    const float* __restrict__ dnP,
    float* __restrict__ cnt,
    __hip_bfloat16* __restrict__ slabs)
{
    __shared__ __hip_bfloat16 ewL[TI][512];   // 16 KB
    __shared__ float invd[HH][TI];
    __shared__ float cpart[4][TI];
    const int tid = threadIdx.x;
    const int wv = tid >> 6, lane = tid & 63, quad = lane >> 4, m16 = lane & 15;
    const int jc = blockIdx.x;
    const int i0 = blockIdx.y * TI;
    const int b  = blockIdx.z;
    const size_t g0 = (size_t)b * SS + i0;
    const size_t gb = (size_t)b * SS;
    const float scale = 0.125f;

    if (tid < HH * TI) {
        const int h = tid >> 4, i = tid & 15;
        float s = 0.f;
        #pragma unroll
        for (int c = 0; c < JC1; ++c)
            s += dnP[((size_t)(c * BB + b) * SS + i0 + i) * HH + h];
        invd[h][i] = 1.0f / s;
    }
    __syncthreads();

    short8 aq[HH][2];
    #pragma unroll
    for (int h = 0; h < HH; ++h)
        #pragma unroll
        for (int ks = 0; ks < 2; ++ks)
            aq[h][ks] = *reinterpret_cast<const short8*>(
                qws + (g0 + m16) * EE + h * 64 + ks * 32 + quad * 8);

    float idv[HH][4];
    #pragma unroll
    for (int h = 0; h < HH; ++h)
        #pragma unroll
        for (int r = 0; r < 4; ++r) idv[h][r] = invd[h][quad * 4 + r];

    float cl[4] = {0.f, 0.f, 0.f, 0.f};
    for (int jt = 0; jt < 8; ++jt) {
        const int j0 = jc * 512 + wv * 128 + jt * 16;
        float wsum[4] = {0.f, 0.f, 0.f, 0.f};
        #pragma unroll
        for (int h = 0; h < HH; ++h) {
            const short8 bk0 = *reinterpret_cast<const short8*>(
                kws + (gb + j0 + m16) * EE + h * 64 + quad * 8);
            const short8 bk1 = *reinterpret_cast<const short8*>(
                kws + (gb + j0 + m16) * EE + h * 64 + 32 + quad * 8);
            f32x4 c = {0.f, 0.f, 0.f, 0.f};
            c = __builtin_amdgcn_mfma_f32_16x16x32_bf16(aq[h][0], bk0, c, 0, 0, 0);
            c = __builtin_amdgcn_mfma_f32_16x16x32_bf16(aq[h][1], bk1, c, 0, 0, 0);
            #pragma unroll
            for (int r = 0; r < 4; ++r) wsum[r] += __expf(c[r] * scale) * idv[h][r];
        }
        const int jloc = wv * 128 + jt * 16 + m16;
        #pragma unroll
        for (int r = 0; r < 4; ++r) {
            const float w = wsum[r] * 0.125f;   // head mean
            if (w > 0.1f) cl[r] += 1.f;
            ewL[quad * 4 + r][jloc] = __float2bfloat16(w);
        }
    }
    #pragma unroll
    for (int off = 1; off <= 8; off <<= 1)
        #pragma unroll
        for (int r = 0; r < 4; ++r) cl[r] += __shfl_xor(cl[r], off, 64);
    if (m16 == 0)
        #pragma unroll
        for (int r = 0; r < 4; ++r) cpart[wv][quad * 4 + r] = cl[r];
    __syncthreads();
    if (tid < TI) {
        const float c = cpart[0][tid] + cpart[1][tid] + cpart[2][tid] + cpart[3][tid];
        if (c != 0.f) atomicAdd(&cnt[g0 + tid], c);   // integer-valued: deterministic
    }

    // partial PV over this block's 512-j chunk
    const int e0 = lane * 8;
    const int ib = wv * 4;
    float acc[4][8] = {};
    for (int jj = 0; jj < 512; jj += 2) {
        const int j = jc * 512 + jj;
        float w4a[4], w4b[4];
        #pragma unroll
        for (int ii = 0; ii < 4; ++ii) {
            const unsigned p = *reinterpret_cast<const unsigned*>(&ewL[ib + ii][jj]);
            w4a[ii] = bflo(p);
            w4b[ii] = bfhi(p);
        }
        const uint4 uva = *reinterpret_cast<const uint4*>(vws + (gb + j) * EE + e0);
        const uint4 uvb = *reinterpret_cast<const uint4*>(vws + (gb + j + 1) * EE + e0);
        const float va[8] = { bflo(uva.x), bfhi(uva.x), bflo(uva.y), bfhi(uva.y),
                              bflo(uva.z), bfhi(uva.z), bflo(uva.w), bfhi(uva.w) };
        const float vb8[8] = { bflo(uvb.x), bfhi(uvb.x), bflo(uvb.y), bfhi(uvb.y),
                               bflo(uvb.z), bfhi(uvb.z), bflo(uvb.w), bfhi(uvb.w) };
        #pragma unroll
        for (int ii = 0; ii < 4; ++ii)
            #pragma unroll
            for (int e = 0; e < 8; ++e)
                acc[ii][e] += w4a[ii] * va[e] + w4b[ii] * vb8[e];
    }
    #pragma unroll
    for (int ii = 0; ii < 4; ++ii) {
        unsigned pw[4];
        #pragma unroll
        for (int p = 0; p < 4; ++p)
            pw[p] = f2bf(acc[ii][2*p]) | (f2bf(acc[ii][2*p+1]) << 16);
        uint4 st; st.x = pw[0]; st.y = pw[1]; st.z = pw[2]; st.w = pw[3];
        *reinterpret_cast<uint4*>(
            slabs + ((size_t)jc * NN + g0 + ib + ii) * EE + e0) = st;
    }
}

// ---------------- K3: finalize u1 = sum slabs (+ exact rare masked path) ----------------
// grid (NN), 256 thr. Overwrites qu row with u1.
__global__ __launch_bounds__(256) void attn_final(
    __hip_bfloat16* qu,
    const __hip_bfloat16* __restrict__ kws,
    const float* __restrict__ x,
    const float* __restrict__ dnP,
    const float* __restrict__ cnt,
    const __hip_bfloat16* __restrict__ slabs)
{
    __shared__ float qrowL[EE];
    __shared__ float wj[SS];
    const int row = blockIdx.x;
    const int b = row >> 11;
    const int tid = threadIdx.x;
    const size_t gb = (size_t)b * SS;
    const int e = tid * 2;
    const float c = cnt[row];

    float lo = 0.f, hi = 0.f;
    #pragma unroll
    for (int jc = 0; jc < JC2; ++jc) {
        const unsigned p = *reinterpret_cast<const unsigned*>(
            slabs + ((size_t)jc * NN + row) * EE + e);
        lo += bflo(p); hi += bfhi(p);
    }

    float mlo = 0.f, mhi = 0.f;
    if (c > 0.f) {   // block-uniform rare path: exact masked aggregation
        const float scale = 0.125f;
        for (int l = tid; l < EE; l += 256) qrowL[l] = (float)qu[(size_t)row * EE + l];
        __syncthreads();
        float invd8[HH];
        #pragma unroll
        for (int h = 0; h < HH; ++h) {
            float s = 0.f;
            #pragma unroll
            for (int cc = 0; cc < JC1; ++cc)
                s += dnP[((size_t)(cc * BB + b) * SS + (row & (SS-1))) * HH + h];
            invd8[h] = 1.0f / s;
        }
        for (int j = tid; j < SS; j += 256) {
            float wsum = 0.f;
            #pragma unroll
            for (int h = 0; h < HH; ++h) {
                const __hip_bfloat16* kr = kws + (gb + j) * EE + h * 64;
                float s = 0.f;
                for (int t = 0; t < 64; ++t) s += qrowL[h*64 + t] * (float)kr[t];
                wsum += __expf(s * scale) * invd8[h];
            }
            wj[j] = wsum * 0.125f;
        }
        __syncthreads();
        const float invn = 1.0f / fmaxf(c, 1.0f);
        for (int j = 0; j < SS; ++j) {
            const float w = wj[j];
            if (w > 0.1f) {
                mlo += w * x[(gb + j) * EE + e];
                mhi += w * x[(gb + j) * EE + e + 1];
            }
        }
        mlo *= invn; mhi *= invn;
    }
    *reinterpret_cast<unsigned*>(qu + (size_t)row * EE + e) =
        f2bf(lo + mlo) | (f2bf(hi + mhi) << 16);
}

__global__ void zero_f32(float* p) { p[blockIdx.x * 256 + threadIdx.x] = 0.f; }

// ---------------- fallback: r7 single-kernel attention (proven) ----------------
__global__ __launch_bounds__(256) void attn_fused(
    __hip_bfloat16* qu,
    const __hip_bfloat16* __restrict__ kws,
    const __hip_bfloat16* __restrict__ vws,
    const float* __restrict__ x)
{
    __shared__ __hip_bfloat16 ewL[TI][1024];
    __shared__ float dpart[4][HH][TI];
    __shared__ float invd[HH][TI];
    __shared__ float invnL[TI];
    __shared__ int   flagH;

    const int tid  = threadIdx.x;
    const int wv   = tid >> 6;
    const int lane = tid & 63;
    const int quad = lane >> 4;
    const int m16  = lane & 15;
    const int b    = blockIdx.y;
    const int i0   = blockIdx.x * TI;
    const size_t g0 = (size_t)b * SS + i0;
    const size_t gb = (size_t)b * SS;
    const float scale = 0.125f;

    short8 aq[HH][2];
    #pragma unroll
    for (int h = 0; h < HH; ++h)
        #pragma unroll
        for (int ks = 0; ks < 2; ++ks)
            aq[h][ks] = *reinterpret_cast<const short8*>(
                qu + (g0 + m16) * EE + h * 64 + ks * 32 + quad * 8);

    #pragma unroll
    for (int h = 0; h < HH; ++h) {
        float dp[4] = {0.f, 0.f, 0.f, 0.f};
        for (int jt = 0; jt < 32; ++jt) {
            const int j0 = wv * 512 + jt * 16;
            const short8 bk0 = *reinterpret_cast<const short8*>(
                kws + (gb + j0 + m16) * EE + h * 64 + quad * 8);
            const short8 bk1 = *reinterpret_cast<const short8*>(
                kws + (gb + j0 + m16) * EE + h * 64 + 32 + quad * 8);
            f32x4 c = {0.f, 0.f, 0.f, 0.f};
            c = __builtin_amdgcn_mfma_f32_16x16x32_bf16(aq[h][0], bk0, c, 0, 0, 0);
            c = __builtin_amdgcn_mfma_f32_16x16x32_bf16(aq[h][1], bk1, c, 0, 0, 0);
            #pragma unroll
            for (int r = 0; r < 4; ++r) dp[r] += __expf(c[r] * scale);
        }
        #pragma unroll
        for (int off = 1; off <= 8; off <<= 1)
            #pragma unroll
            for (int r = 0; r < 4; ++r) dp[r] += __shfl_xor(dp[r], off, 64);
        if (m16 == 0)
            #pragma unroll
            for (int r = 0; r < 4; ++r) dpart[wv][h][quad * 4 + r] = dp[r];
    }
    __syncthreads();
    if (tid < HH * TI) {
        const int h = tid >> 4, i = tid & 15;
        invd[h][i] = 1.0f / (dpart[0][h][i] + dpart[1][h][i]
                           + dpart[2][h][i] + dpart[3][h][i]);
    }
    __syncthreads();

    float idv[HH][4];
    #pragma unroll
    for (int h = 0; h < HH; ++h)
        #pragma unroll
        for (int r = 0; r < 4; ++r) idv[h][r] = invd[h][quad * 4 + r];

    const int e0 = lane * 8;
    const int ib = wv * 4;
    float acc[4][8] = {};
    float mac[4][8] = {};
    float cl[4] = {0.f, 0.f, 0.f, 0.f};

    for (int half = 0; half < 2; ++half) {
        if (tid == 0) flagH = 0;
        __syncthreads();
        int localAny = 0;
        for (int jt = 0; jt < 16; ++jt) {
            const int j0 = half * 1024 + wv * 256 + jt * 16;
            float ws[4] = {0.f, 0.f, 0.f, 0.f};
            #pragma unroll
            for (int h = 0; h < HH; ++h) {
                const short8 bk0 = *reinterpret_cast<const short8*>(
                    kws + (gb + j0 + m16) * EE + h * 64 + quad * 8);
                const short8 bk1 = *reinterpret_cast<const short8*>(
                    kws + (gb + j0 + m16) * EE + h * 64 + 32 + quad * 8);
                f32x4 c = {0.f, 0.f, 0.f, 0.f};
                c = __builtin_amdgcn_mfma_f32_16x16x32_bf16(aq[h][0], bk0, c, 0, 0, 0);
                c = __builtin_amdgcn_mfma_f32_16x16x32_bf16(aq[h][1], bk1, c, 0, 0, 0);
                #pragma unroll
                for (int r = 0; r < 4; ++r) ws[r] += __expf(c[r] * scale) * idv[h][r];
            }
            const int jloc = wv * 256 + jt * 16 + m16;
            #pragma unroll
            for (int r = 0; r < 4; ++r) {
                const float w = ws[r] * 0.125f;
                if (w > 0.1f) { cl[r] += 1.f; localAny = 1; }
                ewL[quad * 4 + r][jloc] = __float2bfloat16(w);
            }
        }
        if (localAny) flagH = 1;
        __syncthreads();

        const bool doX = (flagH != 0);
        for (int jj = 0; jj < 1024; jj += 2) {
            const int j = half * 1024 + jj;
            float w4a[4], w4b[4];
            #pragma unroll
            for (int ii = 0; ii < 4; ++ii) {
                const unsigned p = *reinterpret_cast<const unsigned*>(&ewL[ib + ii][jj]);
                w4a[ii] = bflo(p);
                w4b[ii] = bfhi(p);
            }
            const uint4 uva = *reinterpret_cast<const uint4*>(vws + (gb + j) * EE + e0);
            const uint4 uvb = *reinterpret_cast<const uint4*>(vws + (gb + j + 1) * EE + e0);
            float va[8] = { bflo(uva.x), bfhi(uva.x), bflo(uva.y), bfhi(uva.y),
                            bflo(uva.z), bfhi(uva.z), bflo(uva.w), bfhi(uva.w) };
            float vb[8] = { bflo(uvb.x), bfhi(uvb.x), bflo(uvb.y), bfhi(uvb.y),
                            bflo(uvb.z), bfhi(uvb.z), bflo(uvb.w), bfhi(uvb.w) };
            #pragma unroll
            for (int ii = 0; ii < 4; ++ii)
                #pragma unroll
                for (int e = 0; e < 8; ++e)
                    acc[ii][e] += w4a[ii] * va[e] + w4b[ii] * vb[e];
            if (doX) {
                const float4 xa0 = *reinterpret_cast<const float4*>(x + (gb + j) * EE + e0);
                const float4 xa1 = *reinterpret_cast<const float4*>(x + (gb + j) * EE + e0 + 4);
                const float4 xb0 = *reinterpret_cast<const float4*>(x + (gb + j + 1) * EE + e0);
                const float4 xb1 = *reinterpret_cast<const float4*>(x + (gb + j + 1) * EE + e0 + 4);
                const float xaf[8] = { xa0.x, xa0.y, xa0.z, xa0.w, xa1.x, xa1.y, xa1.z, xa1.w };
                const float xbf[8] = { xb0.x, xb0.y, xb0.z, xb0.w, xb1.x, xb1.y, xb1.z, xb1.w };
                #pragma unroll
                for (int ii = 0; ii < 4; ++ii) {
                    const float mwa = (w4a[ii] > 0.1f) ? w4a[ii] : 0.f;
                    const float mwb = (w4b[ii] > 0.1f) ? w4b[ii] : 0.f;
                    #pragma unroll
                    for (int e = 0; e < 8; ++e)
                        mac[ii][e] += mwa * xaf[e] + mwb * xbf[e];
                }
            }
        }
        __syncthreads();
    }

    #pragma unroll
    for (int off = 1; off <= 8; off <<= 1)
        #pragma unroll
        for (int r = 0; r < 4; ++r) cl[r] += __shfl_xor(cl[r], off, 64);
    if (m16 == 0)
        #pragma unroll
        for (int r = 0; r < 4; ++r) dpart[wv][0][quad * 4 + r] = cl[r];
    __syncthreads();
    if (tid < TI) {
        const float c = dpart[0][0][tid] + dpart[1][0][tid]
                      + dpart[2][0][tid] + dpart[3][0][tid];
        invnL[tid] = 1.0f / fmaxf(c, 1.0f);
    }
    __syncthreads();

    #pragma unroll
    for (int ii = 0; ii < 4; ++ii) {
        const int i = ib + ii;
        const float invn = invnL[i];
        unsigned pw[4];
        #pragma unroll
        for (int p = 0; p < 4; ++p) {
            const unsigned lo = f2bf(acc[ii][2*p]   + mac[ii][2*p]   * invn);
            const unsigned hi = f2bf(acc[ii][2*p+1] + mac[ii][2*p+1] * invn);
            pw[p] = lo | (hi << 16);
        }
        uint4 st; st.x = pw[0]; st.y = pw[1]; st.z = pw[2]; st.w = pw[3];
        *reinterpret_cast<uint4*>(qu + (g0 + i) * EE + e0) = st;
    }
}

extern "C" void kernel_launch(void* const* d_in, const int* in_sizes, int n_in,
                              void* d_out, int out_size, void* d_ws, size_t ws_size,
                              hipStream_t stream)
{
    const float* x   = (const float*)d_in[0];
    const float* Wq  = (const float*)d_in[1];
    const float* bq  = (const float*)d_in[2];
    const float* Wk  = (const float*)d_in[3];
    const float* bk  = (const float*)d_in[4];
    const float* Wv  = (const float*)d_in[5];
    const float* bv  = (const float*)d_in[6];
    const float* Wm1 = (const float*)d_in[7];
    const float* bm1 = (const float*)d_in[8];
    const float* Wm2 = (const float*)d_in[9];
    const float* bm2 = (const float*)d_in[10];
    const float* Wo  = (const float*)d_in[11];
    const float* bo  = (const float*)d_in[12];

    char* ws = (char*)d_ws;
    const size_t MB = 1024 * 1024;
    const bool fast = (ws_size >= 30 * MB);

    __hip_bfloat16* qb = (__hip_bfloat16*)(ws + 0);        // q -> u1 -> t   4MB
    __hip_bfloat16* kb = (__hip_bfloat16*)(ws + 4*MB);     // k -> hm        4MB
    // fast path layout
    __hip_bfloat16* vbF   = (__hip_bfloat16*)(ws + 8*MB);  // v bf16         4MB
    __hip_bfloat16* slabs = (__hip_bfloat16*)(ws + 12*MB); // JC2 PV slabs  16MB
    float* dnP = (float*)(ws + 28*MB);                     // denom partials 1MB
    float* cnt = (float*)(ws + 29*MB);                     // neighbor cnt  16KB
    // fallback: v in d_out scratch
    __hip_bfloat16* vb = fast ? vbF : (__hip_bfloat16*)d_out;

    dim3 blk(256, 1, 1);
    dim3 gg(EE / 64, NN / 64, 1);

    gemm_bt<0,1,0><<<gg, blk, 0, stream>>>(x, Wq, bq, qb, EE);
    gemm_bt<0,1,0><<<gg, blk, 0, stream>>>(x, Wk, bk, kb, EE);
    gemm_bt<0,1,0><<<gg, blk, 0, stream>>>(x, Wv, bv, vb, EE);
    if (fast) {
        zero_f32<<<dim3(NN / 256), blk, 0, stream>>>(cnt);
        attn_denoms<<<dim3(JC1, SS / TI, BB), blk, 0, stream>>>(qb, kb, dnP);
        attn_pv<<<dim3(JC2, SS / TI, BB), blk, 0, stream>>>(qb, kb, vb, dnP, cnt, slabs);
        attn_final<<<dim3(NN, 1, 1), blk, 0, stream>>>(qb, kb, x, dnP, cnt, slabs);
    } else {
        attn_fused<<<dim3(SS / TI, BB, 1), blk, 0, stream>>>(qb, kb, vb, x);
    }
    gemm_bt<1,1,0><<<gg, blk, 0, stream>>>(x, Wm1, bm1, kb, EE + HH);   // hm
    gemm_bt<2,0,0><<<gg, blk, 0, stream>>>(kb, Wm2, bm2, qb, EE);       // t = MLP2 + u1
    gemm_bt<0,0,1><<<gg, blk, 0, stream>>>(qb, Wo, bo, d_out, EE);      // out f32
}

// Round 9
// 595.973 us; speedup vs baseline: 4.0853x; 1.4540x over previous
//
#include <hip/hip_runtime.h>
#include <hip/hip_bf16.h>
#include <math.h>

#define BB 2
#define SS 2048
#define EE 512
#define HH 8
#define NN (BB*SS)
#define TI 16
#define JC1 8   // K1 j-chunks (256 j each)
#define JC2 4   // K2 j-chunks (512 j each)

typedef __attribute__((ext_vector_type(8))) short short8;
typedef __attribute__((ext_vector_type(4))) float f32x4;

__device__ __forceinline__ float bflo(unsigned u){ return __uint_as_float(u << 16); }
__device__ __forceinline__ float bfhi(unsigned u){ return __uint_as_float(u & 0xffff0000u); }
__device__ __forceinline__ unsigned f2bf(float f){
    unsigned u = __float_as_uint(f);
    u += 0x7fffu + ((u >> 16) & 1u);
    return u >> 16;
}

// ---------------- GEMM ----------------
// C = A @ W^T (+bias). W/bias f32. 64x64 tiles, 256 thr, 4x4/thr, K=512.
// AF32: A f32 vs internal bf16.  CF32: C f32 vs bf16.
// CT=1 (only MODE 0): write C transposed per batch: vT[b][e][j] bf16.
// MODE 0 plain; MODE 1 ldb=520 + const-ef(1/S) tail + GELU; MODE 2 in-place +C_old
template<int MODE, int AF32, int CF32, int CT>
__global__ __launch_bounds__(256) void gemm_bt(
    const void* __restrict__ Av,
    const float* __restrict__ W,
    const float* __restrict__ bias,
    void* __restrict__ Cv,
    int ldb)
{
    __shared__ float As[64][65];
    __shared__ float Bs[64][65];
    const int tid = threadIdx.x;
    const int col0 = blockIdx.x * 64;
    const int row0 = blockIdx.y * 64;
    const int tx = tid & 15;
    const int ty = tid >> 4;
    float acc[4][4] = {};

    for (int k0 = 0; k0 < 512; k0 += 64) {
        if (AF32) {
            const float* Af = (const float*)Av;
            #pragma unroll
            for (int l = 0; l < 4; ++l) {
                const int base = (tid + l * 256) * 4;
                const int r = base >> 6, c = base & 63;
                const float4 f = *reinterpret_cast<const float4*>(
                    Af + (size_t)(row0 + r) * EE + k0 + c);
                As[r][c+0] = f.x; As[r][c+1] = f.y; As[r][c+2] = f.z; As[r][c+3] = f.w;
            }
        } else {
            const __hip_bfloat16* Ab = (const __hip_bfloat16*)Av;
            #pragma unroll
            for (int l = 0; l < 2; ++l) {
                const int base = (tid + l * 256) * 8;
                const int r = base >> 6, c = base & 63;
                const uint4 ua = *reinterpret_cast<const uint4*>(
                    Ab + (size_t)(row0 + r) * EE + k0 + c);
                As[r][c+0] = bflo(ua.x); As[r][c+1] = bfhi(ua.x);
                As[r][c+2] = bflo(ua.y); As[r][c+3] = bfhi(ua.y);
                As[r][c+4] = bflo(ua.z); As[r][c+5] = bfhi(ua.z);
                As[r][c+6] = bflo(ua.w); As[r][c+7] = bfhi(ua.w);
            }
        }
        #pragma unroll
        for (int l = 0; l < 4; ++l) {
            const int base = (tid + l * 256) * 4;
            const int r = base >> 6, c = base & 63;
            const float4 f = *reinterpret_cast<const float4*>(
                W + (size_t)(col0 + r) * ldb + k0 + c);
            Bs[r][c+0] = f.x; Bs[r][c+1] = f.y; Bs[r][c+2] = f.z; Bs[r][c+3] = f.w;
        }
        __syncthreads();
        #pragma unroll
        for (int kk = 0; kk < 64; ++kk) {
            float a[4], bv[4];
            #pragma unroll
            for (int i = 0; i < 4; ++i) a[i] = As[ty*4+i][kk];
            #pragma unroll
            for (int j = 0; j < 4; ++j) bv[j] = Bs[tx*4+j][kk];
            #pragma unroll
            for (int i = 0; i < 4; ++i)
                #pragma unroll
                for (int j = 0; j < 4; ++j)
                    acc[i][j] += a[i] * bv[j];
        }
        __syncthreads();
    }

    if (CT) {
        // stage (bias-added) tile to LDS, write transposed bf16: vT[b][e][j]
        #pragma unroll
        for (int i = 0; i < 4; ++i)
            #pragma unroll
            for (int j = 0; j < 4; ++j)
                As[ty*4+i][tx*4+j] = acc[i][j] + bias[col0 + tx*4 + j];
        __syncthreads();
        const int bb = row0 >> 11;
        const int j0 = row0 & (SS - 1);
        const int er = tid >> 2;            // 0..63 (e within tile)
        const int js = (tid & 3) * 16;      // 16 j per thread
        unsigned pk[8];
        #pragma unroll
        for (int p = 0; p < 8; ++p) {
            const unsigned lo = f2bf(As[js + 2*p][er]);
            const unsigned hi = f2bf(As[js + 2*p + 1][er]);
            pk[p] = lo | (hi << 16);
        }
        __hip_bfloat16* vT = (__hip_bfloat16*)Cv;
        uint4 s0; s0.x = pk[0]; s0.y = pk[1]; s0.z = pk[2]; s0.w = pk[3];
        uint4 s1; s1.x = pk[4]; s1.y = pk[5]; s1.z = pk[6]; s1.w = pk[7];
        __hip_bfloat16* dst = vT + ((size_t)(bb * EE + col0 + er)) * SS + j0 + js;
        *reinterpret_cast<uint4*>(dst) = s0;
        *reinterpret_cast<uint4*>(dst + 8) = s1;
        return;
    }

    if (MODE == 1) {
        #pragma unroll
        for (int j = 0; j < 4; ++j) {
            float ts = 0.f;
            #pragma unroll
            for (int h = 0; h < 8; ++h)
                ts += W[(size_t)(col0 + tx*4 + j) * ldb + 512 + h];
            ts *= (1.0f / (float)SS);
            #pragma unroll
            for (int i = 0; i < 4; ++i) acc[i][j] += ts;
        }
    }

    #pragma unroll
    for (int i = 0; i < 4; ++i) {
        const int gr = row0 + ty*4 + i;
        #pragma unroll
        for (int j = 0; j < 4; ++j) {
            const int gc = col0 + tx*4 + j;
            const size_t ci = (size_t)gr * EE + gc;
            float c = acc[i][j] + bias[gc];
            if (MODE == 1) c = 0.5f * c * (1.0f + erff(c * 0.70710678118654752f));
            if (MODE == 2) c += (float)((const __hip_bfloat16*)Cv)[ci];
            if (CF32) ((float*)Cv)[ci] = c;
            else      ((__hip_bfloat16*)Cv)[ci] = __float2bfloat16(c);
        }
    }
}

// ---------------- K1: partial softmax denominators ----------------
__global__ __launch_bounds__(256) void attn_denoms(
    const __hip_bfloat16* __restrict__ qws,
    const __hip_bfloat16* __restrict__ kws,
    float* __restrict__ dnP)
{
    __shared__ float dpart[4][HH][TI];
    const int tid = threadIdx.x;
    const int wv = tid >> 6, lane = tid & 63, quad = lane >> 4, m16 = lane & 15;
    const int jc = blockIdx.x;
    const int i0 = blockIdx.y * TI;
    const int b  = blockIdx.z;
    const size_t g0 = (size_t)b * SS + i0;
    const size_t gb = (size_t)b * SS;
    const float scale = 0.125f;

    #pragma unroll
    for (int h = 0; h < HH; ++h) {
        const short8 a0 = *reinterpret_cast<const short8*>(
            qws + (g0 + m16) * EE + h * 64 + quad * 8);
        const short8 a1 = *reinterpret_cast<const short8*>(
            qws + (g0 + m16) * EE + h * 64 + 32 + quad * 8);
        float dp[4] = {0.f, 0.f, 0.f, 0.f};
        #pragma unroll
        for (int jt = 0; jt < 4; ++jt) {
            const int j0 = jc * 256 + wv * 64 + jt * 16;
            const short8 bk0 = *reinterpret_cast<const short8*>(
                kws + (gb + j0 + m16) * EE + h * 64 + quad * 8);
            const short8 bk1 = *reinterpret_cast<const short8*>(
                kws + (gb + j0 + m16) * EE + h * 64 + 32 + quad * 8);
            f32x4 c = {0.f, 0.f, 0.f, 0.f};
            c = __builtin_amdgcn_mfma_f32_16x16x32_bf16(a0, bk0, c, 0, 0, 0);
            c = __builtin_amdgcn_mfma_f32_16x16x32_bf16(a1, bk1, c, 0, 0, 0);
            #pragma unroll
            for (int r = 0; r < 4; ++r) dp[r] += __expf(c[r] * scale);
        }
        #pragma unroll
        for (int off = 1; off <= 8; off <<= 1)
            #pragma unroll
            for (int r = 0; r < 4; ++r) dp[r] += __shfl_xor(dp[r], off, 64);
        if (m16 == 0)
            #pragma unroll
            for (int r = 0; r < 4; ++r) dpart[wv][h][quad * 4 + r] = dp[r];
    }
    __syncthreads();
    if (tid < HH * TI) {
        const int h = tid >> 4, i = tid & 15;
        dnP[((size_t)(jc * BB + b) * SS + i0 + i) * HH + h] =
            dpart[0][h][i] + dpart[1][h][i] + dpart[2][h][i] + dpart[3][h][i];
    }
}

// ---------------- K2: ew chunk + MFMA PV ----------------
// grid (JC2, SS/TI, BB). slabs[jc][row][e] bf16; cnt atomicAdd (integer-valued).
__global__ __launch_bounds__(256) void attn_pv(
    const __hip_bfloat16* __restrict__ qws,
    const __hip_bfloat16* __restrict__ kws,
    const __hip_bfloat16* __restrict__ vT,
    const float* __restrict__ dnP,
    float* __restrict__ cnt,
    __hip_bfloat16* __restrict__ slabs)
{
    __shared__ __hip_bfloat16 aqL[TI][520];   // Q tile (pad 520: 2-way banks = free)
    __shared__ __hip_bfloat16 ewL[TI][520];   // ew tile
    __shared__ float invd[HH][TI];
    __shared__ float cpart[4][TI];
    const int tid = threadIdx.x;
    const int wv = tid >> 6, lane = tid & 63, quad = lane >> 4, m16 = lane & 15;
    const int jc = blockIdx.x;
    const int i0 = blockIdx.y * TI;
    const int b  = blockIdx.z;
    const size_t g0 = (size_t)b * SS + i0;
    const size_t gb = (size_t)b * SS;
    const float scale = 0.125f;

    // stage Q tile (16 x 512) into LDS
    {
        const int r = tid >> 4;
        const int c0 = (tid & 15) * 32;
        const uint4* src = reinterpret_cast<const uint4*>(qws + (g0 + r) * EE + c0);
        uint4* dst = reinterpret_cast<uint4*>(&aqL[r][c0]);
        dst[0] = src[0]; dst[1] = src[1]; dst[2] = src[2]; dst[3] = src[3];
    }
    if (tid < HH * TI) {
        const int h = tid >> 4, i = tid & 15;
        float s = 0.f;
        #pragma unroll
        for (int c = 0; c < JC1; ++c)
            s += dnP[((size_t)(c * BB + b) * SS + i0 + i) * HH + h];
        invd[h][i] = 1.0f / s;
    }
    __syncthreads();

    float idv[HH][4];
    #pragma unroll
    for (int h = 0; h < HH; ++h)
        #pragma unroll
        for (int r = 0; r < 4; ++r) idv[h][r] = invd[h][quad * 4 + r];

    // phase 1: scores -> ewL (+ neighbor counting)
    float cl[4] = {0.f, 0.f, 0.f, 0.f};
    for (int jt = 0; jt < 8; ++jt) {
        const int j0 = jc * 512 + wv * 128 + jt * 16;
        float wsum[4] = {0.f, 0.f, 0.f, 0.f};
        #pragma unroll
        for (int h = 0; h < HH; ++h) {
            const short8 a0 = *reinterpret_cast<const short8*>(&aqL[m16][h * 64 + quad * 8]);
            const short8 a1 = *reinterpret_cast<const short8*>(&aqL[m16][h * 64 + 32 + quad * 8]);
            const short8 bk0 = *reinterpret_cast<const short8*>(
                kws + (gb + j0 + m16) * EE + h * 64 + quad * 8);
            const short8 bk1 = *reinterpret_cast<const short8*>(
                kws + (gb + j0 + m16) * EE + h * 64 + 32 + quad * 8);
            f32x4 c = {0.f, 0.f, 0.f, 0.f};
            c = __builtin_amdgcn_mfma_f32_16x16x32_bf16(a0, bk0, c, 0, 0, 0);
            c = __builtin_amdgcn_mfma_f32_16x16x32_bf16(a1, bk1, c, 0, 0, 0);
            #pragma unroll
            for (int r = 0; r < 4; ++r) wsum[r] += __expf(c[r] * scale) * idv[h][r];
        }
        const int jloc = wv * 128 + jt * 16 + m16;
        #pragma unroll
        for (int r = 0; r < 4; ++r) {
            const float w = wsum[r] * 0.125f;   // head mean
            if (w > 0.1f) cl[r] += 1.f;
            ewL[quad * 4 + r][jloc] = __float2bfloat16(w);
        }
    }
    #pragma unroll
    for (int off = 1; off <= 8; off <<= 1)
        #pragma unroll
        for (int r = 0; r < 4; ++r) cl[r] += __shfl_xor(cl[r], off, 64);
    if (m16 == 0)
        #pragma unroll
        for (int r = 0; r < 4; ++r) cpart[wv][quad * 4 + r] = cl[r];
    __syncthreads();
    if (tid < TI) {
        const float c = cpart[0][tid] + cpart[1][tid] + cpart[2][tid] + cpart[3][tid];
        if (c != 0.f) atomicAdd(&cnt[g0 + tid], c);
    }

    // phase 2: PV = ewL[16x512] @ V[512 x 512] via MFMA (B from vT rows)
    f32x4 accT[8];
    #pragma unroll
    for (int nt = 0; nt < 8; ++nt) accT[nt] = (f32x4){0.f, 0.f, 0.f, 0.f};
    for (int ks = 0; ks < 16; ++ks) {
        const short8 aew = *reinterpret_cast<const short8*>(&ewL[m16][ks * 32 + quad * 8]);
        #pragma unroll
        for (int nt = 0; nt < 8; ++nt) {
            const int e = (wv * 8 + nt) * 16 + m16;
            const short8 bvv = *reinterpret_cast<const short8*>(
                vT + ((size_t)(b * EE + e)) * SS + jc * 512 + ks * 32 + quad * 8);
            accT[nt] = __builtin_amdgcn_mfma_f32_16x16x32_bf16(aew, bvv, accT[nt], 0, 0, 0);
        }
    }
    #pragma unroll
    for (int nt = 0; nt < 8; ++nt) {
        const int e = (wv * 8 + nt) * 16 + m16;
        #pragma unroll
        for (int r = 0; r < 4; ++r)
            slabs[((size_t)jc * NN + g0 + quad * 4 + r) * EE + e] =
                __float2bfloat16(accT[nt][r]);
    }
}

// ---------------- K3: finalize u1 = sum slabs (+ exact rare masked path) ----------------
__global__ __launch_bounds__(256) void attn_final(
    __hip_bfloat16* qu,
    const __hip_bfloat16* __restrict__ kws,
    const float* __restrict__ x,
    const float* __restrict__ dnP,
    const float* __restrict__ cnt,
    const __hip_bfloat16* __restrict__ slabs)
{
    __shared__ float qrowL[EE];
    __shared__ float wj[SS];
    const int row = blockIdx.x;
    const int b = row >> 11;
    const int tid = threadIdx.x;
    const size_t gb = (size_t)b * SS;
    const int e = tid * 2;
    const float c = cnt[row];

    float lo = 0.f, hi = 0.f;
    #pragma unroll
    for (int jc = 0; jc < JC2; ++jc) {
        const unsigned p = *reinterpret_cast<const unsigned*>(
            slabs + ((size_t)jc * NN + row) * EE + e);
        lo += bflo(p); hi += bfhi(p);
    }

    float mlo = 0.f, mhi = 0.f;
    if (c > 0.f) {   // block-uniform rare path: exact masked aggregation
        const float scale = 0.125f;
        for (int l = tid; l < EE; l += 256) qrowL[l] = (float)qu[(size_t)row * EE + l];
        __syncthreads();
        float invd8[HH];
        #pragma unroll
        for (int h = 0; h < HH; ++h) {
            float s = 0.f;
            #pragma unroll
            for (int cc = 0; cc < JC1; ++cc)
                s += dnP[((size_t)(cc * BB + b) * SS + (row & (SS-1))) * HH + h];
            invd8[h] = 1.0f / s;
        }
        for (int j = tid; j < SS; j += 256) {
            float wsum = 0.f;
            #pragma unroll
            for (int h = 0; h < HH; ++h) {
                const __hip_bfloat16* kr = kws + (gb + j) * EE + h * 64;
                float s = 0.f;
                for (int t = 0; t < 64; ++t) s += qrowL[h*64 + t] * (float)kr[t];
                wsum += __expf(s * scale) * invd8[h];
            }
            wj[j] = wsum * 0.125f;
        }
        __syncthreads();
        const float invn = 1.0f / fmaxf(c, 1.0f);
        for (int j = 0; j < SS; ++j) {
            const float w = wj[j];
            if (w > 0.1f) {
                mlo += w * x[(gb + j) * EE + e];
                mhi += w * x[(gb + j) * EE + e + 1];
            }
        }
        mlo *= invn; mhi *= invn;
    }
    *reinterpret_cast<unsigned*>(qu + (size_t)row * EE + e) =
        f2bf(lo + mlo) | (f2bf(hi + mhi) << 16);
}

__global__ void zero_f32(float* p) { p[blockIdx.x * 256 + threadIdx.x] = 0.f; }

extern "C" void kernel_launch(void* const* d_in, const int* in_sizes, int n_in,
                              void* d_out, int out_size, void* d_ws, size_t ws_size,
                              hipStream_t stream)
{
    const float* x   = (const float*)d_in[0];
    const float* Wq  = (const float*)d_in[1];
    const float* bq  = (const float*)d_in[2];
    const float* Wk  = (const float*)d_in[3];
    const float* bk  = (const float*)d_in[4];
    const float* Wv  = (const float*)d_in[5];
    const float* bv  = (const float*)d_in[6];
    const float* Wm1 = (const float*)d_in[7];
    const float* bm1 = (const float*)d_in[8];
    const float* Wm2 = (const float*)d_in[9];
    const float* bm2 = (const float*)d_in[10];
    const float* Wo  = (const float*)d_in[11];
    const float* bo  = (const float*)d_in[12];

    // ws layout (<= 30 MB; ws_size >= 30 MB confirmed in r8 by fast-path run)
    char* ws = (char*)d_ws;
    const size_t MB = 1024 * 1024;
    __hip_bfloat16* qb = (__hip_bfloat16*)(ws + 0);        // q -> u1 -> t   4MB
    __hip_bfloat16* kb = (__hip_bfloat16*)(ws + 4*MB);     // k -> hm        4MB
    __hip_bfloat16* vT = (__hip_bfloat16*)(ws + 8*MB);     // V^T [b][e][j]  4MB
    __hip_bfloat16* slabs = (__hip_bfloat16*)(ws + 12*MB); // JC2 PV slabs  16MB
    float* dnP = (float*)(ws + 28*MB);                     // denom partials 1MB
    float* cnt = (float*)(ws + 29*MB);                     // neighbor cnt  16KB

    dim3 blk(256, 1, 1);
    dim3 gg(EE / 64, NN / 64, 1);

    gemm_bt<0,1,0,0><<<gg, blk, 0, stream>>>(x, Wq, bq, qb, EE);
    gemm_bt<0,1,0,0><<<gg, blk, 0, stream>>>(x, Wk, bk, kb, EE);
    gemm_bt<0,1,0,1><<<gg, blk, 0, stream>>>(x, Wv, bv, vT, EE);       // V^T
    zero_f32<<<dim3(NN / 256), blk, 0, stream>>>(cnt);
    attn_denoms<<<dim3(JC1, SS / TI, BB), blk, 0, stream>>>(qb, kb, dnP);
    attn_pv<<<dim3(JC2, SS / TI, BB), blk, 0, stream>>>(qb, kb, vT, dnP, cnt, slabs);
    attn_final<<<dim3(NN, 1, 1), blk, 0, stream>>>(qb, kb, x, dnP, cnt, slabs);
    gemm_bt<1,1,0,0><<<gg, blk, 0, stream>>>(x, Wm1, bm1, kb, EE + HH); // hm
    gemm_bt<2,0,0,0><<<gg, blk, 0, stream>>>(kb, Wm2, bm2, qb, EE);     // t = MLP2 + u1
    gemm_bt<0,0,1,0><<<gg, blk, 0, stream>>>(qb, Wo, bo, d_out, EE);    // out f32
}

// Round 10
// 541.704 us; speedup vs baseline: 4.4946x; 1.1002x over previous
//
#include <hip/hip_runtime.h>
#include <hip/hip_bf16.h>
#include <math.h>

#define BB 2
#define SS 2048
#define EE 512
#define HH 8
#define NN (BB*SS)
#define TI 16
#define JC1 8   // K1 j-chunks (256 j each)
#define JC2 4   // K2 j-chunks (512 j each)

typedef __attribute__((ext_vector_type(8))) short short8;
typedef __attribute__((ext_vector_type(4))) float f32x4;

__device__ __forceinline__ float bflo(unsigned u){ return __uint_as_float(u << 16); }
__device__ __forceinline__ float bfhi(unsigned u){ return __uint_as_float(u & 0xffff0000u); }
__device__ __forceinline__ unsigned f2bf(float f){
    unsigned u = __float_as_uint(f);
    u += 0x7fffu + ((u >> 16) & 1u);
    return u >> 16;
}
// pack 16 f32 -> 16 bf16 into LDS (two uint4 stores)
__device__ __forceinline__ void stage16_f32(const float* __restrict__ src,
                                            __hip_bfloat16* dst){
    const float4 f0 = *reinterpret_cast<const float4*>(src);
    const float4 f1 = *reinterpret_cast<const float4*>(src + 4);
    const float4 f2 = *reinterpret_cast<const float4*>(src + 8);
    const float4 f3 = *reinterpret_cast<const float4*>(src + 12);
    uint4 o0, o1;
    o0.x = f2bf(f0.x) | (f2bf(f0.y) << 16);
    o0.y = f2bf(f0.z) | (f2bf(f0.w) << 16);
    o0.z = f2bf(f1.x) | (f2bf(f1.y) << 16);
    o0.w = f2bf(f1.z) | (f2bf(f1.w) << 16);
    o1.x = f2bf(f2.x) | (f2bf(f2.y) << 16);
    o1.y = f2bf(f2.z) | (f2bf(f2.w) << 16);
    o1.z = f2bf(f3.x) | (f2bf(f3.y) << 16);
    o1.w = f2bf(f3.z) | (f2bf(f3.w) << 16);
    *reinterpret_cast<uint4*>(dst) = o0;
    *reinterpret_cast<uint4*>(dst + 8) = o1;
}

// ---------------- MFMA GEMM ----------------
// C = A @ W^T (+bias). W/bias f32 (converted bf16 in staging). 64x64 tiles,
// 256 thr (4 waves), each wave: 16 rows x 64 cols via 4 n-tiles of
// mfma_f32_16x16x32_bf16. LDS rows padded to 72 (144B stride: 2-way = free).
// AF32: A f32 vs internal bf16.  CF32: C f32 vs bf16.
// CT=1 (MODE 0 only): write C transposed per batch: vT[b][e][j] bf16.
// MODE 0 plain; MODE 1 ldb=520 + const-ef(1/S) tail + GELU; MODE 2 in-place +C_old
template<int MODE, int AF32, int CF32, int CT>
__global__ __launch_bounds__(256) void gemm_bt(
    const void* __restrict__ Av,
    const float* __restrict__ W,
    const float* __restrict__ bias,
    void* __restrict__ Cv,
    int ldb)
{
    __shared__ __hip_bfloat16 As[64][72];
    __shared__ __hip_bfloat16 Bs[64][72];
    const int tid = threadIdx.x;
    const int col0 = blockIdx.x * 64;
    const int row0 = blockIdx.y * 64;
    const int wv = tid >> 6, lane = tid & 63, quad = lane >> 4, m16 = lane & 15;
    const int sr = tid >> 2;          // staging row 0..63
    const int sc = (tid & 3) * 16;    // staging col start

    f32x4 acc[4];
    #pragma unroll
    for (int nt = 0; nt < 4; ++nt) acc[nt] = (f32x4){0.f, 0.f, 0.f, 0.f};

    for (int k0 = 0; k0 < 512; k0 += 64) {
        if (AF32) {
            stage16_f32((const float*)Av + (size_t)(row0 + sr) * EE + k0 + sc,
                        &As[sr][sc]);
        } else {
            const uint4* src = reinterpret_cast<const uint4*>(
                (const __hip_bfloat16*)Av + (size_t)(row0 + sr) * EE + k0 + sc);
            uint4* dst = reinterpret_cast<uint4*>(&As[sr][sc]);
            dst[0] = src[0]; dst[1] = src[1];
        }
        stage16_f32(W + (size_t)(col0 + sr) * ldb + k0 + sc, &Bs[sr][sc]);
        __syncthreads();
        #pragma unroll
        for (int ks = 0; ks < 2; ++ks) {
            const short8 a = *reinterpret_cast<const short8*>(
                &As[wv * 16 + m16][ks * 32 + quad * 8]);
            #pragma unroll
            for (int nt = 0; nt < 4; ++nt) {
                const short8 b = *reinterpret_cast<const short8*>(
                    &Bs[nt * 16 + m16][ks * 32 + quad * 8]);
                acc[nt] = __builtin_amdgcn_mfma_f32_16x16x32_bf16(a, b, acc[nt], 0, 0, 0);
            }
        }
        __syncthreads();
    }

    if constexpr (CT) {
        // stage bf16(acc+bias) into Bs[m][e], then transposed write: vT[b][e][j]
        #pragma unroll
        for (int nt = 0; nt < 4; ++nt) {
            const int gn = col0 + nt * 16 + m16;
            const float bb = bias[gn];
            #pragma unroll
            for (int r = 0; r < 4; ++r)
                Bs[wv * 16 + quad * 4 + r][nt * 16 + m16] =
                    __float2bfloat16(acc[nt][r] + bb);
        }
        __syncthreads();
        const int bb2 = row0 >> 11;
        const int j0 = row0 & (SS - 1);
        const int er = tid >> 2;            // 0..63 (e within tile)
        const int js = (tid & 3) * 16;      // 16 j per thread
        unsigned pk[8];
        #pragma unroll
        for (int p = 0; p < 8; ++p) {
            const unsigned lo = *reinterpret_cast<const unsigned short*>(&Bs[js + 2*p][er]);
            const unsigned hi = *reinterpret_cast<const unsigned short*>(&Bs[js + 2*p + 1][er]);
            pk[p] = lo | (hi << 16);
        }
        __hip_bfloat16* vT = (__hip_bfloat16*)Cv;
        uint4 s0; s0.x = pk[0]; s0.y = pk[1]; s0.z = pk[2]; s0.w = pk[3];
        uint4 s1; s1.x = pk[4]; s1.y = pk[5]; s1.z = pk[6]; s1.w = pk[7];
        __hip_bfloat16* dst = vT + ((size_t)(bb2 * EE + col0 + er)) * SS + j0 + js;
        *reinterpret_cast<uint4*>(dst) = s0;
        *reinterpret_cast<uint4*>(dst + 8) = s1;
        return;
    } else {
        #pragma unroll
        for (int nt = 0; nt < 4; ++nt) {
            const int gn = col0 + nt * 16 + m16;
            float bb = bias[gn];
            if (MODE == 1) {
                float ts = 0.f;
                #pragma unroll
                for (int h = 0; h < 8; ++h) ts += W[(size_t)gn * ldb + 512 + h];
                bb += ts * (1.0f / (float)SS);
            }
            #pragma unroll
            for (int r = 0; r < 4; ++r) {
                const int gm = row0 + wv * 16 + quad * 4 + r;
                const size_t ci = (size_t)gm * EE + gn;
                float c = acc[nt][r] + bb;
                if (MODE == 1) c = 0.5f * c * (1.0f + erff(c * 0.70710678118654752f));
                if (MODE == 2) c += (float)((const __hip_bfloat16*)Cv)[ci];
                if (CF32) ((float*)Cv)[ci] = c;
                else      ((__hip_bfloat16*)Cv)[ci] = __float2bfloat16(c);
            }
        }
    }
}

// ---------------- K1: partial softmax denominators ----------------
__global__ __launch_bounds__(256) void attn_denoms(
    const __hip_bfloat16* __restrict__ qws,
    const __hip_bfloat16* __restrict__ kws,
    float* __restrict__ dnP)
{
    __shared__ float dpart[4][HH][TI];
    const int tid = threadIdx.x;
    const int wv = tid >> 6, lane = tid & 63, quad = lane >> 4, m16 = lane & 15;
    const int jc = blockIdx.x;
    const int i0 = blockIdx.y * TI;
    const int b  = blockIdx.z;
    const size_t g0 = (size_t)b * SS + i0;
    const size_t gb = (size_t)b * SS;
    const float scale = 0.125f;

    #pragma unroll
    for (int h = 0; h < HH; ++h) {
        const short8 a0 = *reinterpret_cast<const short8*>(
            qws + (g0 + m16) * EE + h * 64 + quad * 8);
        const short8 a1 = *reinterpret_cast<const short8*>(
            qws + (g0 + m16) * EE + h * 64 + 32 + quad * 8);
        float dp[4] = {0.f, 0.f, 0.f, 0.f};
        #pragma unroll
        for (int jt = 0; jt < 4; ++jt) {
            const int j0 = jc * 256 + wv * 64 + jt * 16;
            const short8 bk0 = *reinterpret_cast<const short8*>(
                kws + (gb + j0 + m16) * EE + h * 64 + quad * 8);
            const short8 bk1 = *reinterpret_cast<const short8*>(
                kws + (gb + j0 + m16) * EE + h * 64 + 32 + quad * 8);
            f32x4 c = {0.f, 0.f, 0.f, 0.f};
            c = __builtin_amdgcn_mfma_f32_16x16x32_bf16(a0, bk0, c, 0, 0, 0);
            c = __builtin_amdgcn_mfma_f32_16x16x32_bf16(a1, bk1, c, 0, 0, 0);
            #pragma unroll
            for (int r = 0; r < 4; ++r) dp[r] += __expf(c[r] * scale);
        }
        #pragma unroll
        for (int off = 1; off <= 8; off <<= 1)
            #pragma unroll
            for (int r = 0; r < 4; ++r) dp[r] += __shfl_xor(dp[r], off, 64);
        if (m16 == 0)
            #pragma unroll
            for (int r = 0; r < 4; ++r) dpart[wv][h][quad * 4 + r] = dp[r];
    }
    __syncthreads();
    if (tid < HH * TI) {
        const int h = tid >> 4, i = tid & 15;
        dnP[((size_t)(jc * BB + b) * SS + i0 + i) * HH + h] =
            dpart[0][h][i] + dpart[1][h][i] + dpart[2][h][i] + dpart[3][h][i];
    }
}

// ---------------- K2: ew chunk + MFMA PV ----------------
// launch_bounds(256,3): cap VGPR ~168 -> 3 waves/SIMD (was 248 -> 2 waves)
__global__ __launch_bounds__(256, 3) void attn_pv(
    const __hip_bfloat16* __restrict__ qws,
    const __hip_bfloat16* __restrict__ kws,
    const __hip_bfloat16* __restrict__ vT,
    const float* __restrict__ dnP,
    float* __restrict__ cnt,
    __hip_bfloat16* __restrict__ slabs)
{
    __shared__ __hip_bfloat16 aqL[TI][520];
    __shared__ __hip_bfloat16 ewL[TI][520];
    __shared__ float invd[HH][TI];
    __shared__ float cpart[4][TI];
    const int tid = threadIdx.x;
    const int wv = tid >> 6, lane = tid & 63, quad = lane >> 4, m16 = lane & 15;
    const int jc = blockIdx.x;
    const int i0 = blockIdx.y * TI;
    const int b  = blockIdx.z;
    const size_t g0 = (size_t)b * SS + i0;
    const size_t gb = (size_t)b * SS;
    const float scale = 0.125f;

    {
        const int r = tid >> 4;
        const int c0 = (tid & 15) * 32;
        const uint4* src = reinterpret_cast<const uint4*>(qws + (g0 + r) * EE + c0);
        uint4* dst = reinterpret_cast<uint4*>(&aqL[r][c0]);
        dst[0] = src[0]; dst[1] = src[1]; dst[2] = src[2]; dst[3] = src[3];
    }
    if (tid < HH * TI) {
        const int h = tid >> 4, i = tid & 15;
        float s = 0.f;
        #pragma unroll
        for (int c = 0; c < JC1; ++c)
            s += dnP[((size_t)(c * BB + b) * SS + i0 + i) * HH + h];
        invd[h][i] = 1.0f / s;
    }
    __syncthreads();

    float idv[HH][4];
    #pragma unroll
    for (int h = 0; h < HH; ++h)
        #pragma unroll
        for (int r = 0; r < 4; ++r) idv[h][r] = invd[h][quad * 4 + r];

    float cl[4] = {0.f, 0.f, 0.f, 0.f};
    for (int jt = 0; jt < 8; ++jt) {
        const int j0 = jc * 512 + wv * 128 + jt * 16;
        float wsum[4] = {0.f, 0.f, 0.f, 0.f};
        #pragma unroll
        for (int h = 0; h < HH; ++h) {
            const short8 a0 = *reinterpret_cast<const short8*>(&aqL[m16][h * 64 + quad * 8]);
            const short8 a1 = *reinterpret_cast<const short8*>(&aqL[m16][h * 64 + 32 + quad * 8]);
            const short8 bk0 = *reinterpret_cast<const short8*>(
                kws + (gb + j0 + m16) * EE + h * 64 + quad * 8);
            const short8 bk1 = *reinterpret_cast<const short8*>(
                kws + (gb + j0 + m16) * EE + h * 64 + 32 + quad * 8);
            f32x4 c = {0.f, 0.f, 0.f, 0.f};
            c = __builtin_amdgcn_mfma_f32_16x16x32_bf16(a0, bk0, c, 0, 0, 0);
            c = __builtin_amdgcn_mfma_f32_16x16x32_bf16(a1, bk1, c, 0, 0, 0);
            #pragma unroll
            for (int r = 0; r < 4; ++r) wsum[r] += __expf(c[r] * scale) * idv[h][r];
        }
        const int jloc = wv * 128 + jt * 16 + m16;
        #pragma unroll
        for (int r = 0; r < 4; ++r) {
            const float w = wsum[r] * 0.125f;   // head mean
            if (w > 0.1f) cl[r] += 1.f;
            ewL[quad * 4 + r][jloc] = __float2bfloat16(w);
        }
    }
    #pragma unroll
    for (int off = 1; off <= 8; off <<= 1)
        #pragma unroll
        for (int r = 0; r < 4; ++r) cl[r] += __shfl_xor(cl[r], off, 64);
    if (m16 == 0)
        #pragma unroll
        for (int r = 0; r < 4; ++r) cpart[wv][quad * 4 + r] = cl[r];
    __syncthreads();
    if (tid < TI) {
        const float c = cpart[0][tid] + cpart[1][tid] + cpart[2][tid] + cpart[3][tid];
        if (c != 0.f) atomicAdd(&cnt[g0 + tid], c);
    }

    // phase 2: PV = ewL[16x512] @ V[512x512] via MFMA (B-frags from vT rows)
    f32x4 accT[8];
    #pragma unroll
    for (int nt = 0; nt < 8; ++nt) accT[nt] = (f32x4){0.f, 0.f, 0.f, 0.f};
    for (int ks = 0; ks < 16; ++ks) {
        const short8 aew = *reinterpret_cast<const short8*>(&ewL[m16][ks * 32 + quad * 8]);
        #pragma unroll
        for (int nt = 0; nt < 8; ++nt) {
            const int e = (wv * 8 + nt) * 16 + m16;
            const short8 bvv = *reinterpret_cast<const short8*>(
                vT + ((size_t)(b * EE + e)) * SS + jc * 512 + ks * 32 + quad * 8);
            accT[nt] = __builtin_amdgcn_mfma_f32_16x16x32_bf16(aew, bvv, accT[nt], 0, 0, 0);
        }
    }
    #pragma unroll
    for (int nt = 0; nt < 8; ++nt) {
        const int e = (wv * 8 + nt) * 16 + m16;
        #pragma unroll
        for (int r = 0; r < 4; ++r)
            slabs[((size_t)jc * NN + g0 + quad * 4 + r) * EE + e] =
                __float2bfloat16(accT[nt][r]);
    }
}

// ---------------- K3: finalize u1 = sum slabs (+ exact rare masked path) ----------------
__global__ __launch_bounds__(256) void attn_final(
    __hip_bfloat16* qu,
    const __hip_bfloat16* __restrict__ kws,
    const float* __restrict__ x,
    const float* __restrict__ dnP,
    const float* __restrict__ cnt,
    const __hip_bfloat16* __restrict__ slabs)
{
    __shared__ float qrowL[EE];
    __shared__ float wj[SS];
    const int row = blockIdx.x;
    const int b = row >> 11;
    const int tid = threadIdx.x;
    const size_t gb = (size_t)b * SS;
    const int e = tid * 2;
    const float c = cnt[row];

    float lo = 0.f, hi = 0.f;
    #pragma unroll
    for (int jc = 0; jc < JC2; ++jc) {
        const unsigned p = *reinterpret_cast<const unsigned*>(
            slabs + ((size_t)jc * NN + row) * EE + e);
        lo += bflo(p); hi += bfhi(p);
    }

    float mlo = 0.f, mhi = 0.f;
    if (c > 0.f) {   // block-uniform rare path: exact masked aggregation
        const float scale = 0.125f;
        for (int l = tid; l < EE; l += 256) qrowL[l] = (float)qu[(size_t)row * EE + l];
        __syncthreads();
        float invd8[HH];
        #pragma unroll
        for (int h = 0; h < HH; ++h) {
            float s = 0.f;
            #pragma unroll
            for (int cc = 0; cc < JC1; ++cc)
                s += dnP[((size_t)(cc * BB + b) * SS + (row & (SS-1))) * HH + h];
            invd8[h] = 1.0f / s;
        }
        for (int j = tid; j < SS; j += 256) {
            float wsum = 0.f;
            #pragma unroll
            for (int h = 0; h < HH; ++h) {
                const __hip_bfloat16* kr = kws + (gb + j) * EE + h * 64;
                float s = 0.f;
                for (int t = 0; t < 64; ++t) s += qrowL[h*64 + t] * (float)kr[t];
                wsum += __expf(s * scale) * invd8[h];
            }
            wj[j] = wsum * 0.125f;
        }
        __syncthreads();
        const float invn = 1.0f / fmaxf(c, 1.0f);
        for (int j = 0; j < SS; ++j) {
            const float w = wj[j];
            if (w > 0.1f) {
                mlo += w * x[(gb + j) * EE + e];
                mhi += w * x[(gb + j) * EE + e + 1];
            }
        }
        mlo *= invn; mhi *= invn;
    }
    *reinterpret_cast<unsigned*>(qu + (size_t)row * EE + e) =
        f2bf(lo + mlo) | (f2bf(hi + mhi) << 16);
}

__global__ void zero_f32(float* p) { p[blockIdx.x * 256 + threadIdx.x] = 0.f; }

extern "C" void kernel_launch(void* const* d_in, const int* in_sizes, int n_in,
                              void* d_out, int out_size, void* d_ws, size_t ws_size,
                              hipStream_t stream)
{
    const float* x   = (const float*)d_in[0];
    const float* Wq  = (const float*)d_in[1];
    const float* bq  = (const float*)d_in[2];
    const float* Wk  = (const float*)d_in[3];
    const float* bk  = (const float*)d_in[4];
    const float* Wv  = (const float*)d_in[5];
    const float* bv  = (const float*)d_in[6];
    const float* Wm1 = (const float*)d_in[7];
    const float* bm1 = (const float*)d_in[8];
    const float* Wm2 = (const float*)d_in[9];
    const float* bm2 = (const float*)d_in[10];
    const float* Wo  = (const float*)d_in[11];
    const float* bo  = (const float*)d_in[12];

    // ws layout (<= 30 MB; ws_size >= 30 MB confirmed by r8 fast-path run)
    char* ws = (char*)d_ws;
    const size_t MB = 1024 * 1024;
    __hip_bfloat16* qb = (__hip_bfloat16*)(ws + 0);        // q -> u1 -> t   4MB
    __hip_bfloat16* kb = (__hip_bfloat16*)(ws + 4*MB);     // k -> hm        4MB
    __hip_bfloat16* vT = (__hip_bfloat16*)(ws + 8*MB);     // V^T [b][e][j]  4MB
    __hip_bfloat16* slabs = (__hip_bfloat16*)(ws + 12*MB); // JC2 PV slabs  16MB
    float* dnP = (float*)(ws + 28*MB);                     // denom partials 1MB
    float* cnt = (float*)(ws + 29*MB);                     // neighbor cnt  16KB

    dim3 blk(256, 1, 1);
    dim3 gg(EE / 64, NN / 64, 1);

    gemm_bt<0,1,0,0><<<gg, blk, 0, stream>>>(x, Wq, bq, qb, EE);
    gemm_bt<0,1,0,0><<<gg, blk, 0, stream>>>(x, Wk, bk, kb, EE);
    gemm_bt<0,1,0,1><<<gg, blk, 0, stream>>>(x, Wv, bv, vT, EE);       // V^T
    zero_f32<<<dim3(NN / 256), blk, 0, stream>>>(cnt);
    attn_denoms<<<dim3(JC1, SS / TI, BB), blk, 0, stream>>>(qb, kb, dnP);
    attn_pv<<<dim3(JC2, SS / TI, BB), blk, 0, stream>>>(qb, kb, vT, dnP, cnt, slabs);
    attn_final<<<dim3(NN, 1, 1), blk, 0, stream>>>(qb, kb, x, dnP, cnt, slabs);
    gemm_bt<1,1,0,0><<<gg, blk, 0, stream>>>(x, Wm1, bm1, kb, EE + HH); // hm
    gemm_bt<2,0,0,0><<<gg, blk, 0, stream>>>(kb, Wm2, bm2, qb, EE);     // t = MLP2 + u1
    gemm_bt<0,0,1,0><<<gg, blk, 0, stream>>>(qb, Wo, bo, d_out, EE);    // out f32
}

// Round 11
// 359.010 us; speedup vs baseline: 6.7818x; 1.5089x over previous
//
#include <hip/hip_runtime.h>
#include <hip/hip_bf16.h>
#include <math.h>

#define BB 2
#define SS 2048
#define EE 512
#define HH 8
#define NN (BB*SS)
#define TI 16
#define JC1 8   // K1 j-chunks (256 j each)
#define JC2 4   // K2 j-chunks (512 j each)

typedef __attribute__((ext_vector_type(8))) short short8;
typedef __attribute__((ext_vector_type(4))) float f32x4;

__device__ __forceinline__ float bflo(unsigned u){ return __uint_as_float(u << 16); }
__device__ __forceinline__ float bfhi(unsigned u){ return __uint_as_float(u & 0xffff0000u); }
__device__ __forceinline__ unsigned f2bf(float f){
    unsigned u = __float_as_uint(f);
    u += 0x7fffu + ((u >> 16) & 1u);
    return u >> 16;
}
// pack 16 f32 -> 16 bf16 into LDS (two uint4 stores)
__device__ __forceinline__ void stage16_f32(const float* __restrict__ src,
                                            __hip_bfloat16* dst){
    const float4 f0 = *reinterpret_cast<const float4*>(src);
    const float4 f1 = *reinterpret_cast<const float4*>(src + 4);
    const float4 f2 = *reinterpret_cast<const float4*>(src + 8);
    const float4 f3 = *reinterpret_cast<const float4*>(src + 12);
    uint4 o0, o1;
    o0.x = f2bf(f0.x) | (f2bf(f0.y) << 16);
    o0.y = f2bf(f0.z) | (f2bf(f0.w) << 16);
    o0.z = f2bf(f1.x) | (f2bf(f1.y) << 16);
    o0.w = f2bf(f1.z) | (f2bf(f1.w) << 16);
    o1.x = f2bf(f2.x) | (f2bf(f2.y) << 16);
    o1.y = f2bf(f2.z) | (f2bf(f2.w) << 16);
    o1.z = f2bf(f3.x) | (f2bf(f3.y) << 16);
    o1.w = f2bf(f3.z) | (f2bf(f3.w) << 16);
    *reinterpret_cast<uint4*>(dst) = o0;
    *reinterpret_cast<uint4*>(dst + 8) = o1;
}

// ---------------- fused QKV projection (MFMA) ----------------
// grid (24, 64): which = blockIdx.x>>3 (0=q,1=k,2=v), col0 = (blockIdx.x&7)*64.
// q,k -> row-major bf16; v -> transposed vT[b][e][j] bf16.
__global__ __launch_bounds__(256) void qkv_gemm(
    const float* __restrict__ x,
    const float* __restrict__ Wq, const float* __restrict__ bq,
    const float* __restrict__ Wk, const float* __restrict__ bk,
    const float* __restrict__ Wv, const float* __restrict__ bv,
    __hip_bfloat16* __restrict__ qb,
    __hip_bfloat16* __restrict__ kb,
    __hip_bfloat16* __restrict__ vT)
{
    __shared__ __hip_bfloat16 As[64][72];
    __shared__ __hip_bfloat16 Bs[64][72];
    const int tid = threadIdx.x;
    const int which = blockIdx.x >> 3;
    const int col0 = (blockIdx.x & 7) * 64;
    const int row0 = blockIdx.y * 64;
    const int wv = tid >> 6, lane = tid & 63, quad = lane >> 4, m16 = lane & 15;
    const int sr = tid >> 2;
    const int sc = (tid & 3) * 16;
    const float* W    = (which == 0) ? Wq : (which == 1) ? Wk : Wv;
    const float* bias = (which == 0) ? bq : (which == 1) ? bk : bv;

    f32x4 acc[4];
    #pragma unroll
    for (int nt = 0; nt < 4; ++nt) acc[nt] = (f32x4){0.f, 0.f, 0.f, 0.f};

    for (int k0 = 0; k0 < 512; k0 += 64) {
        stage16_f32(x + (size_t)(row0 + sr) * EE + k0 + sc, &As[sr][sc]);
        stage16_f32(W + (size_t)(col0 + sr) * EE + k0 + sc, &Bs[sr][sc]);
        __syncthreads();
        #pragma unroll
        for (int ks = 0; ks < 2; ++ks) {
            const short8 a = *reinterpret_cast<const short8*>(
                &As[wv * 16 + m16][ks * 32 + quad * 8]);
            #pragma unroll
            for (int nt = 0; nt < 4; ++nt) {
                const short8 b = *reinterpret_cast<const short8*>(
                    &Bs[nt * 16 + m16][ks * 32 + quad * 8]);
                acc[nt] = __builtin_amdgcn_mfma_f32_16x16x32_bf16(a, b, acc[nt], 0, 0, 0);
            }
        }
        __syncthreads();
    }

    if (which == 2) {
        // transposed epilogue -> vT[b][e][j]
        #pragma unroll
        for (int nt = 0; nt < 4; ++nt) {
            const float bb = bias[col0 + nt * 16 + m16];
            #pragma unroll
            for (int r = 0; r < 4; ++r)
                Bs[wv * 16 + quad * 4 + r][nt * 16 + m16] =
                    __float2bfloat16(acc[nt][r] + bb);
        }
        __syncthreads();
        const int bb2 = row0 >> 11;
        const int j0 = row0 & (SS - 1);
        const int er = tid >> 2;
        const int js = (tid & 3) * 16;
        unsigned pk[8];
        #pragma unroll
        for (int p = 0; p < 8; ++p) {
            const unsigned lo = *reinterpret_cast<const unsigned short*>(&Bs[js + 2*p][er]);
            const unsigned hi = *reinterpret_cast<const unsigned short*>(&Bs[js + 2*p + 1][er]);
            pk[p] = lo | (hi << 16);
        }
        uint4 s0; s0.x = pk[0]; s0.y = pk[1]; s0.z = pk[2]; s0.w = pk[3];
        uint4 s1; s1.x = pk[4]; s1.y = pk[5]; s1.z = pk[6]; s1.w = pk[7];
        __hip_bfloat16* dst = vT + ((size_t)(bb2 * EE + col0 + er)) * SS + j0 + js;
        *reinterpret_cast<uint4*>(dst) = s0;
        *reinterpret_cast<uint4*>(dst + 8) = s1;
    } else {
        __hip_bfloat16* C = (which == 0) ? qb : kb;
        #pragma unroll
        for (int nt = 0; nt < 4; ++nt) {
            const int gn = col0 + nt * 16 + m16;
            const float bb = bias[gn];
            #pragma unroll
            for (int r = 0; r < 4; ++r) {
                const int gm = row0 + wv * 16 + quad * 4 + r;
                C[(size_t)gm * EE + gn] = __float2bfloat16(acc[nt][r] + bb);
            }
        }
    }
}

// ---------------- MFMA GEMM (MLP1 / MLP2 / out-proj) ----------------
// AF32: A f32 vs internal bf16.  CF32: C f32 vs bf16.
// MODE 0 plain; MODE 1 ldb=520 + const-ef(1/S) tail + GELU; MODE 2 in-place +C_old
template<int MODE, int AF32, int CF32>
__global__ __launch_bounds__(256) void gemm_bt(
    const void* __restrict__ Av,
    const float* __restrict__ W,
    const float* __restrict__ bias,
    void* __restrict__ Cv,
    int ldb)
{
    __shared__ __hip_bfloat16 As[64][72];
    __shared__ __hip_bfloat16 Bs[64][72];
    const int tid = threadIdx.x;
    const int col0 = blockIdx.x * 64;
    const int row0 = blockIdx.y * 64;
    const int wv = tid >> 6, lane = tid & 63, quad = lane >> 4, m16 = lane & 15;
    const int sr = tid >> 2;
    const int sc = (tid & 3) * 16;

    f32x4 acc[4];
    #pragma unroll
    for (int nt = 0; nt < 4; ++nt) acc[nt] = (f32x4){0.f, 0.f, 0.f, 0.f};

    for (int k0 = 0; k0 < 512; k0 += 64) {
        if (AF32) {
            stage16_f32((const float*)Av + (size_t)(row0 + sr) * EE + k0 + sc,
                        &As[sr][sc]);
        } else {
            const uint4* src = reinterpret_cast<const uint4*>(
                (const __hip_bfloat16*)Av + (size_t)(row0 + sr) * EE + k0 + sc);
            uint4* dst = reinterpret_cast<uint4*>(&As[sr][sc]);
            dst[0] = src[0]; dst[1] = src[1];
        }
        stage16_f32(W + (size_t)(col0 + sr) * ldb + k0 + sc, &Bs[sr][sc]);
        __syncthreads();
        #pragma unroll
        for (int ks = 0; ks < 2; ++ks) {
            const short8 a = *reinterpret_cast<const short8*>(
                &As[wv * 16 + m16][ks * 32 + quad * 8]);
            #pragma unroll
            for (int nt = 0; nt < 4; ++nt) {
                const short8 b = *reinterpret_cast<const short8*>(
                    &Bs[nt * 16 + m16][ks * 32 + quad * 8]);
                acc[nt] = __builtin_amdgcn_mfma_f32_16x16x32_bf16(a, b, acc[nt], 0, 0, 0);
            }
        }
        __syncthreads();
    }

    #pragma unroll
    for (int nt = 0; nt < 4; ++nt) {
        const int gn = col0 + nt * 16 + m16;
        float bb = bias[gn];
        if (MODE == 1) {
            float ts = 0.f;
            #pragma unroll
            for (int h = 0; h < 8; ++h) ts += W[(size_t)gn * ldb + 512 + h];
            bb += ts * (1.0f / (float)SS);
        }
        #pragma unroll
        for (int r = 0; r < 4; ++r) {
            const int gm = row0 + wv * 16 + quad * 4 + r;
            const size_t ci = (size_t)gm * EE + gn;
            float c = acc[nt][r] + bb;
            if (MODE == 1) c = 0.5f * c * (1.0f + erff(c * 0.70710678118654752f));
            if (MODE == 2) c += (float)((const __hip_bfloat16*)Cv)[ci];
            if (CF32) ((float*)Cv)[ci] = c;
            else      ((__hip_bfloat16*)Cv)[ci] = __float2bfloat16(c);
        }
    }
}

// ---------------- K1: partial softmax denominators (+ cnt zeroing) ----------------
__global__ __launch_bounds__(256) void attn_denoms(
    const __hip_bfloat16* __restrict__ qws,
    const __hip_bfloat16* __restrict__ kws,
    float* __restrict__ dnP,
    float* __restrict__ cnt)
{
    __shared__ float dpart[4][HH][TI];
    const int tid = threadIdx.x;
    const int wv = tid >> 6, lane = tid & 63, quad = lane >> 4, m16 = lane & 15;
    const int jc = blockIdx.x;
    const int i0 = blockIdx.y * TI;
    const int b  = blockIdx.z;
    const size_t g0 = (size_t)b * SS + i0;
    const size_t gb = (size_t)b * SS;
    const float scale = 0.125f;

    if (jc == 0 && tid < TI) cnt[g0 + tid] = 0.f;   // zero before attn_pv runs

    #pragma unroll
    for (int h = 0; h < HH; ++h) {
        const short8 a0 = *reinterpret_cast<const short8*>(
            qws + (g0 + m16) * EE + h * 64 + quad * 8);
        const short8 a1 = *reinterpret_cast<const short8*>(
            qws + (g0 + m16) * EE + h * 64 + 32 + quad * 8);
        float dp[4] = {0.f, 0.f, 0.f, 0.f};
        #pragma unroll
        for (int jt = 0; jt < 4; ++jt) {
            const int j0 = jc * 256 + wv * 64 + jt * 16;
            const short8 bk0 = *reinterpret_cast<const short8*>(
                kws + (gb + j0 + m16) * EE + h * 64 + quad * 8);
            const short8 bk1 = *reinterpret_cast<const short8*>(
                kws + (gb + j0 + m16) * EE + h * 64 + 32 + quad * 8);
            f32x4 c = {0.f, 0.f, 0.f, 0.f};
            c = __builtin_amdgcn_mfma_f32_16x16x32_bf16(a0, bk0, c, 0, 0, 0);
            c = __builtin_amdgcn_mfma_f32_16x16x32_bf16(a1, bk1, c, 0, 0, 0);
            #pragma unroll
            for (int r = 0; r < 4; ++r) dp[r] += __expf(c[r] * scale);
        }
        #pragma unroll
        for (int off = 1; off <= 8; off <<= 1)
            #pragma unroll
            for (int r = 0; r < 4; ++r) dp[r] += __shfl_xor(dp[r], off, 64);
        if (m16 == 0)
            #pragma unroll
            for (int r = 0; r < 4; ++r) dpart[wv][h][quad * 4 + r] = dp[r];
    }
    __syncthreads();
    if (tid < HH * TI) {
        const int h = tid >> 4, i = tid & 15;
        dnP[((size_t)(jc * BB + b) * SS + i0 + i) * HH + h] =
            dpart[0][h][i] + dpart[1][h][i] + dpart[2][h][i] + dpart[3][h][i];
    }
}

// ---------------- K2: ew chunk + MFMA PV ----------------
// No launch_bounds cap (r10: cap(256,3) forced VGPR 84 -> massive scratch
// spills, 396 MB writes). Register pressure reduced structurally instead:
// phase-1 h-loop unroll 2, invd read from LDS (no idv register array).
__global__ __launch_bounds__(256) void attn_pv(
    const __hip_bfloat16* __restrict__ qws,
    const __hip_bfloat16* __restrict__ kws,
    const __hip_bfloat16* __restrict__ vT,
    const float* __restrict__ dnP,
    float* __restrict__ cnt,
    __hip_bfloat16* __restrict__ slabs)
{
    __shared__ __hip_bfloat16 aqL[TI][520];
    __shared__ __hip_bfloat16 ewL[TI][520];
    __shared__ float invd[HH][TI];
    __shared__ float cpart[4][TI];
    const int tid = threadIdx.x;
    const int wv = tid >> 6, lane = tid & 63, quad = lane >> 4, m16 = lane & 15;
    const int jc = blockIdx.x;
    const int i0 = blockIdx.y * TI;
    const int b  = blockIdx.z;
    const size_t g0 = (size_t)b * SS + i0;
    const size_t gb = (size_t)b * SS;
    const float scale = 0.125f;

    {
        const int r = tid >> 4;
        const int c0 = (tid & 15) * 32;
        const uint4* src = reinterpret_cast<const uint4*>(qws + (g0 + r) * EE + c0);
        uint4* dst = reinterpret_cast<uint4*>(&aqL[r][c0]);
        dst[0] = src[0]; dst[1] = src[1]; dst[2] = src[2]; dst[3] = src[3];
    }
    if (tid < HH * TI) {
        const int h = tid >> 4, i = tid & 15;
        float s = 0.f;
        #pragma unroll
        for (int c = 0; c < JC1; ++c)
            s += dnP[((size_t)(c * BB + b) * SS + i0 + i) * HH + h];
        invd[h][i] = 1.0f / s;
    }
    __syncthreads();

    // phase 1: scores -> ewL (+ neighbor counting)
    float cl[4] = {0.f, 0.f, 0.f, 0.f};
    for (int jt = 0; jt < 8; ++jt) {
        const int j0 = jc * 512 + wv * 128 + jt * 16;
        float wsum[4] = {0.f, 0.f, 0.f, 0.f};
        #pragma unroll 2
        for (int h = 0; h < HH; ++h) {
            const short8 a0 = *reinterpret_cast<const short8*>(&aqL[m16][h * 64 + quad * 8]);
            const short8 a1 = *reinterpret_cast<const short8*>(&aqL[m16][h * 64 + 32 + quad * 8]);
            const short8 bk0 = *reinterpret_cast<const short8*>(
                kws + (gb + j0 + m16) * EE + h * 64 + quad * 8);
            const short8 bk1 = *reinterpret_cast<const short8*>(
                kws + (gb + j0 + m16) * EE + h * 64 + 32 + quad * 8);
            f32x4 c = {0.f, 0.f, 0.f, 0.f};
            c = __builtin_amdgcn_mfma_f32_16x16x32_bf16(a0, bk0, c, 0, 0, 0);
            c = __builtin_amdgcn_mfma_f32_16x16x32_bf16(a1, bk1, c, 0, 0, 0);
            #pragma unroll
            for (int r = 0; r < 4; ++r)
                wsum[r] += __expf(c[r] * scale) * invd[h][quad * 4 + r];
        }
        const int jloc = wv * 128 + jt * 16 + m16;
        #pragma unroll
        for (int r = 0; r < 4; ++r) {
            const float w = wsum[r] * 0.125f;   // head mean
            if (w > 0.1f) cl[r] += 1.f;
            ewL[quad * 4 + r][jloc] = __float2bfloat16(w);
        }
    }
    #pragma unroll
    for (int off = 1; off <= 8; off <<= 1)
        #pragma unroll
        for (int r = 0; r < 4; ++r) cl[r] += __shfl_xor(cl[r], off, 64);
    if (m16 == 0)
        #pragma unroll
        for (int r = 0; r < 4; ++r) cpart[wv][quad * 4 + r] = cl[r];
    __syncthreads();
    if (tid < TI) {
        const float c = cpart[0][tid] + cpart[1][tid] + cpart[2][tid] + cpart[3][tid];
        if (c != 0.f) atomicAdd(&cnt[g0 + tid], c);
    }

    // phase 2: PV = ewL[16x512] @ V[512x512] via MFMA (B-frags from vT rows)
    f32x4 accT[8];
    #pragma unroll
    for (int nt = 0; nt < 8; ++nt) accT[nt] = (f32x4){0.f, 0.f, 0.f, 0.f};
    for (int ks = 0; ks < 16; ++ks) {
        const short8 aew = *reinterpret_cast<const short8*>(&ewL[m16][ks * 32 + quad * 8]);
        #pragma unroll
        for (int nt = 0; nt < 8; ++nt) {
            const int e = (wv * 8 + nt) * 16 + m16;
            const short8 bvv = *reinterpret_cast<const short8*>(
                vT + ((size_t)(b * EE + e)) * SS + jc * 512 + ks * 32 + quad * 8);
            accT[nt] = __builtin_amdgcn_mfma_f32_16x16x32_bf16(aew, bvv, accT[nt], 0, 0, 0);
        }
    }
    #pragma unroll
    for (int nt = 0; nt < 8; ++nt) {
        const int e = (wv * 8 + nt) * 16 + m16;
        #pragma unroll
        for (int r = 0; r < 4; ++r)
            slabs[((size_t)jc * NN + g0 + quad * 4 + r) * EE + e] =
                __float2bfloat16(accT[nt][r]);
    }
}

// ---------------- K3: finalize u1 = sum slabs (+ exact rare masked path) ----------------
__global__ __launch_bounds__(256) void attn_final(
    __hip_bfloat16* qu,
    const __hip_bfloat16* __restrict__ kws,
    const float* __restrict__ x,
    const float* __restrict__ dnP,
    const float* __restrict__ cnt,
    const __hip_bfloat16* __restrict__ slabs)
{
    __shared__ float qrowL[EE];
    __shared__ float wj[SS];
    const int row = blockIdx.x;
    const int b = row >> 11;
    const int tid = threadIdx.x;
    const size_t gb = (size_t)b * SS;
    const int e = tid * 2;
    const float c = cnt[row];

    float lo = 0.f, hi = 0.f;
    #pragma unroll
    for (int jc = 0; jc < JC2; ++jc) {
        const unsigned p = *reinterpret_cast<const unsigned*>(
            slabs + ((size_t)jc * NN + row) * EE + e);
        lo += bflo(p); hi += bfhi(p);
    }

    float mlo = 0.f, mhi = 0.f;
    if (c > 0.f) {   // block-uniform rare path: exact masked aggregation
        const float scale = 0.125f;
        for (int l = tid; l < EE; l += 256) qrowL[l] = (float)qu[(size_t)row * EE + l];
        __syncthreads();
        float invd8[HH];
        #pragma unroll
        for (int h = 0; h < HH; ++h) {
            float s = 0.f;
            #pragma unroll
            for (int cc = 0; cc < JC1; ++cc)
                s += dnP[((size_t)(cc * BB + b) * SS + (row & (SS-1))) * HH + h];
            invd8[h] = 1.0f / s;
        }
        for (int j = tid; j < SS; j += 256) {
            float wsum = 0.f;
            #pragma unroll
            for (int h = 0; h < HH; ++h) {
                const __hip_bfloat16* kr = kws + (gb + j) * EE + h * 64;
                float s = 0.f;
                for (int t = 0; t < 64; ++t) s += qrowL[h*64 + t] * (float)kr[t];
                wsum += __expf(s * scale) * invd8[h];
            }
            wj[j] = wsum * 0.125f;
        }
        __syncthreads();
        const float invn = 1.0f / fmaxf(c, 1.0f);
        for (int j = 0; j < SS; ++j) {
            const float w = wj[j];
            if (w > 0.1f) {
                mlo += w * x[(gb + j) * EE + e];
                mhi += w * x[(gb + j) * EE + e + 1];
            }
        }
        mlo *= invn; mhi *= invn;
    }
    *reinterpret_cast<unsigned*>(qu + (size_t)row * EE + e) =
        f2bf(lo + mlo) | (f2bf(hi + mhi) << 16);
}

extern "C" void kernel_launch(void* const* d_in, const int* in_sizes, int n_in,
                              void* d_out, int out_size, void* d_ws, size_t ws_size,
                              hipStream_t stream)
{
    const float* x   = (const float*)d_in[0];
    const float* Wq  = (const float*)d_in[1];
    const float* bq  = (const float*)d_in[2];
    const float* Wk  = (const float*)d_in[3];
    const float* bk  = (const float*)d_in[4];
    const float* Wv  = (const float*)d_in[5];
    const float* bv  = (const float*)d_in[6];
    const float* Wm1 = (const float*)d_in[7];
    const float* bm1 = (const float*)d_in[8];
    const float* Wm2 = (const float*)d_in[9];
    const float* bm2 = (const float*)d_in[10];
    const float* Wo  = (const float*)d_in[11];
    const float* bo  = (const float*)d_in[12];

    // ws layout (<= 30 MB; ws_size >= 30 MB confirmed by r8 fast-path run)
    char* ws = (char*)d_ws;
    const size_t MB = 1024 * 1024;
    __hip_bfloat16* qb = (__hip_bfloat16*)(ws + 0);        // q -> u1 -> t   4MB
    __hip_bfloat16* kb = (__hip_bfloat16*)(ws + 4*MB);     // k -> hm        4MB
    __hip_bfloat16* vT = (__hip_bfloat16*)(ws + 8*MB);     // V^T [b][e][j]  4MB
    __hip_bfloat16* slabs = (__hip_bfloat16*)(ws + 12*MB); // JC2 PV slabs  16MB
    float* dnP = (float*)(ws + 28*MB);                     // denom partials 1MB
    float* cnt = (float*)(ws + 29*MB);                     // neighbor cnt  16KB

    dim3 blk(256, 1, 1);
    dim3 gg(EE / 64, NN / 64, 1);

    qkv_gemm<<<dim3(24, NN / 64, 1), blk, 0, stream>>>(
        x, Wq, bq, Wk, bk, Wv, bv, qb, kb, vT);
    attn_denoms<<<dim3(JC1, SS / TI, BB), blk, 0, stream>>>(qb, kb, dnP, cnt);
    attn_pv<<<dim3(JC2, SS / TI, BB), blk, 0, stream>>>(qb, kb, vT, dnP, cnt, slabs);
    attn_final<<<dim3(NN, 1, 1), blk, 0, stream>>>(qb, kb, x, dnP, cnt, slabs);
    gemm_bt<1,1,0><<<gg, blk, 0, stream>>>(x, Wm1, bm1, kb, EE + HH);   // hm
    gemm_bt<2,0,0><<<gg, blk, 0, stream>>>(kb, Wm2, bm2, qb, EE);       // t = MLP2 + u1
    gemm_bt<0,0,1><<<gg, blk, 0, stream>>>(qb, Wo, bo, d_out, EE);      // out f32
}

// Round 12
// 347.025 us; speedup vs baseline: 7.0160x; 1.0345x over previous
//
#include <hip/hip_runtime.h>
#include <hip/hip_bf16.h>
#include <math.h>

#define BB 2
#define SS 2048
#define EE 512
#define HH 8
#define NN (BB*SS)
#define TI 16
#define JC1 8   // denoms j-chunks (256 j each)
#define JCE 8   // ew j-chunks (256 j each)

typedef __attribute__((ext_vector_type(8))) short short8;
typedef __attribute__((ext_vector_type(4))) float f32x4;

__device__ __forceinline__ float bflo(unsigned u){ return __uint_as_float(u << 16); }
__device__ __forceinline__ float bfhi(unsigned u){ return __uint_as_float(u & 0xffff0000u); }
__device__ __forceinline__ unsigned f2bf(float f){
    unsigned u = __float_as_uint(f);
    u += 0x7fffu + ((u >> 16) & 1u);
    return u >> 16;
}
// pack 16 f32 -> 16 bf16 into LDS (two uint4 stores)
__device__ __forceinline__ void stage16_f32(const float* __restrict__ src,
                                            __hip_bfloat16* dst){
    const float4 f0 = *reinterpret_cast<const float4*>(src);
    const float4 f1 = *reinterpret_cast<const float4*>(src + 4);
    const float4 f2 = *reinterpret_cast<const float4*>(src + 8);
    const float4 f3 = *reinterpret_cast<const float4*>(src + 12);
    uint4 o0, o1;
    o0.x = f2bf(f0.x) | (f2bf(f0.y) << 16);
    o0.y = f2bf(f0.z) | (f2bf(f0.w) << 16);
    o0.z = f2bf(f1.x) | (f2bf(f1.y) << 16);
    o0.w = f2bf(f1.z) | (f2bf(f1.w) << 16);
    o1.x = f2bf(f2.x) | (f2bf(f2.y) << 16);
    o1.y = f2bf(f2.z) | (f2bf(f2.w) << 16);
    o1.z = f2bf(f3.x) | (f2bf(f3.y) << 16);
    o1.w = f2bf(f3.z) | (f2bf(f3.w) << 16);
    *reinterpret_cast<uint4*>(dst) = o0;
    *reinterpret_cast<uint4*>(dst + 8) = o1;
}

// ---------------- fused QKV projection (MFMA) ----------------
__global__ __launch_bounds__(256) void qkv_gemm(
    const float* __restrict__ x,
    const float* __restrict__ Wq, const float* __restrict__ bq,
    const float* __restrict__ Wk, const float* __restrict__ bk,
    const float* __restrict__ Wv, const float* __restrict__ bv,
    __hip_bfloat16* __restrict__ qb,
    __hip_bfloat16* __restrict__ kb,
    __hip_bfloat16* __restrict__ vT)
{
    __shared__ __hip_bfloat16 As[64][72];
    __shared__ __hip_bfloat16 Bs[64][72];
    const int tid = threadIdx.x;
    const int which = blockIdx.x >> 3;
    const int col0 = (blockIdx.x & 7) * 64;
    const int row0 = blockIdx.y * 64;
    const int wv = tid >> 6, lane = tid & 63, quad = lane >> 4, m16 = lane & 15;
    const int sr = tid >> 2;
    const int sc = (tid & 3) * 16;
    const float* W    = (which == 0) ? Wq : (which == 1) ? Wk : Wv;
    const float* bias = (which == 0) ? bq : (which == 1) ? bk : bv;

    f32x4 acc[4];
    #pragma unroll
    for (int nt = 0; nt < 4; ++nt) acc[nt] = (f32x4){0.f, 0.f, 0.f, 0.f};

    for (int k0 = 0; k0 < 512; k0 += 64) {
        stage16_f32(x + (size_t)(row0 + sr) * EE + k0 + sc, &As[sr][sc]);
        stage16_f32(W + (size_t)(col0 + sr) * EE + k0 + sc, &Bs[sr][sc]);
        __syncthreads();
        #pragma unroll
        for (int ks = 0; ks < 2; ++ks) {
            const short8 a = *reinterpret_cast<const short8*>(
                &As[wv * 16 + m16][ks * 32 + quad * 8]);
            #pragma unroll
            for (int nt = 0; nt < 4; ++nt) {
                const short8 b = *reinterpret_cast<const short8*>(
                    &Bs[nt * 16 + m16][ks * 32 + quad * 8]);
                acc[nt] = __builtin_amdgcn_mfma_f32_16x16x32_bf16(a, b, acc[nt], 0, 0, 0);
            }
        }
        __syncthreads();
    }

    if (which == 2) {
        #pragma unroll
        for (int nt = 0; nt < 4; ++nt) {
            const float bb = bias[col0 + nt * 16 + m16];
            #pragma unroll
            for (int r = 0; r < 4; ++r)
                Bs[wv * 16 + quad * 4 + r][nt * 16 + m16] =
                    __float2bfloat16(acc[nt][r] + bb);
        }
        __syncthreads();
        const int bb2 = row0 >> 11;
        const int j0 = row0 & (SS - 1);
        const int er = tid >> 2;
        const int js = (tid & 3) * 16;
        unsigned pk[8];
        #pragma unroll
        for (int p = 0; p < 8; ++p) {
            const unsigned lo = *reinterpret_cast<const unsigned short*>(&Bs[js + 2*p][er]);
            const unsigned hi = *reinterpret_cast<const unsigned short*>(&Bs[js + 2*p + 1][er]);
            pk[p] = lo | (hi << 16);
        }
        uint4 s0; s0.x = pk[0]; s0.y = pk[1]; s0.z = pk[2]; s0.w = pk[3];
        uint4 s1; s1.x = pk[4]; s1.y = pk[5]; s1.z = pk[6]; s1.w = pk[7];
        __hip_bfloat16* dst = vT + ((size_t)(bb2 * EE + col0 + er)) * SS + j0 + js;
        *reinterpret_cast<uint4*>(dst) = s0;
        *reinterpret_cast<uint4*>(dst + 8) = s1;
    } else {
        __hip_bfloat16* C = (which == 0) ? qb : kb;
        #pragma unroll
        for (int nt = 0; nt < 4; ++nt) {
            const int gn = col0 + nt * 16 + m16;
            const float bb = bias[gn];
            #pragma unroll
            for (int r = 0; r < 4; ++r) {
                const int gm = row0 + wv * 16 + quad * 4 + r;
                C[(size_t)gm * EE + gn] = __float2bfloat16(acc[nt][r] + bb);
            }
        }
    }
}

// ---------------- MFMA GEMM (MLP1 / MLP2 / out-proj) ----------------
// MODE 0 plain; MODE 1 ldb=520 + const-ef(1/S) tail + GELU; MODE 2 in-place +C_old
template<int MODE, int AF32, int CF32>
__global__ __launch_bounds__(256) void gemm_bt(
    const void* __restrict__ Av,
    const float* __restrict__ W,
    const float* __restrict__ bias,
    void* __restrict__ Cv,
    int ldb)
{
    __shared__ __hip_bfloat16 As[64][72];
    __shared__ __hip_bfloat16 Bs[64][72];
    const int tid = threadIdx.x;
    const int col0 = blockIdx.x * 64;
    const int row0 = blockIdx.y * 64;
    const int wv = tid >> 6, lane = tid & 63, quad = lane >> 4, m16 = lane & 15;
    const int sr = tid >> 2;
    const int sc = (tid & 3) * 16;

    f32x4 acc[4];
    #pragma unroll
    for (int nt = 0; nt < 4; ++nt) acc[nt] = (f32x4){0.f, 0.f, 0.f, 0.f};

    for (int k0 = 0; k0 < 512; k0 += 64) {
        if (AF32) {
            stage16_f32((const float*)Av + (size_t)(row0 + sr) * EE + k0 + sc,
                        &As[sr][sc]);
        } else {
            const uint4* src = reinterpret_cast<const uint4*>(
                (const __hip_bfloat16*)Av + (size_t)(row0 + sr) * EE + k0 + sc);
            uint4* dst = reinterpret_cast<uint4*>(&As[sr][sc]);
            dst[0] = src[0]; dst[1] = src[1];
        }
        stage16_f32(W + (size_t)(col0 + sr) * ldb + k0 + sc, &Bs[sr][sc]);
        __syncthreads();
        #pragma unroll
        for (int ks = 0; ks < 2; ++ks) {
            const short8 a = *reinterpret_cast<const short8*>(
                &As[wv * 16 + m16][ks * 32 + quad * 8]);
            #pragma unroll
            for (int nt = 0; nt < 4; ++nt) {
                const short8 b = *reinterpret_cast<const short8*>(
                    &Bs[nt * 16 + m16][ks * 32 + quad * 8]);
                acc[nt] = __builtin_amdgcn_mfma_f32_16x16x32_bf16(a, b, acc[nt], 0, 0, 0);
            }
        }
        __syncthreads();
    }

    #pragma unroll
    for (int nt = 0; nt < 4; ++nt) {
        const int gn = col0 + nt * 16 + m16;
        float bb = bias[gn];
        if (MODE == 1) {
            float ts = 0.f;
            #pragma unroll
            for (int h = 0; h < 8; ++h) ts += W[(size_t)gn * ldb + 512 + h];
            bb += ts * (1.0f / (float)SS);
        }
        #pragma unroll
        for (int r = 0; r < 4; ++r) {
            const int gm = row0 + wv * 16 + quad * 4 + r;
            const size_t ci = (size_t)gm * EE + gn;
            float c = acc[nt][r] + bb;
            if (MODE == 1) c = 0.5f * c * (1.0f + erff(c * 0.70710678118654752f));
            if (MODE == 2) c += (float)((const __hip_bfloat16*)Cv)[ci];
            if (CF32) ((float*)Cv)[ci] = c;
            else      ((__hip_bfloat16*)Cv)[ci] = __float2bfloat16(c);
        }
    }
}

// ---------------- K1: partial softmax denominators (+ cnt zeroing) ----------------
__global__ __launch_bounds__(256) void attn_denoms(
    const __hip_bfloat16* __restrict__ qws,
    const __hip_bfloat16* __restrict__ kws,
    float* __restrict__ dnP,
    float* __restrict__ cnt)
{
    __shared__ float dpart[4][HH][TI];
    const int tid = threadIdx.x;
    const int wv = tid >> 6, lane = tid & 63, quad = lane >> 4, m16 = lane & 15;
    const int jc = blockIdx.x;
    const int i0 = blockIdx.y * TI;
    const int b  = blockIdx.z;
    const size_t g0 = (size_t)b * SS + i0;
    const size_t gb = (size_t)b * SS;
    const float scale = 0.125f;

    if (jc == 0 && tid < TI) cnt[g0 + tid] = 0.f;

    #pragma unroll
    for (int h = 0; h < HH; ++h) {
        const short8 a0 = *reinterpret_cast<const short8*>(
            qws + (g0 + m16) * EE + h * 64 + quad * 8);
        const short8 a1 = *reinterpret_cast<const short8*>(
            qws + (g0 + m16) * EE + h * 64 + 32 + quad * 8);
        float dp[4] = {0.f, 0.f, 0.f, 0.f};
        #pragma unroll
        for (int jt = 0; jt < 4; ++jt) {
            const int j0 = jc * 256 + wv * 64 + jt * 16;
            const short8 bk0 = *reinterpret_cast<const short8*>(
                kws + (gb + j0 + m16) * EE + h * 64 + quad * 8);
            const short8 bk1 = *reinterpret_cast<const short8*>(
                kws + (gb + j0 + m16) * EE + h * 64 + 32 + quad * 8);
            f32x4 c = {0.f, 0.f, 0.f, 0.f};
            c = __builtin_amdgcn_mfma_f32_16x16x32_bf16(a0, bk0, c, 0, 0, 0);
            c = __builtin_amdgcn_mfma_f32_16x16x32_bf16(a1, bk1, c, 0, 0, 0);
            #pragma unroll
            for (int r = 0; r < 4; ++r) dp[r] += __expf(c[r] * scale);
        }
        #pragma unroll
        for (int off = 1; off <= 8; off <<= 1)
            #pragma unroll
            for (int r = 0; r < 4; ++r) dp[r] += __shfl_xor(dp[r], off, 64);
        if (m16 == 0)
            #pragma unroll
            for (int r = 0; r < 4; ++r) dpart[wv][h][quad * 4 + r] = dp[r];
    }
    __syncthreads();
    if (tid < HH * TI) {
        const int h = tid >> 4, i = tid & 15;
        dnP[((size_t)(jc * BB + b) * SS + i0 + i) * HH + h] =
            dpart[0][h][i] + dpart[1][h][i] + dpart[2][h][i] + dpart[3][h][i];
    }
}

// ---------------- K2: ew tile -> global ewG (+ neighbor count) ----------------
// grid (JCE, SS/TI, BB) = 2048 blocks; 256-j chunk each; coalesced ewG stores.
__global__ __launch_bounds__(256) void attn_ew(
    const __hip_bfloat16* __restrict__ qws,
    const __hip_bfloat16* __restrict__ kws,
    const float* __restrict__ dnP,
    float* __restrict__ cnt,
    __hip_bfloat16* __restrict__ ewG)
{
    __shared__ __hip_bfloat16 aqL[TI][520];
    __shared__ __hip_bfloat16 ewT[TI][264];
    __shared__ float invd[HH][TI];
    __shared__ float cpart[4][TI];
    const int tid = threadIdx.x;
    const int wv = tid >> 6, lane = tid & 63, quad = lane >> 4, m16 = lane & 15;
    const int jc = blockIdx.x;
    const int i0 = blockIdx.y * TI;
    const int b  = blockIdx.z;
    const size_t g0 = (size_t)b * SS + i0;
    const size_t gb = (size_t)b * SS;
    const float scale = 0.125f;

    {
        const int r = tid >> 4;
        const int c0 = (tid & 15) * 32;
        const uint4* src = reinterpret_cast<const uint4*>(qws + (g0 + r) * EE + c0);
        uint4* dst = reinterpret_cast<uint4*>(&aqL[r][c0]);
        dst[0] = src[0]; dst[1] = src[1]; dst[2] = src[2]; dst[3] = src[3];
    }
    if (tid < HH * TI) {
        const int h = tid >> 4, i = tid & 15;
        float s = 0.f;
        #pragma unroll
        for (int c = 0; c < JC1; ++c)
            s += dnP[((size_t)(c * BB + b) * SS + i0 + i) * HH + h];
        invd[h][i] = 1.0f / s;
    }
    __syncthreads();

    float cl[4] = {0.f, 0.f, 0.f, 0.f};
    #pragma unroll
    for (int jt = 0; jt < 4; ++jt) {
        const int j0 = jc * 256 + wv * 64 + jt * 16;
        float wsum[4] = {0.f, 0.f, 0.f, 0.f};
        #pragma unroll 2
        for (int h = 0; h < HH; ++h) {
            const short8 a0 = *reinterpret_cast<const short8*>(&aqL[m16][h * 64 + quad * 8]);
            const short8 a1 = *reinterpret_cast<const short8*>(&aqL[m16][h * 64 + 32 + quad * 8]);
            const short8 bk0 = *reinterpret_cast<const short8*>(
                kws + (gb + j0 + m16) * EE + h * 64 + quad * 8);
            const short8 bk1 = *reinterpret_cast<const short8*>(
                kws + (gb + j0 + m16) * EE + h * 64 + 32 + quad * 8);
            f32x4 c = {0.f, 0.f, 0.f, 0.f};
            c = __builtin_amdgcn_mfma_f32_16x16x32_bf16(a0, bk0, c, 0, 0, 0);
            c = __builtin_amdgcn_mfma_f32_16x16x32_bf16(a1, bk1, c, 0, 0, 0);
            #pragma unroll
            for (int r = 0; r < 4; ++r)
                wsum[r] += __expf(c[r] * scale) * invd[h][quad * 4 + r];
        }
        const int jloc = wv * 64 + jt * 16 + m16;
        #pragma unroll
        for (int r = 0; r < 4; ++r) {
            const __hip_bfloat16 wb = __float2bfloat16(wsum[r] * 0.125f);
            if ((float)wb > 0.1f) cl[r] += 1.f;
            ewT[quad * 4 + r][jloc] = wb;
        }
    }
    #pragma unroll
    for (int off = 1; off <= 8; off <<= 1)
        #pragma unroll
        for (int r = 0; r < 4; ++r) cl[r] += __shfl_xor(cl[r], off, 64);
    if (m16 == 0)
        #pragma unroll
        for (int r = 0; r < 4; ++r) cpart[wv][quad * 4 + r] = cl[r];
    __syncthreads();
    if (tid < TI) {
        const float c = cpart[0][tid] + cpart[1][tid] + cpart[2][tid] + cpart[3][tid];
        if (c != 0.f) atomicAdd(&cnt[g0 + tid], c);
    }

    // coalesced copy-out: 16 rows x 256 cols
    const int row = tid >> 4;
    const int cs = (tid & 15) * 16;
    const uint4* s = reinterpret_cast<const uint4*>(&ewT[row][cs]);
    uint4* d = reinterpret_cast<uint4*>(
        ewG + ((size_t)(gb + i0 + row)) * SS + jc * 256 + cs);
    d[0] = s[0]; d[1] = s[1];
}

// ---------------- K3: u1 = ewG @ V via clean MFMA GEMM (K=2048) ----------------
// grid (EE/64, NN/64). A=ewG rows (coalesced), B=vT rows (coalesced). Epilogue
// adds exact rare masked-aggregation path (cnt>0, never taken for this data)
// and writes u1 bf16 into qb rows (q dead).
__global__ __launch_bounds__(256) void attn_pv_gemm(
    const __hip_bfloat16* __restrict__ ewG,
    const __hip_bfloat16* __restrict__ vT,
    const float* __restrict__ cnt,
    const float* __restrict__ x,
    __hip_bfloat16* __restrict__ u1out)
{
    __shared__ __hip_bfloat16 As[64][72];
    __shared__ __hip_bfloat16 Bs[64][72];
    __shared__ float cntL[64];
    const int tid = threadIdx.x;
    const int col0 = blockIdx.x * 64;
    const int row0 = blockIdx.y * 64;
    const int b = row0 >> 11;
    const int i0 = row0 & (SS - 1);
    const int wv = tid >> 6, lane = tid & 63, quad = lane >> 4, m16 = lane & 15;
    const int sr = tid >> 2;
    const int sc = (tid & 3) * 16;
    const __hip_bfloat16* Abase = ewG + ((size_t)b * SS + i0) * SS;
    const __hip_bfloat16* Bbase = vT + ((size_t)(b * EE + col0)) * SS;

    if (tid < 64) cntL[tid] = cnt[(size_t)row0 + tid];

    f32x4 acc[4];
    #pragma unroll
    for (int nt = 0; nt < 4; ++nt) acc[nt] = (f32x4){0.f, 0.f, 0.f, 0.f};

    for (int k0 = 0; k0 < SS; k0 += 64) {
        const uint4* sa = reinterpret_cast<const uint4*>(Abase + (size_t)sr * SS + k0 + sc);
        uint4* da = reinterpret_cast<uint4*>(&As[sr][sc]);
        da[0] = sa[0]; da[1] = sa[1];
        const uint4* sb = reinterpret_cast<const uint4*>(Bbase + (size_t)sr * SS + k0 + sc);
        uint4* db = reinterpret_cast<uint4*>(&Bs[sr][sc]);
        db[0] = sb[0]; db[1] = sb[1];
        __syncthreads();
        #pragma unroll
        for (int ks = 0; ks < 2; ++ks) {
            const short8 a = *reinterpret_cast<const short8*>(
                &As[wv * 16 + m16][ks * 32 + quad * 8]);
            #pragma unroll
            for (int nt = 0; nt < 4; ++nt) {
                const short8 bfr = *reinterpret_cast<const short8*>(
                    &Bs[nt * 16 + m16][ks * 32 + quad * 8]);
                acc[nt] = __builtin_amdgcn_mfma_f32_16x16x32_bf16(a, bfr, acc[nt], 0, 0, 0);
            }
        }
        __syncthreads();
    }

    #pragma unroll
    for (int nt = 0; nt < 4; ++nt) {
        const int gn = col0 + nt * 16 + m16;
        #pragma unroll
        for (int r = 0; r < 4; ++r) {
            const int lr = wv * 16 + quad * 4 + r;
            const int gm = row0 + lr;
            float val = acc[nt][r];
            const float c = cntL[lr];
            if (c > 0.f) {   // exact rare path: masked mean aggregation
                float m = 0.f;
                const __hip_bfloat16* er = Abase + (size_t)lr * SS;
                for (int j = 0; j < SS; ++j) {
                    const float w = (float)er[j];
                    if (w > 0.1f) m += w * x[((size_t)b * SS + j) * EE + gn];
                }
                val += m / c;
            }
            u1out[(size_t)gm * EE + gn] = __float2bfloat16(val);
        }
    }
}

extern "C" void kernel_launch(void* const* d_in, const int* in_sizes, int n_in,
                              void* d_out, int out_size, void* d_ws, size_t ws_size,
                              hipStream_t stream)
{
    const float* x   = (const float*)d_in[0];
    const float* Wq  = (const float*)d_in[1];
    const float* bq  = (const float*)d_in[2];
    const float* Wk  = (const float*)d_in[3];
    const float* bk  = (const float*)d_in[4];
    const float* Wv  = (const float*)d_in[5];
    const float* bv  = (const float*)d_in[6];
    const float* Wm1 = (const float*)d_in[7];
    const float* bm1 = (const float*)d_in[8];
    const float* Wm2 = (const float*)d_in[9];
    const float* bm2 = (const float*)d_in[10];
    const float* Wo  = (const float*)d_in[11];
    const float* bo  = (const float*)d_in[12];

    // ws layout (<= 30 MB; ws_size >= 30 MB confirmed by r8 fast-path run)
    char* ws = (char*)d_ws;
    const size_t MB = 1024 * 1024;
    __hip_bfloat16* qb = (__hip_bfloat16*)(ws + 0);        // q -> u1 -> t   4MB
    __hip_bfloat16* kb = (__hip_bfloat16*)(ws + 4*MB);     // k -> hm        4MB
    __hip_bfloat16* vT = (__hip_bfloat16*)(ws + 8*MB);     // V^T [b][e][j]  4MB
    __hip_bfloat16* ewG = (__hip_bfloat16*)(ws + 12*MB);   // ew [B,S,S]    16MB
    float* dnP = (float*)(ws + 28*MB);                     // denom partials 1MB
    float* cnt = (float*)(ws + 29*MB);                     // neighbor cnt  16KB

    dim3 blk(256, 1, 1);
    dim3 gg(EE / 64, NN / 64, 1);

    qkv_gemm<<<dim3(24, NN / 64, 1), blk, 0, stream>>>(
        x, Wq, bq, Wk, bk, Wv, bv, qb, kb, vT);
    attn_denoms<<<dim3(JC1, SS / TI, BB), blk, 0, stream>>>(qb, kb, dnP, cnt);
    attn_ew<<<dim3(JCE, SS / TI, BB), blk, 0, stream>>>(qb, kb, dnP, cnt, ewG);
    attn_pv_gemm<<<gg, blk, 0, stream>>>(ewG, vT, cnt, x, qb);          // u1 -> qb
    gemm_bt<1,1,0><<<gg, blk, 0, stream>>>(x, Wm1, bm1, kb, EE + HH);   // hm
    gemm_bt<2,0,0><<<gg, blk, 0, stream>>>(kb, Wm2, bm2, qb, EE);       // t = MLP2 + u1
    gemm_bt<0,0,1><<<gg, blk, 0, stream>>>(qb, Wo, bo, d_out, EE);      // out f32
}

// Round 13
// 319.188 us; speedup vs baseline: 7.6279x; 1.0872x over previous
//
#include <hip/hip_runtime.h>
#include <hip/hip_bf16.h>
#include <math.h>

#define BB 2
#define SS 2048
#define EE 512
#define HH 8
#define NN (BB*SS)
#define TI 16
#define JC1 8   // denoms j-chunks (256 j each)
#define JCE 8   // ew j-chunks (256 j each)

typedef __attribute__((ext_vector_type(8))) short short8;
typedef __attribute__((ext_vector_type(4))) float f32x4;

__device__ __forceinline__ float bflo(unsigned u){ return __uint_as_float(u << 16); }
__device__ __forceinline__ float bfhi(unsigned u){ return __uint_as_float(u & 0xffff0000u); }
__device__ __forceinline__ unsigned f2bf(float f){
    unsigned u = __float_as_uint(f);
    u += 0x7fffu + ((u >> 16) & 1u);
    return u >> 16;
}
__device__ __forceinline__ void stage16_f32(const float* __restrict__ src,
                                            __hip_bfloat16* dst){
    const float4 f0 = *reinterpret_cast<const float4*>(src);
    const float4 f1 = *reinterpret_cast<const float4*>(src + 4);
    const float4 f2 = *reinterpret_cast<const float4*>(src + 8);
    const float4 f3 = *reinterpret_cast<const float4*>(src + 12);
    uint4 o0, o1;
    o0.x = f2bf(f0.x) | (f2bf(f0.y) << 16);
    o0.y = f2bf(f0.z) | (f2bf(f0.w) << 16);
    o0.z = f2bf(f1.x) | (f2bf(f1.y) << 16);
    o0.w = f2bf(f1.z) | (f2bf(f1.w) << 16);
    o1.x = f2bf(f2.x) | (f2bf(f2.y) << 16);
    o1.y = f2bf(f2.z) | (f2bf(f2.w) << 16);
    o1.z = f2bf(f3.x) | (f2bf(f3.y) << 16);
    o1.w = f2bf(f3.z) | (f2bf(f3.w) << 16);
    *reinterpret_cast<uint4*>(dst) = o0;
    *reinterpret_cast<uint4*>(dst + 8) = o1;
}
__device__ __forceinline__ void stage16_b16(const __hip_bfloat16* __restrict__ src,
                                            __hip_bfloat16* dst){
    const uint4* s = reinterpret_cast<const uint4*>(src);
    uint4* d = reinterpret_cast<uint4*>(dst);
    d[0] = s[0]; d[1] = s[1];
}

// ---------------- one-time f32 -> bf16 conversion of x + 6 weights ----------------
__global__ void conv_bf16(
    const float* s0, const float* s1, const float* s2, const float* s3,
    const float* s4, const float* s5, const float* s6,
    __hip_bfloat16* d0, __hip_bfloat16* d1, __hip_bfloat16* d2, __hip_bfloat16* d3,
    __hip_bfloat16* d4, __hip_bfloat16* d5, __hip_bfloat16* d6)
{
    const int which = blockIdx.y;
    const float* s; __hip_bfloat16* d; int n;
    switch (which) {
        case 0: s = s0; d = d0; n = 2097152; break;
        case 1: s = s1; d = d1; n = 262144; break;
        case 2: s = s2; d = d2; n = 262144; break;
        case 3: s = s3; d = d3; n = 262144; break;
        case 4: s = s4; d = d4; n = 266240; break;
        case 5: s = s5; d = d5; n = 262144; break;
        default: s = s6; d = d6; n = 262144; break;
    }
    const int base = (blockIdx.x * 256 + threadIdx.x) * 4;
    if (base >= n) return;
    const float4 f = *reinterpret_cast<const float4*>(s + base);
    uint2 o;
    o.x = f2bf(f.x) | (f2bf(f.y) << 16);
    o.y = f2bf(f.z) | (f2bf(f.w) << 16);
    *reinterpret_cast<uint2*>(d + base) = o;
}

// ---------------- fused QKV projection (MFMA) ----------------
// B16=1: x/W already bf16 (staging = pure copy).
template<int B16>
__global__ __launch_bounds__(256) void qkv_gemm(
    const void* __restrict__ x,
    const void* __restrict__ Wq, const float* __restrict__ bq,
    const void* __restrict__ Wk, const float* __restrict__ bk,
    const void* __restrict__ Wv, const float* __restrict__ bv,
    __hip_bfloat16* __restrict__ qb,
    __hip_bfloat16* __restrict__ kb,
    __hip_bfloat16* __restrict__ vT)
{
    __shared__ __hip_bfloat16 As[64][72];
    __shared__ __hip_bfloat16 Bs[64][72];
    const int tid = threadIdx.x;
    const int which = blockIdx.x >> 3;
    const int col0 = (blockIdx.x & 7) * 64;
    const int row0 = blockIdx.y * 64;
    const int wv = tid >> 6, lane = tid & 63, quad = lane >> 4, m16 = lane & 15;
    const int sr = tid >> 2;
    const int sc = (tid & 3) * 16;
    const void* W    = (which == 0) ? Wq : (which == 1) ? Wk : Wv;
    const float* bias = (which == 0) ? bq : (which == 1) ? bk : bv;

    f32x4 acc[4];
    #pragma unroll
    for (int nt = 0; nt < 4; ++nt) acc[nt] = (f32x4){0.f, 0.f, 0.f, 0.f};

    for (int k0 = 0; k0 < 512; k0 += 64) {
        if (B16) {
            stage16_b16((const __hip_bfloat16*)x + (size_t)(row0 + sr) * EE + k0 + sc, &As[sr][sc]);
            stage16_b16((const __hip_bfloat16*)W + (size_t)(col0 + sr) * EE + k0 + sc, &Bs[sr][sc]);
        } else {
            stage16_f32((const float*)x + (size_t)(row0 + sr) * EE + k0 + sc, &As[sr][sc]);
            stage16_f32((const float*)W + (size_t)(col0 + sr) * EE + k0 + sc, &Bs[sr][sc]);
        }
        __syncthreads();
        #pragma unroll
        for (int ks = 0; ks < 2; ++ks) {
            const short8 a = *reinterpret_cast<const short8*>(
                &As[wv * 16 + m16][ks * 32 + quad * 8]);
            #pragma unroll
            for (int nt = 0; nt < 4; ++nt) {
                const short8 b = *reinterpret_cast<const short8*>(
                    &Bs[nt * 16 + m16][ks * 32 + quad * 8]);
                acc[nt] = __builtin_amdgcn_mfma_f32_16x16x32_bf16(a, b, acc[nt], 0, 0, 0);
            }
        }
        __syncthreads();
    }

    if (which == 2) {
        #pragma unroll
        for (int nt = 0; nt < 4; ++nt) {
            const float bb = bias[col0 + nt * 16 + m16];
            #pragma unroll
            for (int r = 0; r < 4; ++r)
                Bs[wv * 16 + quad * 4 + r][nt * 16 + m16] =
                    __float2bfloat16(acc[nt][r] + bb);
        }
        __syncthreads();
        const int bb2 = row0 >> 11;
        const int j0 = row0 & (SS - 1);
        const int er = tid >> 2;
        const int js = (tid & 3) * 16;
        unsigned pk[8];
        #pragma unroll
        for (int p = 0; p < 8; ++p) {
            const unsigned lo = *reinterpret_cast<const unsigned short*>(&Bs[js + 2*p][er]);
            const unsigned hi = *reinterpret_cast<const unsigned short*>(&Bs[js + 2*p + 1][er]);
            pk[p] = lo | (hi << 16);
        }
        uint4 s0; s0.x = pk[0]; s0.y = pk[1]; s0.z = pk[2]; s0.w = pk[3];
        uint4 s1; s1.x = pk[4]; s1.y = pk[5]; s1.z = pk[6]; s1.w = pk[7];
        __hip_bfloat16* dst = vT + ((size_t)(bb2 * EE + col0 + er)) * SS + j0 + js;
        *reinterpret_cast<uint4*>(dst) = s0;
        *reinterpret_cast<uint4*>(dst + 8) = s1;
    } else {
        __hip_bfloat16* C = (which == 0) ? qb : kb;
        #pragma unroll
        for (int nt = 0; nt < 4; ++nt) {
            const int gn = col0 + nt * 16 + m16;
            const float bb = bias[gn];
            #pragma unroll
            for (int r = 0; r < 4; ++r) {
                const int gm = row0 + wv * 16 + quad * 4 + r;
                C[(size_t)gm * EE + gn] = __float2bfloat16(acc[nt][r] + bb);
            }
        }
    }
}

// ---------------- MFMA GEMM (MLP1 / MLP2 / out-proj) ----------------
// MODE 0 plain; MODE 1 ldb=520 + const-ef(1/S) tail + GELU; MODE 2 in-place +C_old
// AB16: A is bf16 (else f32).  WB16: W is bf16 (else f32).  CF32: C f32 out.
template<int MODE, int AB16, int WB16, int CF32>
__global__ __launch_bounds__(256) void gemm_bt(
    const void* __restrict__ Av,
    const void* __restrict__ Wv_,
    const float* __restrict__ bias,
    void* __restrict__ Cv,
    int ldb)
{
    __shared__ __hip_bfloat16 As[64][72];
    __shared__ __hip_bfloat16 Bs[64][72];
    const int tid = threadIdx.x;
    const int col0 = blockIdx.x * 64;
    const int row0 = blockIdx.y * 64;
    const int wv = tid >> 6, lane = tid & 63, quad = lane >> 4, m16 = lane & 15;
    const int sr = tid >> 2;
    const int sc = (tid & 3) * 16;

    f32x4 acc[4];
    #pragma unroll
    for (int nt = 0; nt < 4; ++nt) acc[nt] = (f32x4){0.f, 0.f, 0.f, 0.f};

    for (int k0 = 0; k0 < 512; k0 += 64) {
        if (AB16)
            stage16_b16((const __hip_bfloat16*)Av + (size_t)(row0 + sr) * EE + k0 + sc, &As[sr][sc]);
        else
            stage16_f32((const float*)Av + (size_t)(row0 + sr) * EE + k0 + sc, &As[sr][sc]);
        if (WB16)
            stage16_b16((const __hip_bfloat16*)Wv_ + (size_t)(col0 + sr) * ldb + k0 + sc, &Bs[sr][sc]);
        else
            stage16_f32((const float*)Wv_ + (size_t)(col0 + sr) * ldb + k0 + sc, &Bs[sr][sc]);
        __syncthreads();
        #pragma unroll
        for (int ks = 0; ks < 2; ++ks) {
            const short8 a = *reinterpret_cast<const short8*>(
                &As[wv * 16 + m16][ks * 32 + quad * 8]);
            #pragma unroll
            for (int nt = 0; nt < 4; ++nt) {
                const short8 b = *reinterpret_cast<const short8*>(
                    &Bs[nt * 16 + m16][ks * 32 + quad * 8]);
                acc[nt] = __builtin_amdgcn_mfma_f32_16x16x32_bf16(a, b, acc[nt], 0, 0, 0);
            }
        }
        __syncthreads();
    }

    #pragma unroll
    for (int nt = 0; nt < 4; ++nt) {
        const int gn = col0 + nt * 16 + m16;
        float bb = bias[gn];
        if (MODE == 1) {
            float ts = 0.f;
            #pragma unroll
            for (int h = 0; h < 8; ++h) {
                const size_t wi = (size_t)gn * ldb + 512 + h;
                ts += WB16 ? (float)((const __hip_bfloat16*)Wv_)[wi]
                           : ((const float*)Wv_)[wi];
            }
            bb += ts * (1.0f / (float)SS);
        }
        #pragma unroll
        for (int r = 0; r < 4; ++r) {
            const int gm = row0 + wv * 16 + quad * 4 + r;
            const size_t ci = (size_t)gm * EE + gn;
            float c = acc[nt][r] + bb;
            if (MODE == 1) c = 0.5f * c * (1.0f + erff(c * 0.70710678118654752f));
            if (MODE == 2) c += (float)((const __hip_bfloat16*)Cv)[ci];
            if (CF32) ((float*)Cv)[ci] = c;
            else      ((__hip_bfloat16*)Cv)[ci] = __float2bfloat16(c);
        }
    }
}

// ---------------- K1: partial softmax denominators (pipelined) ----------------
__global__ __launch_bounds__(256) void attn_denoms(
    const __hip_bfloat16* __restrict__ qws,
    const __hip_bfloat16* __restrict__ kws,
    float* __restrict__ dnP,
    float* __restrict__ cnt)
{
    __shared__ __hip_bfloat16 aqL[TI][520];
    __shared__ float dpart[4][HH][TI];
    const int tid = threadIdx.x;
    const int wv = tid >> 6, lane = tid & 63, quad = lane >> 4, m16 = lane & 15;
    const int jc = blockIdx.x;
    const int i0 = blockIdx.y * TI;
    const int b  = blockIdx.z;
    const size_t g0 = (size_t)b * SS + i0;
    const size_t gb = (size_t)b * SS;
    const float scale = 0.125f;

    if (jc == 0 && tid < TI) cnt[g0 + tid] = 0.f;
    {   // stage Q tile (coalesced)
        const int r = tid >> 4;
        const int c0 = (tid & 15) * 32;
        const uint4* src = reinterpret_cast<const uint4*>(qws + (g0 + r) * EE + c0);
        uint4* dst = reinterpret_cast<uint4*>(&aqL[r][c0]);
        dst[0] = src[0]; dst[1] = src[1]; dst[2] = src[2]; dst[3] = src[3];
    }
    __syncthreads();

    // flattened t = h*4 + jt; 2-deep K prefetch
    const int jbase = jc * 256 + wv * 64;
    auto kptr = [&](int t, int half) -> const short8* {
        const int h = t >> 2, jt = t & 3;
        return reinterpret_cast<const short8*>(
            kws + (gb + jbase + jt * 16 + m16) * EE + h * 64 + half * 32 + quad * 8);
    };
    short8 kA0 = *kptr(0, 0), kB0 = *kptr(0, 1);
    short8 kA1 = *kptr(1, 0), kB1 = *kptr(1, 1);
    float dp[4] = {0.f, 0.f, 0.f, 0.f};

    auto step = [&](int t, short8& ka, short8& kb_) {
        const int h = t >> 2;
        const short8 a0 = *reinterpret_cast<const short8*>(&aqL[m16][h * 64 + quad * 8]);
        const short8 a1 = *reinterpret_cast<const short8*>(&aqL[m16][h * 64 + 32 + quad * 8]);
        f32x4 c = {0.f, 0.f, 0.f, 0.f};
        c = __builtin_amdgcn_mfma_f32_16x16x32_bf16(a0, ka, c, 0, 0, 0);
        c = __builtin_amdgcn_mfma_f32_16x16x32_bf16(a1, kb_, c, 0, 0, 0);
        if (t < 30) { ka = *kptr(t + 2, 0); kb_ = *kptr(t + 2, 1); }
        #pragma unroll
        for (int r = 0; r < 4; ++r) dp[r] += __expf(c[r] * scale);
        if ((t & 3) == 3) {
            #pragma unroll
            for (int off = 1; off <= 8; off <<= 1)
                #pragma unroll
                for (int r = 0; r < 4; ++r) dp[r] += __shfl_xor(dp[r], off, 64);
            if (m16 == 0)
                #pragma unroll
                for (int r = 0; r < 4; ++r) dpart[wv][h][quad * 4 + r] = dp[r];
            #pragma unroll
            for (int r = 0; r < 4; ++r) dp[r] = 0.f;
        }
    };
    for (int tt = 0; tt < 32; tt += 2) { step(tt, kA0, kB0); step(tt + 1, kA1, kB1); }

    __syncthreads();
    if (tid < HH * TI) {
        const int h = tid >> 4, i = tid & 15;
        dnP[((size_t)(jc * BB + b) * SS + i0 + i) * HH + h] =
            dpart[0][h][i] + dpart[1][h][i] + dpart[2][h][i] + dpart[3][h][i];
    }
}

// ---------------- K2: ew tile -> global ewG (pipelined) ----------------
__global__ __launch_bounds__(256) void attn_ew(
    const __hip_bfloat16* __restrict__ qws,
    const __hip_bfloat16* __restrict__ kws,
    const float* __restrict__ dnP,
    float* __restrict__ cnt,
    __hip_bfloat16* __restrict__ ewG)
{
    __shared__ __hip_bfloat16 aqL[TI][520];
    __shared__ __hip_bfloat16 ewT[TI][264];
    __shared__ float invd[HH][TI];
    __shared__ float cpart[4][TI];
    const int tid = threadIdx.x;
    const int wv = tid >> 6, lane = tid & 63, quad = lane >> 4, m16 = lane & 15;
    const int jc = blockIdx.x;
    const int i0 = blockIdx.y * TI;
    const int b  = blockIdx.z;
    const size_t g0 = (size_t)b * SS + i0;
    const size_t gb = (size_t)b * SS;
    const float scale = 0.125f;

    {
        const int r = tid >> 4;
        const int c0 = (tid & 15) * 32;
        const uint4* src = reinterpret_cast<const uint4*>(qws + (g0 + r) * EE + c0);
        uint4* dst = reinterpret_cast<uint4*>(&aqL[r][c0]);
        dst[0] = src[0]; dst[1] = src[1]; dst[2] = src[2]; dst[3] = src[3];
    }
    if (tid < HH * TI) {
        const int h = tid >> 4, i = tid & 15;
        float s = 0.f;
        #pragma unroll
        for (int c = 0; c < JC1; ++c)
            s += dnP[((size_t)(c * BB + b) * SS + i0 + i) * HH + h];
        invd[h][i] = 0.125f / s;   // head-mean folded in
    }
    __syncthreads();

    // flattened t = jt*8 + h; 2-deep K prefetch
    const int jbase = jc * 256 + wv * 64;
    auto kptr = [&](int t, int half) -> const short8* {
        const int jt = t >> 3, h = t & 7;
        return reinterpret_cast<const short8*>(
            kws + (gb + jbase + jt * 16 + m16) * EE + h * 64 + half * 32 + quad * 8);
    };
    short8 kA0 = *kptr(0, 0), kB0 = *kptr(0, 1);
    short8 kA1 = *kptr(1, 0), kB1 = *kptr(1, 1);
    float wsum[4] = {0.f, 0.f, 0.f, 0.f};
    float cl[4] = {0.f, 0.f, 0.f, 0.f};

    auto step = [&](int t, short8& ka, short8& kb_) {
        const int h = t & 7;
        const short8 a0 = *reinterpret_cast<const short8*>(&aqL[m16][h * 64 + quad * 8]);
        const short8 a1 = *reinterpret_cast<const short8*>(&aqL[m16][h * 64 + 32 + quad * 8]);
        f32x4 c = {0.f, 0.f, 0.f, 0.f};
        c = __builtin_amdgcn_mfma_f32_16x16x32_bf16(a0, ka, c, 0, 0, 0);
        c = __builtin_amdgcn_mfma_f32_16x16x32_bf16(a1, kb_, c, 0, 0, 0);
        if (t < 30) { ka = *kptr(t + 2, 0); kb_ = *kptr(t + 2, 1); }
        #pragma unroll
        for (int r = 0; r < 4; ++r)
            wsum[r] += __expf(c[r] * scale) * invd[h][quad * 4 + r];
        if (h == 7) {
            const int jloc = wv * 64 + (t >> 3) * 16 + m16;
            #pragma unroll
            for (int r = 0; r < 4; ++r) {
                const __hip_bfloat16 wb = __float2bfloat16(wsum[r]);
                if ((float)wb > 0.1f) cl[r] += 1.f;
                ewT[quad * 4 + r][jloc] = wb;
                wsum[r] = 0.f;
            }
        }
    };
    for (int tt = 0; tt < 32; tt += 2) { step(tt, kA0, kB0); step(tt + 1, kA1, kB1); }

    #pragma unroll
    for (int off = 1; off <= 8; off <<= 1)
        #pragma unroll
        for (int r = 0; r < 4; ++r) cl[r] += __shfl_xor(cl[r], off, 64);
    if (m16 == 0)
        #pragma unroll
        for (int r = 0; r < 4; ++r) cpart[wv][quad * 4 + r] = cl[r];
    __syncthreads();
    if (tid < TI) {
        const float c = cpart[0][tid] + cpart[1][tid] + cpart[2][tid] + cpart[3][tid];
        if (c != 0.f) atomicAdd(&cnt[g0 + tid], c);
    }

    // coalesced copy-out: 16 rows x 256 cols
    const int row = tid >> 4;
    const int cs = (tid & 15) * 16;
    const uint4* s = reinterpret_cast<const uint4*>(&ewT[row][cs]);
    uint4* d = reinterpret_cast<uint4*>(
        ewG + ((size_t)(gb + i0 + row)) * SS + jc * 256 + cs);
    d[0] = s[0]; d[1] = s[1];
}

// ---------------- K3: u1 = ewG @ V via MFMA GEMM (K=2048) ----------------
__global__ __launch_bounds__(256) void attn_pv_gemm(
    const __hip_bfloat16* __restrict__ ewG,
    const __hip_bfloat16* __restrict__ vT,
    const float* __restrict__ cnt,
    const float* __restrict__ x,
    __hip_bfloat16* __restrict__ u1out)
{
    __shared__ __hip_bfloat16 As[64][72];
    __shared__ __hip_bfloat16 Bs[64][72];
    __shared__ float cntL[64];
    const int tid = threadIdx.x;
    const int col0 = blockIdx.x * 64;
    const int row0 = blockIdx.y * 64;
    const int b = row0 >> 11;
    const int i0 = row0 & (SS - 1);
    const int wv = tid >> 6, lane = tid & 63, quad = lane >> 4, m16 = lane & 15;
    const int sr = tid >> 2;
    const int sc = (tid & 3) * 16;
    const __hip_bfloat16* Abase = ewG + ((size_t)b * SS + i0) * SS;
    const __hip_bfloat16* Bbase = vT + ((size_t)(b * EE + col0)) * SS;

    if (tid < 64) cntL[tid] = cnt[(size_t)row0 + tid];

    f32x4 acc[4];
    #pragma unroll
    for (int nt = 0; nt < 4; ++nt) acc[nt] = (f32x4){0.f, 0.f, 0.f, 0.f};

    for (int k0 = 0; k0 < SS; k0 += 64) {
        const uint4* sa = reinterpret_cast<const uint4*>(Abase + (size_t)sr * SS + k0 + sc);
        uint4* da = reinterpret_cast<uint4*>(&As[sr][sc]);
        da[0] = sa[0]; da[1] = sa[1];
        const uint4* sb = reinterpret_cast<const uint4*>(Bbase + (size_t)sr * SS + k0 + sc);
        uint4* db = reinterpret_cast<uint4*>(&Bs[sr][sc]);
        db[0] = sb[0]; db[1] = sb[1];
        __syncthreads();
        #pragma unroll
        for (int ks = 0; ks < 2; ++ks) {
            const short8 a = *reinterpret_cast<const short8*>(
                &As[wv * 16 + m16][ks * 32 + quad * 8]);
            #pragma unroll
            for (int nt = 0; nt < 4; ++nt) {
                const short8 bfr = *reinterpret_cast<const short8*>(
                    &Bs[nt * 16 + m16][ks * 32 + quad * 8]);
                acc[nt] = __builtin_amdgcn_mfma_f32_16x16x32_bf16(a, bfr, acc[nt], 0, 0, 0);
            }
        }
        __syncthreads();
    }

    #pragma unroll
    for (int nt = 0; nt < 4; ++nt) {
        const int gn = col0 + nt * 16 + m16;
        #pragma unroll
        for (int r = 0; r < 4; ++r) {
            const int lr = wv * 16 + quad * 4 + r;
            const int gm = row0 + lr;
            float val = acc[nt][r];
            const float c = cntL[lr];
            if (c > 0.f) {   // exact rare path: masked mean aggregation
                float m = 0.f;
                const __hip_bfloat16* er = Abase + (size_t)lr * SS;
                for (int j = 0; j < SS; ++j) {
                    const float w = (float)er[j];
                    if (w > 0.1f) m += w * x[((size_t)b * SS + j) * EE + gn];
                }
                val += m / c;
            }
            u1out[(size_t)gm * EE + gn] = __float2bfloat16(val);
        }
    }
}

extern "C" void kernel_launch(void* const* d_in, const int* in_sizes, int n_in,
                              void* d_out, int out_size, void* d_ws, size_t ws_size,
                              hipStream_t stream)
{
    const float* x   = (const float*)d_in[0];
    const float* Wq  = (const float*)d_in[1];
    const float* bq  = (const float*)d_in[2];
    const float* Wk  = (const float*)d_in[3];
    const float* bk  = (const float*)d_in[4];
    const float* Wv  = (const float*)d_in[5];
    const float* bv  = (const float*)d_in[6];
    const float* Wm1 = (const float*)d_in[7];
    const float* bm1 = (const float*)d_in[8];
    const float* Wm2 = (const float*)d_in[9];
    const float* bm2 = (const float*)d_in[10];
    const float* Wo  = (const float*)d_in[11];
    const float* bo  = (const float*)d_in[12];

    char* ws = (char*)d_ws;
    const size_t MB = 1024 * 1024;
    __hip_bfloat16* qb = (__hip_bfloat16*)(ws + 0);        // q -> u1 -> t   4MB
    __hip_bfloat16* kb = (__hip_bfloat16*)(ws + 4*MB);     // k -> hm        4MB
    __hip_bfloat16* vT = (__hip_bfloat16*)(ws + 8*MB);     // V^T [b][e][j]  4MB
    __hip_bfloat16* ewG = (__hip_bfloat16*)(ws + 12*MB);   // ew [B,S,S]    16MB
    float* dnP = (float*)(ws + 28*MB);                     // denom partials 1MB
    float* cnt = (float*)(ws + 29*MB);                     // neighbor cnt  16KB
    // extended region (only if ws_size >= 38MB): bf16 copies of x + weights
    const bool EXT = (ws_size >= 38 * MB);
    __hip_bfloat16* xb   = (__hip_bfloat16*)(ws + 30*MB);          // 4MB
    __hip_bfloat16* wqb  = (__hip_bfloat16*)(ws + 34*MB);          // 512KB
    __hip_bfloat16* wkb  = (__hip_bfloat16*)(ws + 34*MB + 512*1024);
    __hip_bfloat16* wvb  = (__hip_bfloat16*)(ws + 35*MB);
    __hip_bfloat16* wm1b = (__hip_bfloat16*)(ws + 35*MB + 512*1024); // 520KB
    __hip_bfloat16* wm2b = (__hip_bfloat16*)(ws + 36*MB + 256*1024);
    __hip_bfloat16* wob  = (__hip_bfloat16*)(ws + 36*MB + 768*1024); // ends < 37.3MB

    dim3 blk(256, 1, 1);
    dim3 gg(EE / 64, NN / 64, 1);

    if (EXT) {
        conv_bf16<<<dim3(2048, 7, 1), blk, 0, stream>>>(
            x, Wq, Wk, Wv, Wm1, Wm2, Wo, xb, wqb, wkb, wvb, wm1b, wm2b, wob);
        qkv_gemm<1><<<dim3(24, NN / 64, 1), blk, 0, stream>>>(
            xb, wqb, bq, wkb, bk, wvb, bv, qb, kb, vT);
    } else {
        qkv_gemm<0><<<dim3(24, NN / 64, 1), blk, 0, stream>>>(
            x, Wq, bq, Wk, bk, Wv, bv, qb, kb, vT);
    }
    attn_denoms<<<dim3(JC1, SS / TI, BB), blk, 0, stream>>>(qb, kb, dnP, cnt);
    attn_ew<<<dim3(JCE, SS / TI, BB), blk, 0, stream>>>(qb, kb, dnP, cnt, ewG);
    attn_pv_gemm<<<gg, blk, 0, stream>>>(ewG, vT, cnt, x, qb);          // u1 -> qb
    if (EXT) {
        gemm_bt<1,1,1,0><<<gg, blk, 0, stream>>>(xb, wm1b, bm1, kb, EE + HH);
        gemm_bt<2,1,1,0><<<gg, blk, 0, stream>>>(kb, wm2b, bm2, qb, EE);
        gemm_bt<0,1,1,1><<<gg, blk, 0, stream>>>(qb, wob, bo, d_out, EE);
    } else {
        gemm_bt<1,0,0,0><<<gg, blk, 0, stream>>>(x, Wm1, bm1, kb, EE + HH);
        gemm_bt<2,1,0,0><<<gg, blk, 0, stream>>>(kb, Wm2, bm2, qb, EE);
        gemm_bt<0,1,0,1><<<gg, blk, 0, stream>>>(qb, Wo, bo, d_out, EE);
    }
}

// Round 14
// 261.810 us; speedup vs baseline: 9.2996x; 1.2192x over previous
//
#include <hip/hip_runtime.h>
#include <hip/hip_bf16.h>
#include <math.h>

#define BB 2
#define SS 2048
#define EE 512
#define HH 8
#define NN (BB*SS)
#define JC1 8   // denoms j-chunks (256 j each)
#define JCE 16  // ew j-chunks (128 j each)

typedef __attribute__((ext_vector_type(8))) short short8;
typedef __attribute__((ext_vector_type(4))) float f32x4;

__device__ __forceinline__ float bflo(unsigned u){ return __uint_as_float(u << 16); }
__device__ __forceinline__ float bfhi(unsigned u){ return __uint_as_float(u & 0xffff0000u); }
__device__ __forceinline__ unsigned f2bf(float f){
    unsigned u = __float_as_uint(f);
    u += 0x7fffu + ((u >> 16) & 1u);
    return u >> 16;
}
__device__ __forceinline__ void stage16_f32(const float* __restrict__ src,
                                            __hip_bfloat16* dst){
    const float4 f0 = *reinterpret_cast<const float4*>(src);
    const float4 f1 = *reinterpret_cast<const float4*>(src + 4);
    const float4 f2 = *reinterpret_cast<const float4*>(src + 8);
    const float4 f3 = *reinterpret_cast<const float4*>(src + 12);
    uint4 o0, o1;
    o0.x = f2bf(f0.x) | (f2bf(f0.y) << 16);
    o0.y = f2bf(f0.z) | (f2bf(f0.w) << 16);
    o0.z = f2bf(f1.x) | (f2bf(f1.y) << 16);
    o0.w = f2bf(f1.z) | (f2bf(f1.w) << 16);
    o1.x = f2bf(f2.x) | (f2bf(f2.y) << 16);
    o1.y = f2bf(f2.z) | (f2bf(f2.w) << 16);
    o1.z = f2bf(f3.x) | (f2bf(f3.y) << 16);
    o1.w = f2bf(f3.z) | (f2bf(f3.w) << 16);
    *reinterpret_cast<uint4*>(dst) = o0;
    *reinterpret_cast<uint4*>(dst + 8) = o1;
}
__device__ __forceinline__ void stage16_b16(const __hip_bfloat16* __restrict__ src,
                                            __hip_bfloat16* dst){
    const uint4* s = reinterpret_cast<const uint4*>(src);
    uint4* d = reinterpret_cast<uint4*>(dst);
    d[0] = s[0]; d[1] = s[1];
}

// ---------------- one-time f32 -> bf16 conversion of x + 6 weights ----------------
__global__ void conv_bf16(
    const float* s0, const float* s1, const float* s2, const float* s3,
    const float* s4, const float* s5, const float* s6,
    __hip_bfloat16* d0, __hip_bfloat16* d1, __hip_bfloat16* d2, __hip_bfloat16* d3,
    __hip_bfloat16* d4, __hip_bfloat16* d5, __hip_bfloat16* d6)
{
    const int which = blockIdx.y;
    const float* s; __hip_bfloat16* d; int n;
    switch (which) {
        case 0: s = s0; d = d0; n = 2097152; break;
        case 1: s = s1; d = d1; n = 262144; break;
        case 2: s = s2; d = d2; n = 262144; break;
        case 3: s = s3; d = d3; n = 262144; break;
        case 4: s = s4; d = d4; n = 266240; break;
        case 5: s = s5; d = d5; n = 262144; break;
        default: s = s6; d = d6; n = 262144; break;
    }
    const int base = (blockIdx.x * 256 + threadIdx.x) * 4;
    if (base >= n) return;
    const float4 f = *reinterpret_cast<const float4*>(s + base);
    uint2 o;
    o.x = f2bf(f.x) | (f2bf(f.y) << 16);
    o.y = f2bf(f.z) | (f2bf(f.w) << 16);
    *reinterpret_cast<uint2*>(d + base) = o;
}

// ---------------- fused QKV projection (MFMA) ----------------
template<int B16>
__global__ __launch_bounds__(256) void qkv_gemm(
    const void* __restrict__ x,
    const void* __restrict__ Wq, const float* __restrict__ bq,
    const void* __restrict__ Wk, const float* __restrict__ bk,
    const void* __restrict__ Wv, const float* __restrict__ bv,
    __hip_bfloat16* __restrict__ qb,
    __hip_bfloat16* __restrict__ kb,
    __hip_bfloat16* __restrict__ vT)
{
    __shared__ __hip_bfloat16 As[64][72];
    __shared__ __hip_bfloat16 Bs[64][72];
    const int tid = threadIdx.x;
    const int which = blockIdx.x >> 3;
    const int col0 = (blockIdx.x & 7) * 64;
    const int row0 = blockIdx.y * 64;
    const int wv = tid >> 6, lane = tid & 63, quad = lane >> 4, m16 = lane & 15;
    const int sr = tid >> 2;
    const int sc = (tid & 3) * 16;
    const void* W    = (which == 0) ? Wq : (which == 1) ? Wk : Wv;
    const float* bias = (which == 0) ? bq : (which == 1) ? bk : bv;

    f32x4 acc[4];
    #pragma unroll
    for (int nt = 0; nt < 4; ++nt) acc[nt] = (f32x4){0.f, 0.f, 0.f, 0.f};

    for (int k0 = 0; k0 < 512; k0 += 64) {
        if (B16) {
            stage16_b16((const __hip_bfloat16*)x + (size_t)(row0 + sr) * EE + k0 + sc, &As[sr][sc]);
            stage16_b16((const __hip_bfloat16*)W + (size_t)(col0 + sr) * EE + k0 + sc, &Bs[sr][sc]);
        } else {
            stage16_f32((const float*)x + (size_t)(row0 + sr) * EE + k0 + sc, &As[sr][sc]);
            stage16_f32((const float*)W + (size_t)(col0 + sr) * EE + k0 + sc, &Bs[sr][sc]);
        }
        __syncthreads();
        #pragma unroll
        for (int ks = 0; ks < 2; ++ks) {
            const short8 a = *reinterpret_cast<const short8*>(
                &As[wv * 16 + m16][ks * 32 + quad * 8]);
            #pragma unroll
            for (int nt = 0; nt < 4; ++nt) {
                const short8 b = *reinterpret_cast<const short8*>(
                    &Bs[nt * 16 + m16][ks * 32 + quad * 8]);
                acc[nt] = __builtin_amdgcn_mfma_f32_16x16x32_bf16(a, b, acc[nt], 0, 0, 0);
            }
        }
        __syncthreads();
    }

    if (which == 2) {
        #pragma unroll
        for (int nt = 0; nt < 4; ++nt) {
            const float bb = bias[col0 + nt * 16 + m16];
            #pragma unroll
            for (int r = 0; r < 4; ++r)
                Bs[wv * 16 + quad * 4 + r][nt * 16 + m16] =
                    __float2bfloat16(acc[nt][r] + bb);
        }
        __syncthreads();
        const int bb2 = row0 >> 11;
        const int j0 = row0 & (SS - 1);
        const int er = tid >> 2;
        const int js = (tid & 3) * 16;
        unsigned pk[8];
        #pragma unroll
        for (int p = 0; p < 8; ++p) {
            const unsigned lo = *reinterpret_cast<const unsigned short*>(&Bs[js + 2*p][er]);
            const unsigned hi = *reinterpret_cast<const unsigned short*>(&Bs[js + 2*p + 1][er]);
            pk[p] = lo | (hi << 16);
        }
        uint4 s0; s0.x = pk[0]; s0.y = pk[1]; s0.z = pk[2]; s0.w = pk[3];
        uint4 s1; s1.x = pk[4]; s1.y = pk[5]; s1.z = pk[6]; s1.w = pk[7];
        __hip_bfloat16* dst = vT + ((size_t)(bb2 * EE + col0 + er)) * SS + j0 + js;
        *reinterpret_cast<uint4*>(dst) = s0;
        *reinterpret_cast<uint4*>(dst + 8) = s1;
    } else {
        __hip_bfloat16* C = (which == 0) ? qb : kb;
        #pragma unroll
        for (int nt = 0; nt < 4; ++nt) {
            const int gn = col0 + nt * 16 + m16;
            const float bb = bias[gn];
            #pragma unroll
            for (int r = 0; r < 4; ++r) {
                const int gm = row0 + wv * 16 + quad * 4 + r;
                C[(size_t)gm * EE + gn] = __float2bfloat16(acc[nt][r] + bb);
            }
        }
    }
}

// ---------------- MFMA GEMM (MLP1 / MLP2 / out-proj) ----------------
template<int MODE, int AB16, int WB16, int CF32>
__global__ __launch_bounds__(256) void gemm_bt(
    const void* __restrict__ Av,
    const void* __restrict__ Wv_,
    const float* __restrict__ bias,
    void* __restrict__ Cv,
    int ldb)
{
    __shared__ __hip_bfloat16 As[64][72];
    __shared__ __hip_bfloat16 Bs[64][72];
    const int tid = threadIdx.x;
    const int col0 = blockIdx.x * 64;
    const int row0 = blockIdx.y * 64;
    const int wv = tid >> 6, lane = tid & 63, quad = lane >> 4, m16 = lane & 15;
    const int sr = tid >> 2;
    const int sc = (tid & 3) * 16;

    f32x4 acc[4];
    #pragma unroll
    for (int nt = 0; nt < 4; ++nt) acc[nt] = (f32x4){0.f, 0.f, 0.f, 0.f};

    for (int k0 = 0; k0 < 512; k0 += 64) {
        if (AB16)
            stage16_b16((const __hip_bfloat16*)Av + (size_t)(row0 + sr) * EE + k0 + sc, &As[sr][sc]);
        else
            stage16_f32((const float*)Av + (size_t)(row0 + sr) * EE + k0 + sc, &As[sr][sc]);
        if (WB16)
            stage16_b16((const __hip_bfloat16*)Wv_ + (size_t)(col0 + sr) * ldb + k0 + sc, &Bs[sr][sc]);
        else
            stage16_f32((const float*)Wv_ + (size_t)(col0 + sr) * ldb + k0 + sc, &Bs[sr][sc]);
        __syncthreads();
        #pragma unroll
        for (int ks = 0; ks < 2; ++ks) {
            const short8 a = *reinterpret_cast<const short8*>(
                &As[wv * 16 + m16][ks * 32 + quad * 8]);
            #pragma unroll
            for (int nt = 0; nt < 4; ++nt) {
                const short8 b = *reinterpret_cast<const short8*>(
                    &Bs[nt * 16 + m16][ks * 32 + quad * 8]);
                acc[nt] = __builtin_amdgcn_mfma_f32_16x16x32_bf16(a, b, acc[nt], 0, 0, 0);
            }
        }
        __syncthreads();
    }

    #pragma unroll
    for (int nt = 0; nt < 4; ++nt) {
        const int gn = col0 + nt * 16 + m16;
        float bb = bias[gn];
        if (MODE == 1) {
            float ts = 0.f;
            #pragma unroll
            for (int h = 0; h < 8; ++h) {
                const size_t wi = (size_t)gn * ldb + 512 + h;
                ts += WB16 ? (float)((const __hip_bfloat16*)Wv_)[wi]
                           : ((const float*)Wv_)[wi];
            }
            bb += ts * (1.0f / (float)SS);
        }
        #pragma unroll
        for (int r = 0; r < 4; ++r) {
            const int gm = row0 + wv * 16 + quad * 4 + r;
            const size_t ci = (size_t)gm * EE + gn;
            float c = acc[nt][r] + bb;
            if (MODE == 1) c = 0.5f * c * (1.0f + erff(c * 0.70710678118654752f));
            if (MODE == 2) c += (float)((const __hip_bfloat16*)Cv)[ci];
            if (CF32) ((float*)Cv)[ci] = c;
            else      ((__hip_bfloat16*)Cv)[ci] = __float2bfloat16(c);
        }
    }
}

// ---------------- K1: partial softmax denominators (tiled, coalesced K) ----------------
// Block = 64 i-rows x 256 j. Waves own 16 i each (Q A-frags in registers);
// K tiles (16 j x 512) staged cooperatively into LDS -> coalesced global reads.
__global__ __launch_bounds__(256) void attn_denoms(
    const __hip_bfloat16* __restrict__ qws,
    const __hip_bfloat16* __restrict__ kws,
    float* __restrict__ dnP,
    float* __restrict__ cnt)
{
    __shared__ __hip_bfloat16 KL[16][520];
    const int tid = threadIdx.x;
    const int wv = tid >> 6, lane = tid & 63, quad = lane >> 4, m16 = lane & 15;
    const int jc = blockIdx.x;              // 8 chunks x 256 j
    const int it = blockIdx.y;              // 32 tiles x 64 i
    const int b  = blockIdx.z;
    const size_t g0 = (size_t)b * SS + it * 64;
    const size_t gb = (size_t)b * SS;
    const float scale = 0.125f;

    if (jc == 0 && tid < 64) cnt[g0 + tid] = 0.f;

    // Q A-frags: this wave's 16 i-rows, all 8 heads (64 VGPR)
    short8 aq[HH][2];
    #pragma unroll
    for (int h = 0; h < HH; ++h)
        #pragma unroll
        for (int ks = 0; ks < 2; ++ks)
            aq[h][ks] = *reinterpret_cast<const short8*>(
                qws + (g0 + wv * 16 + m16) * EE + h * 64 + ks * 32 + quad * 8);

    float dph[HH][4];
    #pragma unroll
    for (int h = 0; h < HH; ++h)
        #pragma unroll
        for (int r = 0; r < 4; ++r) dph[h][r] = 0.f;

    const int srow = tid >> 4, scol = (tid & 15) * 32;
    for (int jt = 0; jt < 16; ++jt) {
        const int j0 = jc * 256 + jt * 16;
        const uint4* src = reinterpret_cast<const uint4*>(
            kws + (gb + j0 + srow) * EE + scol);
        uint4* dst = reinterpret_cast<uint4*>(&KL[srow][scol]);
        dst[0] = src[0]; dst[1] = src[1]; dst[2] = src[2]; dst[3] = src[3];
        __syncthreads();
        #pragma unroll
        for (int h = 0; h < HH; ++h) {
            const short8 b0 = *reinterpret_cast<const short8*>(&KL[m16][h * 64 + quad * 8]);
            const short8 b1 = *reinterpret_cast<const short8*>(&KL[m16][h * 64 + 32 + quad * 8]);
            f32x4 c = {0.f, 0.f, 0.f, 0.f};
            c = __builtin_amdgcn_mfma_f32_16x16x32_bf16(aq[h][0], b0, c, 0, 0, 0);
            c = __builtin_amdgcn_mfma_f32_16x16x32_bf16(aq[h][1], b1, c, 0, 0, 0);
            #pragma unroll
            for (int r = 0; r < 4; ++r) dph[h][r] += __expf(c[r] * scale);
        }
        __syncthreads();
    }

    // reduce over the 16 j-lanes (m16) once, write dnP
    #pragma unroll
    for (int h = 0; h < HH; ++h)
        #pragma unroll
        for (int off = 1; off <= 8; off <<= 1)
            #pragma unroll
            for (int r = 0; r < 4; ++r) dph[h][r] += __shfl_xor(dph[h][r], off, 64);
    if (m16 == 0) {
        const size_t i = (size_t)it * 64 + wv * 16 + quad * 4;
        #pragma unroll
        for (int h = 0; h < HH; ++h)
            #pragma unroll
            for (int r = 0; r < 4; ++r)
                dnP[((size_t)(jc * BB + b) * SS + i + r) * HH + h] = dph[h][r];
    }
}

// ---------------- K2: ew tiles -> ewG (tiled, coalesced K) ----------------
// Block = 64 i x 128 j. grid (16, 32, 2) = 1024 blocks, LDS 36 KB -> 4 blocks/CU.
__global__ __launch_bounds__(256) void attn_ew(
    const __hip_bfloat16* __restrict__ qws,
    const __hip_bfloat16* __restrict__ kws,
    const float* __restrict__ dnP,
    float* __restrict__ cnt,
    __hip_bfloat16* __restrict__ ewG)
{
    __shared__ __hip_bfloat16 KL[16][520];     // 16.6 KB
    __shared__ __hip_bfloat16 ewT[64][136];    // 17.4 KB
    __shared__ float invd[HH][64];             // 2 KB
    const int tid = threadIdx.x;
    const int wv = tid >> 6, lane = tid & 63, quad = lane >> 4, m16 = lane & 15;
    const int jc = blockIdx.x;                 // 16 chunks x 128 j
    const int it = blockIdx.y;                 // 32 tiles x 64 i
    const int b  = blockIdx.z;
    const size_t g0 = (size_t)b * SS + it * 64;
    const size_t gb = (size_t)b * SS;
    const float scale = 0.125f;

    for (int idx = tid; idx < HH * 64; idx += 256) {
        const int h = idx >> 6, i = idx & 63;
        float s = 0.f;
        #pragma unroll
        for (int c = 0; c < JC1; ++c)
            s += dnP[((size_t)(c * BB + b) * SS + it * 64 + i) * HH + h];
        invd[h][i] = 0.125f / s;   // head-mean folded in
    }

    short8 aq[HH][2];
    #pragma unroll
    for (int h = 0; h < HH; ++h)
        #pragma unroll
        for (int ks = 0; ks < 2; ++ks)
            aq[h][ks] = *reinterpret_cast<const short8*>(
                qws + (g0 + wv * 16 + m16) * EE + h * 64 + ks * 32 + quad * 8);
    __syncthreads();

    float cl[4] = {0.f, 0.f, 0.f, 0.f};
    const int srow = tid >> 4, scol = (tid & 15) * 32;
    for (int jt = 0; jt < 8; ++jt) {
        const int j0 = jc * 128 + jt * 16;
        const uint4* src = reinterpret_cast<const uint4*>(
            kws + (gb + j0 + srow) * EE + scol);
        uint4* dst = reinterpret_cast<uint4*>(&KL[srow][scol]);
        dst[0] = src[0]; dst[1] = src[1]; dst[2] = src[2]; dst[3] = src[3];
        __syncthreads();
        float wsum[4] = {0.f, 0.f, 0.f, 0.f};
        #pragma unroll
        for (int h = 0; h < HH; ++h) {
            const short8 b0 = *reinterpret_cast<const short8*>(&KL[m16][h * 64 + quad * 8]);
            const short8 b1 = *reinterpret_cast<const short8*>(&KL[m16][h * 64 + 32 + quad * 8]);
            f32x4 c = {0.f, 0.f, 0.f, 0.f};
            c = __builtin_amdgcn_mfma_f32_16x16x32_bf16(aq[h][0], b0, c, 0, 0, 0);
            c = __builtin_amdgcn_mfma_f32_16x16x32_bf16(aq[h][1], b1, c, 0, 0, 0);
            #pragma unroll
            for (int r = 0; r < 4; ++r)
                wsum[r] += __expf(c[r] * scale) * invd[h][wv * 16 + quad * 4 + r];
        }
        const int jloc = jt * 16 + m16;
        #pragma unroll
        for (int r = 0; r < 4; ++r) {
            const __hip_bfloat16 wb = __float2bfloat16(wsum[r]);
            if ((float)wb > 0.1f) cl[r] += 1.f;
            ewT[wv * 16 + quad * 4 + r][jloc] = wb;
        }
        __syncthreads();
    }

    // neighbor counts: reduce over the 16 j-lanes, atomicAdd (integer-valued)
    #pragma unroll
    for (int off = 1; off <= 8; off <<= 1)
        #pragma unroll
        for (int r = 0; r < 4; ++r) cl[r] += __shfl_xor(cl[r], off, 64);
    if (m16 == 0) {
        #pragma unroll
        for (int r = 0; r < 4; ++r)
            if (cl[r] != 0.f) atomicAdd(&cnt[g0 + wv * 16 + quad * 4 + r], cl[r]);
    }

    // coalesced copy-out: 64 rows x 128 cols (4 threads/row, 64 B each)
    const int row = tid >> 2;
    const int cs = (tid & 3) * 32;
    const uint4* s = reinterpret_cast<const uint4*>(&ewT[row][cs]);
    uint4* d = reinterpret_cast<uint4*>(
        ewG + ((size_t)(gb + it * 64 + row)) * SS + jc * 128 + cs);
    d[0] = s[0]; d[1] = s[1]; d[2] = s[2]; d[3] = s[3];
}

// ---------------- K3: u1 = ewG @ V via MFMA GEMM (K=2048) ----------------
__global__ __launch_bounds__(256) void attn_pv_gemm(
    const __hip_bfloat16* __restrict__ ewG,
    const __hip_bfloat16* __restrict__ vT,
    const float* __restrict__ cnt,
    const float* __restrict__ x,
    __hip_bfloat16* __restrict__ u1out)
{
    __shared__ __hip_bfloat16 As[64][72];
    __shared__ __hip_bfloat16 Bs[64][72];
    __shared__ float cntL[64];
    const int tid = threadIdx.x;
    const int col0 = blockIdx.x * 64;
    const int row0 = blockIdx.y * 64;
    const int b = row0 >> 11;
    const int i0 = row0 & (SS - 1);
    const int wv = tid >> 6, lane = tid & 63, quad = lane >> 4, m16 = lane & 15;
    const int sr = tid >> 2;
    const int sc = (tid & 3) * 16;
    const __hip_bfloat16* Abase = ewG + ((size_t)b * SS + i0) * SS;
    const __hip_bfloat16* Bbase = vT + ((size_t)(b * EE + col0)) * SS;

    if (tid < 64) cntL[tid] = cnt[(size_t)row0 + tid];

    f32x4 acc[4];
    #pragma unroll
    for (int nt = 0; nt < 4; ++nt) acc[nt] = (f32x4){0.f, 0.f, 0.f, 0.f};

    for (int k0 = 0; k0 < SS; k0 += 64) {
        const uint4* sa = reinterpret_cast<const uint4*>(Abase + (size_t)sr * SS + k0 + sc);
        uint4* da = reinterpret_cast<uint4*>(&As[sr][sc]);
        da[0] = sa[0]; da[1] = sa[1];
        const uint4* sb = reinterpret_cast<const uint4*>(Bbase + (size_t)sr * SS + k0 + sc);
        uint4* db = reinterpret_cast<uint4*>(&Bs[sr][sc]);
        db[0] = sb[0]; db[1] = sb[1];
        __syncthreads();
        #pragma unroll
        for (int ks = 0; ks < 2; ++ks) {
            const short8 a = *reinterpret_cast<const short8*>(
                &As[wv * 16 + m16][ks * 32 + quad * 8]);
            #pragma unroll
            for (int nt = 0; nt < 4; ++nt) {
                const short8 bfr = *reinterpret_cast<const short8*>(
                    &Bs[nt * 16 + m16][ks * 32 + quad * 8]);
                acc[nt] = __builtin_amdgcn_mfma_f32_16x16x32_bf16(a, bfr, acc[nt], 0, 0, 0);
            }
        }
        __syncthreads();
    }

    #pragma unroll
    for (int nt = 0; nt < 4; ++nt) {
        const int gn = col0 + nt * 16 + m16;
        #pragma unroll
        for (int r = 0; r < 4; ++r) {
            const int lr = wv * 16 + quad * 4 + r;
            const int gm = row0 + lr;
            float val = acc[nt][r];
            const float c = cntL[lr];
            if (c > 0.f) {   // exact rare path: masked mean aggregation
                float m = 0.f;
                const __hip_bfloat16* er = Abase + (size_t)lr * SS;
                for (int j = 0; j < SS; ++j) {
                    const float w = (float)er[j];
                    if (w > 0.1f) m += w * x[((size_t)b * SS + j) * EE + gn];
                }
                val += m / c;
            }
            u1out[(size_t)gm * EE + gn] = __float2bfloat16(val);
        }
    }
}

extern "C" void kernel_launch(void* const* d_in, const int* in_sizes, int n_in,
                              void* d_out, int out_size, void* d_ws, size_t ws_size,
                              hipStream_t stream)
{
    const float* x   = (const float*)d_in[0];
    const float* Wq  = (const float*)d_in[1];
    const float* bq  = (const float*)d_in[2];
    const float* Wk  = (const float*)d_in[3];
    const float* bk  = (const float*)d_in[4];
    const float* Wv  = (const float*)d_in[5];
    const float* bv  = (const float*)d_in[6];
    const float* Wm1 = (const float*)d_in[7];
    const float* bm1 = (const float*)d_in[8];
    const float* Wm2 = (const float*)d_in[9];
    const float* bm2 = (const float*)d_in[10];
    const float* Wo  = (const float*)d_in[11];
    const float* bo  = (const float*)d_in[12];

    char* ws = (char*)d_ws;
    const size_t MB = 1024 * 1024;
    __hip_bfloat16* qb = (__hip_bfloat16*)(ws + 0);        // q -> u1 -> t   4MB
    __hip_bfloat16* kb = (__hip_bfloat16*)(ws + 4*MB);     // k -> hm        4MB
    __hip_bfloat16* vT = (__hip_bfloat16*)(ws + 8*MB);     // V^T [b][e][j]  4MB
    __hip_bfloat16* ewG = (__hip_bfloat16*)(ws + 12*MB);   // ew [B,S,S]    16MB
    float* dnP = (float*)(ws + 28*MB);                     // denom partials 1MB
    float* cnt = (float*)(ws + 29*MB);                     // neighbor cnt  16KB
    const bool EXT = (ws_size >= 38 * MB);
    __hip_bfloat16* xb   = (__hip_bfloat16*)(ws + 30*MB);          // 4MB
    __hip_bfloat16* wqb  = (__hip_bfloat16*)(ws + 34*MB);
    __hip_bfloat16* wkb  = (__hip_bfloat16*)(ws + 34*MB + 512*1024);
    __hip_bfloat16* wvb  = (__hip_bfloat16*)(ws + 35*MB);
    __hip_bfloat16* wm1b = (__hip_bfloat16*)(ws + 35*MB + 512*1024);
    __hip_bfloat16* wm2b = (__hip_bfloat16*)(ws + 36*MB + 256*1024);
    __hip_bfloat16* wob  = (__hip_bfloat16*)(ws + 36*MB + 768*1024);

    dim3 blk(256, 1, 1);
    dim3 gg(EE / 64, NN / 64, 1);

    if (EXT) {
        conv_bf16<<<dim3(2048, 7, 1), blk, 0, stream>>>(
            x, Wq, Wk, Wv, Wm1, Wm2, Wo, xb, wqb, wkb, wvb, wm1b, wm2b, wob);
        qkv_gemm<1><<<dim3(24, NN / 64, 1), blk, 0, stream>>>(
            xb, wqb, bq, wkb, bk, wvb, bv, qb, kb, vT);
    } else {
        qkv_gemm<0><<<dim3(24, NN / 64, 1), blk, 0, stream>>>(
            x, Wq, bq, Wk, bk, Wv, bv, qb, kb, vT);
    }
    attn_denoms<<<dim3(JC1, SS / 64, BB), blk, 0, stream>>>(qb, kb, dnP, cnt);
    attn_ew<<<dim3(JCE, SS / 64, BB), blk, 0, stream>>>(qb, kb, dnP, cnt, ewG);
    attn_pv_gemm<<<gg, blk, 0, stream>>>(ewG, vT, cnt, x, qb);          // u1 -> qb
    if (EXT) {
        gemm_bt<1,1,1,0><<<gg, blk, 0, stream>>>(xb, wm1b, bm1, kb, EE + HH);
        gemm_bt<2,1,1,0><<<gg, blk, 0, stream>>>(kb, wm2b, bm2, qb, EE);
        gemm_bt<0,1,1,1><<<gg, blk, 0, stream>>>(qb, wob, bo, d_out, EE);
    } else {
        gemm_bt<1,0,0,0><<<gg, blk, 0, stream>>>(x, Wm1, bm1, kb, EE + HH);
        gemm_bt<2,1,0,0><<<gg, blk, 0, stream>>>(kb, Wm2, bm2, qb, EE);
        gemm_bt<0,1,0,1><<<gg, blk, 0, stream>>>(qb, Wo, bo, d_out, EE);
    }
}